// Round 2
// baseline (715.262 us; speedup 1.0000x reference)
//
#include <hip/hip_runtime.h>
#include <math.h>

#define N_PROP 1024
#define C_FEAT 32
#define ROI 7
#define SR 6
#define S_GRID 42
#define IMG_H 360
#define IMG_W 1200
#define BEV_H 700
#define BEV_W 800
#define D_FEAT (C_FEAT*ROI*ROI)   // 1568
#define HID 2048
#define NMS_K 100
#define NMS_THR 0.01f

typedef __attribute__((ext_vector_type(8))) short bf16x8;
typedef __attribute__((ext_vector_type(4))) float f32x4;
typedef __attribute__((ext_vector_type(2), aligned(4))) float f32x2u;

// ---------------- workspace layout (float offsets) ----------------
// Peak 5,102,592 floats = 20.4 MB (< 25.3 MB proven).
//   img phase: img_s @R0 written; img_t (channel-last 8ch chunk, 3.456M f)
//              overlaid at R1 (bev_s region + fused region, both dead then)
//   bev phase: bev_s @R1 overwrites dead img_t
//   combine:   reads R0,R1 -> fusedHi/Lo (bf16, after R1)
//   gemm1:     reads fused -> h1Hi/Lo (bf16) @ R0
//   gemm2:     reads h1 -> h2 fp32 @ after h1
#define WS_IMG_BOXES 0
#define WS_BEV_BOXES (WS_IMG_BOXES + 4*N_PROP)
#define WS_OBJS      (WS_BEV_BOXES + 4*N_PROP)
#define WS_OFF       (WS_OBJS + 2*N_PROP)
#define WS_ORIENT    (WS_OFF + 10*N_PROP)
#define WS_PRED      (WS_ORIENT + N_PROP)
#define WS_PBEV      (WS_PRED + 6*N_PROP)
#define WS_SCORES    (WS_PBEV + 4*N_PROP)
#define WS_IDX       (WS_SCORES + N_PROP)
#define WS_R0        40960
#define WS_R1        (WS_R0 + N_PROP*D_FEAT)            // 1646592
#define WS_IMGT      WS_R1                               // img_t chunk alias (3,456,000 f)
#define WS_FUSED_HI  (WS_R0 + 2*N_PROP*D_FEAT)          // 3252224 (802816 f)
#define WS_FUSED_LO  (WS_FUSED_HI + N_PROP*D_FEAT/2)    // 4055040
#define WS_H1HI      WS_R0                               // bf16 2M elems
#define WS_H1LO      (WS_R0 + N_PROP*HID/2)             // 1089536
#define WS_H2        (WS_R0 + N_PROP*HID)               // 2138112 (fp32)

__device__ __forceinline__ unsigned int bf16_rtn(float x) {
    unsigned int u = __float_as_uint(x);
    return (u + 0x7FFFu + ((u >> 16) & 1u)) >> 16;
}

// ---------------- K1: project boxes ----------------
__global__ void boxes_kernel(const float* __restrict__ anchors,
                             const float* __restrict__ calib,
                             const int* __restrict__ imshape,
                             float* __restrict__ img_boxes,
                             float* __restrict__ bev_boxes) {
    int n = blockIdx.x * blockDim.x + threadIdx.x;
    if (n >= N_PROP) return;
    float x = anchors[n*6+0], y = anchors[n*6+1], z = anchors[n*6+2];
    float dx = anchors[n*6+3], dy = anchors[n*6+4], dz = anchors[n*6+5];

    bev_boxes[n*4+0] = ((x - dx*0.5f) - (-40.0f)) / 0.1f;
    bev_boxes[n*4+1] = (70.0f - (z + dz*0.5f)) / 0.1f;
    bev_boxes[n*4+2] = ((x + dx*0.5f) - (-40.0f)) / 0.1f;
    bev_boxes[n*4+3] = (70.0f - (z - dz*0.5f)) / 0.1f;

    float P[12];
    #pragma unroll
    for (int i = 0; i < 12; i++) P[i] = calib[i];

    float umin = 1e30f, vmin = 1e30f, umax = -1e30f, vmax = -1e30f;
    #pragma unroll
    for (int k = 0; k < 8; k++) {
        float fsx = (k & 4) ? 1.0f : -1.0f;
        float fsy = (k & 2) ? 1.0f : -1.0f;
        float fsz = (k & 1) ? 1.0f : -1.0f;
        float cx = x + fsx * dx * 0.5f;
        float cy = y + fsy * dy * 0.5f;
        float cz = z + fsz * dz * 0.5f;
        float p0 = P[0]*cx + P[1]*cy + P[2]*cz + P[3];
        float p1 = P[4]*cx + P[5]*cy + P[6]*cz + P[7];
        float p2 = P[8]*cx + P[9]*cy + P[10]*cz + P[11];
        float zz = fmaxf(p2, 0.1f);
        float u = p0 / zz, v = p1 / zz;
        umin = fminf(umin, u); umax = fmaxf(umax, u);
        vmin = fminf(vmin, v); vmax = fmaxf(vmax, v);
    }
    float Hf = (float)imshape[0];
    float Wf = (float)imshape[1];
    img_boxes[n*4+0] = fminf(fmaxf(umin, 0.0f), Wf);
    img_boxes[n*4+1] = fminf(fmaxf(vmin, 0.0f), Hf);
    img_boxes[n*4+2] = fminf(fmaxf(umax, 0.0f), Wf);
    img_boxes[n*4+3] = fminf(fmaxf(vmax, 0.0f), Hf);
}

// ---------------- K2a: transpose img chunk [8c][H][W] -> [H][W][8c] ----------
__global__ __launch_bounds__(256) void transpose_img_kernel(
        const float* __restrict__ in, float* __restrict__ out, int c0) {
    __shared__ float lds[64*9];
    int y = blockIdx.y;
    int x0 = blockIdx.x * 64;
    int xl = threadIdx.x & 63;
    int ch = threadIdx.x >> 6;       // 0..3
    int x = x0 + xl;
    #pragma unroll
    for (int i = 0; i < 2; i++) {
        int c = ch + i*4;            // 0..7
        float v = 0.0f;
        if (x < IMG_W)
            v = in[(size_t)(c0+c)*IMG_H*IMG_W + (size_t)y*IMG_W + x];
        lds[xl*9 + c] = v;
    }
    __syncthreads();
    int c8 = threadIdx.x & 7;
    int xp = threadIdx.x >> 3;       // 0..31
    #pragma unroll
    for (int j = 0; j < 2; j++) {
        int xx = x0 + xp + j*32;
        if (xx < IMG_W)
            out[((size_t)y*IMG_W + xx)*8 + c8] = lds[(xp + j*32)*9 + c8];
    }
}

// ---------------- K2b: channel-last img roi (tap-optimized) ----------------
// T: [H][W][8] fp32 chunk.  Block = 1 box, 4 waves split py {w, w+4}.
// Lane = sy2(b5) sxb(b4) px(b3..1) c4(b0): each lane bilinears an f32x4 of
// 4 channels; a wave-load covers 28 samples x 8ch in ~14-28 line taps
// (vs 42 taps for 42 samples x 1ch in the planar layout).
__global__ __launch_bounds__(256) void roi_img_cl_kernel(
        const float* __restrict__ T, const float* __restrict__ img_boxes,
        float* __restrict__ img_out, int c0) {
    int b = blockIdx.x;
    __shared__ float s_xw[S_GRID], s_yw[S_GRID];
    __shared__ int   s_xi[S_GRID], s_yr[S_GRID];
    __shared__ float s_out[8*49];
    int tid = threadIdx.x;
    if (tid < S_GRID) {
        float g = ((float)tid + 0.5f) / (float)S_GRID;
        float bx1 = img_boxes[b*4+0] - 0.5f, by1 = img_boxes[b*4+1] - 0.5f;
        float bx2 = img_boxes[b*4+2] - 0.5f, by2 = img_boxes[b*4+3] - 0.5f;
        float xs = bx1 + g * (bx2 - bx1);
        float x0f = fminf(fmaxf(floorf(xs), 0.0f), (float)(IMG_W-2));
        s_xw[tid] = fminf(fmaxf(xs - x0f, 0.0f), 1.0f);
        s_xi[tid] = (int)x0f * 8;                 // float offset: x*8
        float ys = by1 + g * (by2 - by1);
        float y0f = fminf(fmaxf(floorf(ys), 0.0f), (float)(IMG_H-2));
        s_yw[tid] = fminf(fmaxf(ys - y0f, 0.0f), 1.0f);
        s_yr[tid] = (int)y0f * (IMG_W*8);         // float offset: y*W*8
    }
    __syncthreads();

    int wv   = tid >> 6;
    int lane = tid & 63;
    int sy2 = lane >> 5;
    int sxb = (lane >> 4) & 1;
    int px  = (lane >> 1) & 7;    // 7 is idle
    int c4  = lane & 1;
    bool act = (px < 7);

    for (int pyi = 0; pyi < 2; pyi++) {
        int py = wv + pyi*4;
        if (py > 6) break;
        f32x4 acc = {0.f, 0.f, 0.f, 0.f};
        if (act) {
            #pragma unroll
            for (int t = 0; t < 3; t++) {
                int sy = py*6 + t*2 + sy2;
                int row0 = s_yr[sy];
                float wy = s_yw[sy];
                #pragma unroll
                for (int s = 0; s < 3; s++) {
                    int sx = px*6 + s*2 + sxb;
                    int col = s_xi[sx] + c4*4;
                    const float* p00 = T + row0 + col;
                    f32x4 v00 = *(const f32x4*)(p00);
                    f32x4 v01 = *(const f32x4*)(p00 + 8);
                    f32x4 v10 = *(const f32x4*)(p00 + IMG_W*8);
                    f32x4 v11 = *(const f32x4*)(p00 + IMG_W*8 + 8);
                    float wx = s_xw[sx];
                    #pragma unroll
                    for (int e = 0; e < 4; e++) {
                        float top = fmaf(wx, v01[e] - v00[e], v00[e]);
                        float bot = fmaf(wx, v11[e] - v10[e], v10[e]);
                        acc[e] += fmaf(wy, bot - top, top);
                    }
                }
            }
        }
        // reduce partial sums across sy2 (xor32) and sxb (xor16)
        #pragma unroll
        for (int e = 0; e < 4; e++) acc[e] += __shfl_xor(acc[e], 32);
        #pragma unroll
        for (int e = 0; e < 4; e++) acc[e] += __shfl_xor(acc[e], 16);
        if (act && sy2 == 0 && sxb == 0) {
            #pragma unroll
            for (int e = 0; e < 4; e++)
                s_out[(c4*4+e)*49 + py*7 + px] = acc[e];
        }
    }
    __syncthreads();
    float* op = img_out + (size_t)b * D_FEAT + c0*49;
    for (int t = tid; t < 8*49; t += 256) op[t] = s_out[t];
}

// ---------------- K2c: bev roi (planar, proven — bev boxes are narrow) -------
__global__ __launch_bounds__(64, 8) void roi_bev_kernel(
        const float* __restrict__ bevF, const float* __restrict__ bev_boxes,
        float* __restrict__ bev_out) {
    int c = blockIdx.x;
    int b = blockIdx.y;
    const int W = BEV_W, H = BEV_H;
    const float* f = bevF + (size_t)c * W * H;

    int lane = threadIdx.x;
    float bx1 = bev_boxes[b*4+0], by1 = bev_boxes[b*4+1];
    float bx2 = bev_boxes[b*4+2], by2 = bev_boxes[b*4+3];

    __shared__ int   s_row0[S_GRID];
    __shared__ float s_wy[S_GRID];

    int x0i = 0;
    float wx = 0.0f;
    if (lane < S_GRID) {
        float g = ((float)lane + 0.5f) / (float)S_GRID;
        float c1 = bx1 - 0.5f, c2 = bx2 - 0.5f;
        float xs = c1 + g * (c2 - c1);
        float x0f = fminf(fmaxf(floorf(xs), 0.0f), (float)(W-2));
        wx = fminf(fmaxf(xs - x0f, 0.0f), 1.0f);
        x0i = (int)x0f;

        float d1 = by1 - 0.5f, d2 = by2 - 0.5f;
        float ys = d1 + g * (d2 - d1);
        float y0f = fminf(fmaxf(floorf(ys), 0.0f), (float)(H-2));
        float wyv = fminf(fmaxf(ys - y0f, 0.0f), 1.0f);
        int y0 = (int)y0f;
        s_row0[lane] = y0 * W;
        s_wy[lane] = wyv;
    }
    __syncthreads();

    float* op = bev_out + (size_t)b * D_FEAT + c * 49;
    #pragma unroll 1
    for (int py = 0; py < ROI; py++) {
        float pl = 0.0f;
        #pragma unroll
        for (int sy = 0; sy < SR; sy++) {
            int yi = py * SR + sy;
            int r0 = s_row0[yi];
            float wy = s_wy[yi];
            if (lane < S_GRID) {
                f32x2u p0 = *(const f32x2u*)(f + r0 + x0i);
                f32x2u p1 = *(const f32x2u*)(f + r0 + W + x0i);
                float top = fmaf(wx, p0.y - p0.x, p0.x);
                float bot = fmaf(wx, p1.y - p1.x, p1.x);
                pl += fmaf(wy, bot - top, top);
            }
        }
        float s = pl;
        #pragma unroll
        for (int k = 1; k < 6; k++) s += __shfl_down(pl, k);
        if (lane < S_GRID && (lane % 6) == 0)
            op[py * ROI + lane / 6] = s;
    }
}

// ---------------- K3: combine masks + split fp32 -> bf16 hi/lo ----------------
__global__ __launch_bounds__(256) void combine_split_kernel(
        const float4* __restrict__ img, const float4* __restrict__ bev,
        const float* __restrict__ img_mask, const float* __restrict__ bev_mask,
        ushort4* __restrict__ outHi, ushort4* __restrict__ outLo, int total4) {
    int i = blockIdx.x * 256 + threadIdx.x;
    if (i >= total4) return;
    float m0 = img_mask[0], m1 = bev_mask[0];
    float inv = 1.0f / ((m0 + m1) * 36.0f);
    float w0 = m0 * inv, w1 = m1 * inv;
    float4 a = img[i], b = bev[i];
    float v[4] = { w0*a.x + w1*b.x, w0*a.y + w1*b.y, w0*a.z + w1*b.z, w0*a.w + w1*b.w };
    ushort4 hv, lv;
    unsigned short* hp = &hv.x;
    unsigned short* lp = &lv.x;
    #pragma unroll
    for (int e = 0; e < 4; e++) {
        unsigned int rh = bf16_rtn(v[e]);
        float lo = v[e] - __uint_as_float(rh << 16);
        hp[e] = (unsigned short)rh;
        lp[e] = (unsigned short)bf16_rtn(lo);
    }
    outHi[i] = hv;
    outLo[i] = lv;
}

// ---------------- K4: bf16x2 MFMA GEMM, C = relu(A@W + bias) ----------------
#define LDK 40   // LDS row stride (shorts); 80B rows keep b128 16B-aligned
template<int EPI>
__global__ __launch_bounds__(256) void gemm_bf16x2_kernel(
        const unsigned short* __restrict__ Ahi, const unsigned short* __restrict__ Alo,
        const float* __restrict__ W, const float* __restrict__ bias, int K,
        unsigned short* __restrict__ outHi, unsigned short* __restrict__ outLo,
        float* __restrict__ outF) {
    __shared__ short AsH[64*LDK], AsL[64*LDK];
    __shared__ short BsH[128*LDK], BsL[128*LDK];

    const int tid = threadIdx.x;
    const int m0 = blockIdx.y * 64, n0 = blockIdx.x * 128;

    const int am = tid >> 2, ac = tid & 3;
    const uint4* ApH = (const uint4*)(Ahi + (size_t)(m0 + am) * K + ac*8);
    const uint4* ApL = (const uint4*)(Alo + (size_t)(m0 + am) * K + ac*8);
    const int nn = tid & 127, rbase = (tid >> 7) * 16;
    const float* Bp = W + (size_t)rbase * 2048 + n0 + nn;

    const int lane = tid & 63, wave = tid >> 6;
    const int wm = wave & 1, wn = wave >> 1;
    const int l15 = lane & 15, quad = lane >> 4;

    f32x4 acc[2][4];
    #pragma unroll
    for (int i = 0; i < 2; i++)
        #pragma unroll
        for (int j = 0; j < 4; j++)
            acc[i][j] = (f32x4){0.f, 0.f, 0.f, 0.f};

    const int nK = K >> 5;
    uint4 aHr = ApH[0];
    uint4 aLr = ApL[0];
    float bReg[16];
    #pragma unroll
    for (int j = 0; j < 16; j++) bReg[j] = Bp[(size_t)j * 2048];

    for (int ks = 0; ks < nK; ks++) {
        __syncthreads();
        *(uint4*)&AsH[am*LDK + ac*8] = aHr;
        *(uint4*)&AsL[am*LDK + ac*8] = aLr;
        {
            unsigned short hv[16], lv[16];
            #pragma unroll
            for (int j = 0; j < 16; j++) {
                unsigned int rh = bf16_rtn(bReg[j]);
                float lo = bReg[j] - __uint_as_float(rh << 16);
                hv[j] = (unsigned short)rh;
                lv[j] = (unsigned short)bf16_rtn(lo);
            }
            *(uint4*)&BsH[nn*LDK + rbase + 0] = *(uint4*)&hv[0];
            *(uint4*)&BsH[nn*LDK + rbase + 8] = *(uint4*)&hv[8];
            *(uint4*)&BsL[nn*LDK + rbase + 0] = *(uint4*)&lv[0];
            *(uint4*)&BsL[nn*LDK + rbase + 8] = *(uint4*)&lv[8];
        }
        __syncthreads();
        if (ks + 1 < nK) {
            int k0n = (ks + 1) * 32;
            aHr = ApH[k0n >> 3];
            aLr = ApL[k0n >> 3];
            #pragma unroll
            for (int j = 0; j < 16; j++) bReg[j] = Bp[(size_t)(k0n + j) * 2048];
        }
        const short* aBH = AsH + (wm*32 + l15)*LDK + quad*8;
        const short* aBL = AsL + (wm*32 + l15)*LDK + quad*8;
        const short* bBH = BsH + (wn*64 + l15)*LDK + quad*8;
        const short* bBL = BsL + (wn*64 + l15)*LDK + quad*8;
        bf16x8 aH0 = *(const bf16x8*)(aBH);
        bf16x8 aH1 = *(const bf16x8*)(aBH + 16*LDK);
        bf16x8 aL0 = *(const bf16x8*)(aBL);
        bf16x8 aL1 = *(const bf16x8*)(aBL + 16*LDK);
        #pragma unroll
        for (int nt = 0; nt < 4; nt++) {
            bf16x8 bH = *(const bf16x8*)(bBH + nt*16*LDK);
            bf16x8 bL = *(const bf16x8*)(bBL + nt*16*LDK);
            acc[0][nt] = __builtin_amdgcn_mfma_f32_16x16x32_bf16(aH0, bH, acc[0][nt], 0, 0, 0);
            acc[0][nt] = __builtin_amdgcn_mfma_f32_16x16x32_bf16(aH0, bL, acc[0][nt], 0, 0, 0);
            acc[0][nt] = __builtin_amdgcn_mfma_f32_16x16x32_bf16(aL0, bH, acc[0][nt], 0, 0, 0);
            acc[1][nt] = __builtin_amdgcn_mfma_f32_16x16x32_bf16(aH1, bH, acc[1][nt], 0, 0, 0);
            acc[1][nt] = __builtin_amdgcn_mfma_f32_16x16x32_bf16(aH1, bL, acc[1][nt], 0, 0, 0);
            acc[1][nt] = __builtin_amdgcn_mfma_f32_16x16x32_bf16(aL1, bH, acc[1][nt], 0, 0, 0);
        }
    }

    #pragma unroll
    for (int mt = 0; mt < 2; mt++) {
        #pragma unroll
        for (int nt = 0; nt < 4; nt++) {
            int n = n0 + wn*64 + nt*16 + l15;
            float bv = bias[n];
            #pragma unroll
            for (int reg = 0; reg < 4; reg++) {
                int m = m0 + wm*32 + mt*16 + quad*4 + reg;
                float v = fmaxf(acc[mt][nt][reg] + bv, 0.0f);
                if (EPI == 1) {
                    unsigned int rh = bf16_rtn(v);
                    float lo = v - __uint_as_float(rh << 16);
                    outHi[(size_t)m * 2048 + n] = (unsigned short)rh;
                    outLo[(size_t)m * 2048 + n] = (unsigned short)bf16_rtn(lo);
                } else {
                    outF[(size_t)m * 2048 + n] = v;
                }
            }
        }
    }
}

// ---------------- K5: heads (obj/off/ang) + postprocess per row ----------------
__global__ __launch_bounds__(256) void heads_kernel(
        const float* __restrict__ h,
        const float* __restrict__ Wc, const float* __restrict__ bc,
        const float* __restrict__ Wo, const float* __restrict__ bo,
        const float* __restrict__ Wa, const float* __restrict__ ba,
        const float* __restrict__ anchors,
        float* __restrict__ obj_soft, float* __restrict__ off_out,
        float* __restrict__ orient, float* __restrict__ pred,
        float* __restrict__ pbev, float* __restrict__ scores) {
    int row = blockIdx.x;
    const float* hr = h + (size_t)row * HID;
    float acc[14];
    #pragma unroll
    for (int j = 0; j < 14; j++) acc[j] = 0.0f;
    for (int k = threadIdx.x; k < HID; k += 256) {
        float hv = hr[k];
        acc[0]  += hv * Wc[k*2+0];
        acc[1]  += hv * Wc[k*2+1];
        #pragma unroll
        for (int j = 0; j < 10; j++) acc[2+j] += hv * Wo[k*10+j];
        acc[12] += hv * Wa[k*2+0];
        acc[13] += hv * Wa[k*2+1];
    }
    #pragma unroll
    for (int d = 32; d > 0; d >>= 1) {
        #pragma unroll
        for (int j = 0; j < 14; j++) acc[j] += __shfl_down(acc[j], d);
    }
    __shared__ float red[4][14];
    int wid = threadIdx.x >> 6, lane = threadIdx.x & 63;
    if (lane == 0) {
        #pragma unroll
        for (int j = 0; j < 14; j++) red[wid][j] = acc[j];
    }
    __syncthreads();
    if (threadIdx.x == 0) {
        float f[14];
        #pragma unroll
        for (int j = 0; j < 14; j++)
            f[j] = red[0][j] + red[1][j] + red[2][j] + red[3][j];
        float obj0 = f[0] + bc[0], obj1 = f[1] + bc[1];
        float offv[10];
        #pragma unroll
        for (int j = 0; j < 10; j++) offv[j] = f[2+j] + bo[j];
        float ang0 = f[12] + ba[0], ang1 = f[13] + ba[1];
        float mx = fmaxf(obj0, obj1);
        float e0 = expf(obj0 - mx), e1 = expf(obj1 - mx);
        float den = e0 + e1;
        obj_soft[row*2+0] = e0 / den;
        obj_soft[row*2+1] = e1 / den;
        scores[row] = obj1;
        orient[row] = atan2f(ang1, ang0);
        float pa[6];
        #pragma unroll
        for (int j = 0; j < 6; j++) {
            pa[j] = anchors[row*6+j] + offv[j];
            pred[row*6+j] = pa[j];
        }
        #pragma unroll
        for (int j = 0; j < 10; j++) off_out[row*10+j] = offv[j];
        float x = pa[0], z = pa[2], ddx = pa[3], ddz = pa[5];
        pbev[row*4+0] = ((x - ddx*0.5f) - (-40.0f)) / 0.1f;
        pbev[row*4+1] = (70.0f - (z + ddz*0.5f)) / 0.1f;
        pbev[row*4+2] = ((x + ddx*0.5f) - (-40.0f)) / 0.1f;
        pbev[row*4+3] = (70.0f - (z - ddz*0.5f)) / 0.1f;
    }
}

// ---------------- K6: sequential NMS, single wave, fused suppress+argmax -------
__global__ void nms_kernel(const float* __restrict__ boxes,
                           const float* __restrict__ scores_g,
                           int* __restrict__ idx_out) {
    __shared__ float4 sb4[N_PROP];
    __shared__ float  sa[N_PROP];
    int lane = threadIdx.x;
    float sc[16], x1v[16], y1v[16], x2v[16], y2v[16], ar[16];
    const float4* bp = (const float4*)boxes;
    #pragma unroll
    for (int j = 0; j < 16; j++) {
        int g = lane + 64*j;
        float4 bb = bp[g];
        x1v[j] = bb.x; y1v[j] = bb.y; x2v[j] = bb.z; y2v[j] = bb.w;
        ar[j] = (bb.z - bb.x) * (bb.w - bb.y);
        sc[j] = scores_g[g];
        sb4[g] = bb;
        sa[g] = ar[j];
    }
    float bv = sc[0]; int bi = lane;
    #pragma unroll
    for (int j = 1; j < 16; j++) {
        int g = lane + 64*j;
        if (sc[j] > bv) { bv = sc[j]; bi = g; }
    }
    for (int t = 0; t < NMS_K; t++) {
        #pragma unroll
        for (int d = 1; d < 64; d <<= 1) {
            float ov = __shfl_xor(bv, d);
            int   oi = __shfl_xor(bi, d);
            if (ov > bv || (ov == bv && oi < bi)) { bv = ov; bi = oi; }
        }
        if (lane == 0) idx_out[t] = bi;
        float4 pb = sb4[bi];
        float pa = sa[bi];
        float nbv = -INFINITY; int nbi = lane;
        #pragma unroll
        for (int j = 0; j < 16; j++) {
            int g = lane + 64*j;
            float xx1 = fmaxf(x1v[j], pb.x), yy1 = fmaxf(y1v[j], pb.y);
            float xx2 = fminf(x2v[j], pb.z), yy2 = fminf(y2v[j], pb.w);
            float inter = fmaxf(xx2 - xx1, 0.0f) * fmaxf(yy2 - yy1, 0.0f);
            float iou = inter / (ar[j] + pa - inter + 1e-6f);
            if (iou > NMS_THR || g == bi) sc[j] = -INFINITY;
            if (sc[j] > nbv) { nbv = sc[j]; nbi = g; }
        }
        bv = nbv; bi = nbi;
    }
}

// ---------------- K7: gather outputs ----------------
__global__ void gather_kernel(const int* __restrict__ idx,
                              const float* __restrict__ obj_soft,
                              const float* __restrict__ pred,
                              const float* __restrict__ off,
                              const float* __restrict__ orient,
                              float* __restrict__ out) {
    int i = threadIdx.x;
    if (i < NMS_K) {
        int j = idx[i];
        out[2*i+0] = obj_soft[j*2+0];
        out[2*i+1] = obj_soft[j*2+1];
        #pragma unroll
        for (int t = 0; t < 6; t++) out[200 + 6*i + t] = pred[j*6+t];
        #pragma unroll
        for (int t = 0; t < 10; t++) out[800 + 10*i + t] = off[j*10+t];
        #pragma unroll
        for (int t = 0; t < 6; t++) out[1800 + 7*i + t] = pred[j*6+t];
        out[1800 + 7*i + 6] = 0.0f;
        out[2500 + i] = orient[j];
    }
}

extern "C" void kernel_launch(void* const* d_in, const int* in_sizes, int n_in,
                              void* d_out, int out_size, void* d_ws, size_t ws_size,
                              hipStream_t stream) {
    const float* imgF     = (const float*)d_in[0];
    const float* bevF     = (const float*)d_in[1];
    const float* anchors  = (const float*)d_in[2];
    const float* calib    = (const float*)d_in[3];
    const float* img_mask = (const float*)d_in[5];
    const float* bev_mask = (const float*)d_in[6];
    const float* W1 = (const float*)d_in[7];
    const float* b1 = (const float*)d_in[8];
    const float* W2 = (const float*)d_in[9];
    const float* b2 = (const float*)d_in[10];
    const float* Wc = (const float*)d_in[11];
    const float* bc = (const float*)d_in[12];
    const float* Wo = (const float*)d_in[13];
    const float* bo = (const float*)d_in[14];
    const float* Wa = (const float*)d_in[15];
    const float* ba = (const float*)d_in[16];
    const int* image_shape = (const int*)d_in[17];

    float* ws = (float*)d_ws;
    float* img_boxes = ws + WS_IMG_BOXES;
    float* bev_boxes = ws + WS_BEV_BOXES;
    float* obj_soft  = ws + WS_OBJS;
    float* off       = ws + WS_OFF;
    float* orient    = ws + WS_ORIENT;
    float* pred      = ws + WS_PRED;
    float* pbev      = ws + WS_PBEV;
    float* scores    = ws + WS_SCORES;
    int*   idx       = (int*)(ws + WS_IDX);
    float* img_s     = ws + WS_R0;
    float* bev_s     = ws + WS_R1;
    float* img_t     = ws + WS_IMGT;    // alias of R1+ region; dead before bev roi
    unsigned short* fusedHi = (unsigned short*)(ws + WS_FUSED_HI);
    unsigned short* fusedLo = (unsigned short*)(ws + WS_FUSED_LO);
    unsigned short* h1Hi    = (unsigned short*)(ws + WS_H1HI);
    unsigned short* h1Lo    = (unsigned short*)(ws + WS_H1LO);
    float* h2        = ws + WS_H2;

    boxes_kernel<<<N_PROP/64, 64, 0, stream>>>(anchors, calib, image_shape,
                                               img_boxes, bev_boxes);
    // img: 4 chunks of 8 channels, transpose to channel-last then tap-lean roi
    for (int ch = 0; ch < 4; ch++) {
        transpose_img_kernel<<<dim3((IMG_W+63)/64, IMG_H), 256, 0, stream>>>(
            imgF, img_t, ch*8);
        roi_img_cl_kernel<<<N_PROP, 256, 0, stream>>>(
            img_t, img_boxes, img_s, ch*8);
    }
    // bev: planar kernel (narrow boxes -> already ~1-3 line taps per load)
    roi_bev_kernel<<<dim3(C_FEAT, N_PROP), 64, 0, stream>>>(
        bevF, bev_boxes, bev_s);
    combine_split_kernel<<<(N_PROP*D_FEAT/4 + 255)/256, 256, 0, stream>>>(
        (const float4*)img_s, (const float4*)bev_s, img_mask, bev_mask,
        (ushort4*)fusedHi, (ushort4*)fusedLo, N_PROP*D_FEAT/4);
    gemm_bf16x2_kernel<1><<<dim3(16, 16), 256, 0, stream>>>(
        fusedHi, fusedLo, W1, b1, D_FEAT, h1Hi, h1Lo, nullptr);
    gemm_bf16x2_kernel<0><<<dim3(16, 16), 256, 0, stream>>>(
        h1Hi, h1Lo, W2, b2, HID, nullptr, nullptr, h2);
    heads_kernel<<<N_PROP, 256, 0, stream>>>(h2, Wc, bc, Wo, bo, Wa, ba, anchors,
                                             obj_soft, off, orient, pred, pbev, scores);
    nms_kernel<<<1, 64, 0, stream>>>(pbev, scores, idx);
    gather_kernel<<<1, 128, 0, stream>>>(idx, obj_soft, pred, off, orient,
                                         (float*)d_out);
}

// Round 3
// 666.057 us; speedup vs baseline: 1.0739x; 1.0739x over previous
//
#include <hip/hip_runtime.h>
#include <math.h>

#define N_PROP 1024
#define C_FEAT 32
#define ROI 7
#define SR 6
#define S_GRID 42
#define IMG_H 360
#define IMG_W 1200
#define BEV_H 700
#define BEV_W 800
#define D_FEAT (C_FEAT*ROI*ROI)   // 1568
#define HID 2048
#define NMS_K 100
#define NMS_THR 0.01f

typedef __attribute__((ext_vector_type(8))) short bf16x8;
typedef __attribute__((ext_vector_type(4))) float f32x4;
typedef __attribute__((ext_vector_type(2), aligned(4))) float f32x2u;

// ---------------- workspace layout (float offsets) ----------------
// Peak 5,102,592 floats = 20.4 MB (< 25.3 MB proven).
//   img phase: img_s @R0 written; img_t (channel-last 8ch chunk) overlaid @R1
//   bev phase: bev_s @R1 overwrites dead img_t
//   combine:   reads R0,R1 -> fusedHi/Lo (bf16, after R1)
//   gemm1:     reads fused -> h1Hi/Lo (bf16) @ R0
//   gemm2:     reads h1 -> h2 fp32 @ after h1
//   nms:       M bitmap (32768 f = 128 KB) @ R0 (h1 dead after gemm2)
#define WS_IMG_BOXES 0
#define WS_BEV_BOXES (WS_IMG_BOXES + 4*N_PROP)
#define WS_OBJS      (WS_BEV_BOXES + 4*N_PROP)
#define WS_OFF       (WS_OBJS + 2*N_PROP)
#define WS_ORIENT    (WS_OFF + 10*N_PROP)
#define WS_PRED      (WS_ORIENT + N_PROP)
#define WS_PBEV      (WS_PRED + 6*N_PROP)
#define WS_SCORES    (WS_PBEV + 4*N_PROP)
#define WS_IDX       (WS_SCORES + N_PROP)
#define WS_R0        40960
#define WS_R1        (WS_R0 + N_PROP*D_FEAT)            // 1646592
#define WS_IMGT      WS_R1                               // img_t chunk alias
#define WS_FUSED_HI  (WS_R0 + 2*N_PROP*D_FEAT)          // 3252224
#define WS_FUSED_LO  (WS_FUSED_HI + N_PROP*D_FEAT/2)    // 4055040
#define WS_H1HI      WS_R0
#define WS_H1LO      (WS_R0 + N_PROP*HID/2)
#define WS_H2        (WS_R0 + N_PROP*HID)               // 2138112
#define WS_NMSM      WS_R0                               // u64[1024][16] over dead h1

__device__ __forceinline__ unsigned int bf16_rtn(float x) {
    unsigned int u = __float_as_uint(x);
    return (u + 0x7FFFu + ((u >> 16) & 1u)) >> 16;
}

// ---------------- K1: project boxes ----------------
__global__ void boxes_kernel(const float* __restrict__ anchors,
                             const float* __restrict__ calib,
                             const int* __restrict__ imshape,
                             float* __restrict__ img_boxes,
                             float* __restrict__ bev_boxes) {
    int n = blockIdx.x * blockDim.x + threadIdx.x;
    if (n >= N_PROP) return;
    float x = anchors[n*6+0], y = anchors[n*6+1], z = anchors[n*6+2];
    float dx = anchors[n*6+3], dy = anchors[n*6+4], dz = anchors[n*6+5];

    bev_boxes[n*4+0] = ((x - dx*0.5f) - (-40.0f)) / 0.1f;
    bev_boxes[n*4+1] = (70.0f - (z + dz*0.5f)) / 0.1f;
    bev_boxes[n*4+2] = ((x + dx*0.5f) - (-40.0f)) / 0.1f;
    bev_boxes[n*4+3] = (70.0f - (z - dz*0.5f)) / 0.1f;

    float P[12];
    #pragma unroll
    for (int i = 0; i < 12; i++) P[i] = calib[i];

    float umin = 1e30f, vmin = 1e30f, umax = -1e30f, vmax = -1e30f;
    #pragma unroll
    for (int k = 0; k < 8; k++) {
        float fsx = (k & 4) ? 1.0f : -1.0f;
        float fsy = (k & 2) ? 1.0f : -1.0f;
        float fsz = (k & 1) ? 1.0f : -1.0f;
        float cx = x + fsx * dx * 0.5f;
        float cy = y + fsy * dy * 0.5f;
        float cz = z + fsz * dz * 0.5f;
        float p0 = P[0]*cx + P[1]*cy + P[2]*cz + P[3];
        float p1 = P[4]*cx + P[5]*cy + P[6]*cz + P[7];
        float p2 = P[8]*cx + P[9]*cy + P[10]*cz + P[11];
        float zz = fmaxf(p2, 0.1f);
        float u = p0 / zz, v = p1 / zz;
        umin = fminf(umin, u); umax = fmaxf(umax, u);
        vmin = fminf(vmin, v); vmax = fmaxf(vmax, v);
    }
    float Hf = (float)imshape[0];
    float Wf = (float)imshape[1];
    img_boxes[n*4+0] = fminf(fmaxf(umin, 0.0f), Wf);
    img_boxes[n*4+1] = fminf(fmaxf(vmin, 0.0f), Hf);
    img_boxes[n*4+2] = fminf(fmaxf(umax, 0.0f), Wf);
    img_boxes[n*4+3] = fminf(fmaxf(vmax, 0.0f), Hf);
}

// ---------------- K2a: transpose img chunk [8c][H][W] -> [H][W][8c] ----------
__global__ __launch_bounds__(256) void transpose_img_kernel(
        const float* __restrict__ in, float* __restrict__ out, int c0) {
    __shared__ float lds[64*9];
    int y = blockIdx.y;
    int x0 = blockIdx.x * 64;
    int xl = threadIdx.x & 63;
    int ch = threadIdx.x >> 6;       // 0..3
    int x = x0 + xl;
    #pragma unroll
    for (int i = 0; i < 2; i++) {
        int c = ch + i*4;            // 0..7
        float v = 0.0f;
        if (x < IMG_W)
            v = in[(size_t)(c0+c)*IMG_H*IMG_W + (size_t)y*IMG_W + x];
        lds[xl*9 + c] = v;
    }
    __syncthreads();
    int c8 = threadIdx.x & 7;
    int xp = threadIdx.x >> 3;       // 0..31
    #pragma unroll
    for (int j = 0; j < 2; j++) {
        int xx = x0 + xp + j*32;
        if (xx < IMG_W)
            out[((size_t)y*IMG_W + xx)*8 + c8] = lds[(xp + j*32)*9 + c8];
    }
}

// ---------------- K2b: channel-last img roi (tap-optimized) ----------------
__global__ __launch_bounds__(256) void roi_img_cl_kernel(
        const float* __restrict__ T, const float* __restrict__ img_boxes,
        float* __restrict__ img_out, int c0) {
    int b = blockIdx.x;
    __shared__ float s_xw[S_GRID], s_yw[S_GRID];
    __shared__ int   s_xi[S_GRID], s_yr[S_GRID];
    __shared__ float s_out[8*49];
    int tid = threadIdx.x;
    if (tid < S_GRID) {
        float g = ((float)tid + 0.5f) / (float)S_GRID;
        float bx1 = img_boxes[b*4+0] - 0.5f, by1 = img_boxes[b*4+1] - 0.5f;
        float bx2 = img_boxes[b*4+2] - 0.5f, by2 = img_boxes[b*4+3] - 0.5f;
        float xs = bx1 + g * (bx2 - bx1);
        float x0f = fminf(fmaxf(floorf(xs), 0.0f), (float)(IMG_W-2));
        s_xw[tid] = fminf(fmaxf(xs - x0f, 0.0f), 1.0f);
        s_xi[tid] = (int)x0f * 8;                 // float offset: x*8
        float ys = by1 + g * (by2 - by1);
        float y0f = fminf(fmaxf(floorf(ys), 0.0f), (float)(IMG_H-2));
        s_yw[tid] = fminf(fmaxf(ys - y0f, 0.0f), 1.0f);
        s_yr[tid] = (int)y0f * (IMG_W*8);         // float offset: y*W*8
    }
    __syncthreads();

    int wv   = tid >> 6;
    int lane = tid & 63;
    int sy2 = lane >> 5;
    int sxb = (lane >> 4) & 1;
    int px  = (lane >> 1) & 7;    // 7 is idle
    int c4  = lane & 1;
    bool act = (px < 7);

    for (int pyi = 0; pyi < 2; pyi++) {
        int py = wv + pyi*4;
        if (py > 6) break;
        f32x4 acc = {0.f, 0.f, 0.f, 0.f};
        if (act) {
            #pragma unroll
            for (int t = 0; t < 3; t++) {
                int sy = py*6 + t*2 + sy2;
                int row0 = s_yr[sy];
                float wy = s_yw[sy];
                #pragma unroll
                for (int s = 0; s < 3; s++) {
                    int sx = px*6 + s*2 + sxb;
                    int col = s_xi[sx] + c4*4;
                    const float* p00 = T + row0 + col;
                    f32x4 v00 = *(const f32x4*)(p00);
                    f32x4 v01 = *(const f32x4*)(p00 + 8);
                    f32x4 v10 = *(const f32x4*)(p00 + IMG_W*8);
                    f32x4 v11 = *(const f32x4*)(p00 + IMG_W*8 + 8);
                    float wx = s_xw[sx];
                    #pragma unroll
                    for (int e = 0; e < 4; e++) {
                        float top = fmaf(wx, v01[e] - v00[e], v00[e]);
                        float bot = fmaf(wx, v11[e] - v10[e], v10[e]);
                        acc[e] += fmaf(wy, bot - top, top);
                    }
                }
            }
        }
        #pragma unroll
        for (int e = 0; e < 4; e++) acc[e] += __shfl_xor(acc[e], 32);
        #pragma unroll
        for (int e = 0; e < 4; e++) acc[e] += __shfl_xor(acc[e], 16);
        if (act && sy2 == 0 && sxb == 0) {
            #pragma unroll
            for (int e = 0; e < 4; e++)
                s_out[(c4*4+e)*49 + py*7 + px] = acc[e];
        }
    }
    __syncthreads();
    float* op = img_out + (size_t)b * D_FEAT + c0*49;
    for (int t = tid; t < 8*49; t += 256) op[t] = s_out[t];
}

// ---------------- K2c: bev roi (planar — bev boxes are narrow) -------
__global__ __launch_bounds__(64, 8) void roi_bev_kernel(
        const float* __restrict__ bevF, const float* __restrict__ bev_boxes,
        float* __restrict__ bev_out) {
    int c = blockIdx.x;
    int b = blockIdx.y;
    const int W = BEV_W, H = BEV_H;
    const float* f = bevF + (size_t)c * W * H;

    int lane = threadIdx.x;
    float bx1 = bev_boxes[b*4+0], by1 = bev_boxes[b*4+1];
    float bx2 = bev_boxes[b*4+2], by2 = bev_boxes[b*4+3];

    __shared__ int   s_row0[S_GRID];
    __shared__ float s_wy[S_GRID];

    int x0i = 0;
    float wx = 0.0f;
    if (lane < S_GRID) {
        float g = ((float)lane + 0.5f) / (float)S_GRID;
        float c1 = bx1 - 0.5f, c2 = bx2 - 0.5f;
        float xs = c1 + g * (c2 - c1);
        float x0f = fminf(fmaxf(floorf(xs), 0.0f), (float)(W-2));
        wx = fminf(fmaxf(xs - x0f, 0.0f), 1.0f);
        x0i = (int)x0f;

        float d1 = by1 - 0.5f, d2 = by2 - 0.5f;
        float ys = d1 + g * (d2 - d1);
        float y0f = fminf(fmaxf(floorf(ys), 0.0f), (float)(H-2));
        float wyv = fminf(fmaxf(ys - y0f, 0.0f), 1.0f);
        int y0 = (int)y0f;
        s_row0[lane] = y0 * W;
        s_wy[lane] = wyv;
    }
    __syncthreads();

    float* op = bev_out + (size_t)b * D_FEAT + c * 49;
    #pragma unroll 1
    for (int py = 0; py < ROI; py++) {
        float pl = 0.0f;
        #pragma unroll
        for (int sy = 0; sy < SR; sy++) {
            int yi = py * SR + sy;
            int r0 = s_row0[yi];
            float wy = s_wy[yi];
            if (lane < S_GRID) {
                f32x2u p0 = *(const f32x2u*)(f + r0 + x0i);
                f32x2u p1 = *(const f32x2u*)(f + r0 + W + x0i);
                float top = fmaf(wx, p0.y - p0.x, p0.x);
                float bot = fmaf(wx, p1.y - p1.x, p1.x);
                pl += fmaf(wy, bot - top, top);
            }
        }
        float s = pl;
        #pragma unroll
        for (int k = 1; k < 6; k++) s += __shfl_down(pl, k);
        if (lane < S_GRID && (lane % 6) == 0)
            op[py * ROI + lane / 6] = s;
    }
}

// ---------------- K3: combine masks + split fp32 -> bf16 hi/lo ----------------
__global__ __launch_bounds__(256) void combine_split_kernel(
        const float4* __restrict__ img, const float4* __restrict__ bev,
        const float* __restrict__ img_mask, const float* __restrict__ bev_mask,
        ushort4* __restrict__ outHi, ushort4* __restrict__ outLo, int total4) {
    int i = blockIdx.x * 256 + threadIdx.x;
    if (i >= total4) return;
    float m0 = img_mask[0], m1 = bev_mask[0];
    float inv = 1.0f / ((m0 + m1) * 36.0f);
    float w0 = m0 * inv, w1 = m1 * inv;
    float4 a = img[i], b = bev[i];
    float v[4] = { w0*a.x + w1*b.x, w0*a.y + w1*b.y, w0*a.z + w1*b.z, w0*a.w + w1*b.w };
    ushort4 hv, lv;
    unsigned short* hp = &hv.x;
    unsigned short* lp = &lv.x;
    #pragma unroll
    for (int e = 0; e < 4; e++) {
        unsigned int rh = bf16_rtn(v[e]);
        float lo = v[e] - __uint_as_float(rh << 16);
        hp[e] = (unsigned short)rh;
        lp[e] = (unsigned short)bf16_rtn(lo);
    }
    outHi[i] = hv;
    outLo[i] = lv;
}

// ---------------- K4: bf16x2 MFMA GEMM, C = relu(A@W + bias) ----------------
#define LDK 40   // LDS row stride (shorts); 80B rows keep b128 16B-aligned
template<int EPI>
__global__ __launch_bounds__(256) void gemm_bf16x2_kernel(
        const unsigned short* __restrict__ Ahi, const unsigned short* __restrict__ Alo,
        const float* __restrict__ W, const float* __restrict__ bias, int K,
        unsigned short* __restrict__ outHi, unsigned short* __restrict__ outLo,
        float* __restrict__ outF) {
    __shared__ short AsH[64*LDK], AsL[64*LDK];
    __shared__ short BsH[128*LDK], BsL[128*LDK];

    const int tid = threadIdx.x;
    const int m0 = blockIdx.y * 64, n0 = blockIdx.x * 128;

    const int am = tid >> 2, ac = tid & 3;
    const uint4* ApH = (const uint4*)(Ahi + (size_t)(m0 + am) * K + ac*8);
    const uint4* ApL = (const uint4*)(Alo + (size_t)(m0 + am) * K + ac*8);
    const int nn = tid & 127, rbase = (tid >> 7) * 16;
    const float* Bp = W + (size_t)rbase * 2048 + n0 + nn;

    const int lane = tid & 63, wave = tid >> 6;
    const int wm = wave & 1, wn = wave >> 1;
    const int l15 = lane & 15, quad = lane >> 4;

    f32x4 acc[2][4];
    #pragma unroll
    for (int i = 0; i < 2; i++)
        #pragma unroll
        for (int j = 0; j < 4; j++)
            acc[i][j] = (f32x4){0.f, 0.f, 0.f, 0.f};

    const int nK = K >> 5;
    uint4 aHr = ApH[0];
    uint4 aLr = ApL[0];
    float bReg[16];
    #pragma unroll
    for (int j = 0; j < 16; j++) bReg[j] = Bp[(size_t)j * 2048];

    for (int ks = 0; ks < nK; ks++) {
        __syncthreads();
        *(uint4*)&AsH[am*LDK + ac*8] = aHr;
        *(uint4*)&AsL[am*LDK + ac*8] = aLr;
        {
            unsigned short hv[16], lv[16];
            #pragma unroll
            for (int j = 0; j < 16; j++) {
                unsigned int rh = bf16_rtn(bReg[j]);
                float lo = bReg[j] - __uint_as_float(rh << 16);
                hv[j] = (unsigned short)rh;
                lv[j] = (unsigned short)bf16_rtn(lo);
            }
            *(uint4*)&BsH[nn*LDK + rbase + 0] = *(uint4*)&hv[0];
            *(uint4*)&BsH[nn*LDK + rbase + 8] = *(uint4*)&hv[8];
            *(uint4*)&BsL[nn*LDK + rbase + 0] = *(uint4*)&lv[0];
            *(uint4*)&BsL[nn*LDK + rbase + 8] = *(uint4*)&lv[8];
        }
        __syncthreads();
        if (ks + 1 < nK) {
            int k0n = (ks + 1) * 32;
            aHr = ApH[k0n >> 3];
            aLr = ApL[k0n >> 3];
            #pragma unroll
            for (int j = 0; j < 16; j++) bReg[j] = Bp[(size_t)(k0n + j) * 2048];
        }
        const short* aBH = AsH + (wm*32 + l15)*LDK + quad*8;
        const short* aBL = AsL + (wm*32 + l15)*LDK + quad*8;
        const short* bBH = BsH + (wn*64 + l15)*LDK + quad*8;
        const short* bBL = BsL + (wn*64 + l15)*LDK + quad*8;
        bf16x8 aH0 = *(const bf16x8*)(aBH);
        bf16x8 aH1 = *(const bf16x8*)(aBH + 16*LDK);
        bf16x8 aL0 = *(const bf16x8*)(aBL);
        bf16x8 aL1 = *(const bf16x8*)(aBL + 16*LDK);
        #pragma unroll
        for (int nt = 0; nt < 4; nt++) {
            bf16x8 bH = *(const bf16x8*)(bBH + nt*16*LDK);
            bf16x8 bL = *(const bf16x8*)(bBL + nt*16*LDK);
            acc[0][nt] = __builtin_amdgcn_mfma_f32_16x16x32_bf16(aH0, bH, acc[0][nt], 0, 0, 0);
            acc[0][nt] = __builtin_amdgcn_mfma_f32_16x16x32_bf16(aH0, bL, acc[0][nt], 0, 0, 0);
            acc[0][nt] = __builtin_amdgcn_mfma_f32_16x16x32_bf16(aL0, bH, acc[0][nt], 0, 0, 0);
            acc[1][nt] = __builtin_amdgcn_mfma_f32_16x16x32_bf16(aH1, bH, acc[1][nt], 0, 0, 0);
            acc[1][nt] = __builtin_amdgcn_mfma_f32_16x16x32_bf16(aH1, bL, acc[1][nt], 0, 0, 0);
            acc[1][nt] = __builtin_amdgcn_mfma_f32_16x16x32_bf16(aL1, bH, acc[1][nt], 0, 0, 0);
        }
    }

    #pragma unroll
    for (int mt = 0; mt < 2; mt++) {
        #pragma unroll
        for (int nt = 0; nt < 4; nt++) {
            int n = n0 + wn*64 + nt*16 + l15;
            float bv = bias[n];
            #pragma unroll
            for (int reg = 0; reg < 4; reg++) {
                int m = m0 + wm*32 + mt*16 + quad*4 + reg;
                float v = fmaxf(acc[mt][nt][reg] + bv, 0.0f);
                if (EPI == 1) {
                    unsigned int rh = bf16_rtn(v);
                    float lo = v - __uint_as_float(rh << 16);
                    outHi[(size_t)m * 2048 + n] = (unsigned short)rh;
                    outLo[(size_t)m * 2048 + n] = (unsigned short)bf16_rtn(lo);
                } else {
                    outF[(size_t)m * 2048 + n] = v;
                }
            }
        }
    }
}

// ---------------- K5: heads (obj/off/ang) + postprocess per row ----------------
__global__ __launch_bounds__(256) void heads_kernel(
        const float* __restrict__ h,
        const float* __restrict__ Wc, const float* __restrict__ bc,
        const float* __restrict__ Wo, const float* __restrict__ bo,
        const float* __restrict__ Wa, const float* __restrict__ ba,
        const float* __restrict__ anchors,
        float* __restrict__ obj_soft, float* __restrict__ off_out,
        float* __restrict__ orient, float* __restrict__ pred,
        float* __restrict__ pbev, float* __restrict__ scores) {
    int row = blockIdx.x;
    const float* hr = h + (size_t)row * HID;
    float acc[14];
    #pragma unroll
    for (int j = 0; j < 14; j++) acc[j] = 0.0f;
    for (int k = threadIdx.x; k < HID; k += 256) {
        float hv = hr[k];
        acc[0]  += hv * Wc[k*2+0];
        acc[1]  += hv * Wc[k*2+1];
        #pragma unroll
        for (int j = 0; j < 10; j++) acc[2+j] += hv * Wo[k*10+j];
        acc[12] += hv * Wa[k*2+0];
        acc[13] += hv * Wa[k*2+1];
    }
    #pragma unroll
    for (int d = 32; d > 0; d >>= 1) {
        #pragma unroll
        for (int j = 0; j < 14; j++) acc[j] += __shfl_down(acc[j], d);
    }
    __shared__ float red[4][14];
    int wid = threadIdx.x >> 6, lane = threadIdx.x & 63;
    if (lane == 0) {
        #pragma unroll
        for (int j = 0; j < 14; j++) red[wid][j] = acc[j];
    }
    __syncthreads();
    if (threadIdx.x == 0) {
        float f[14];
        #pragma unroll
        for (int j = 0; j < 14; j++)
            f[j] = red[0][j] + red[1][j] + red[2][j] + red[3][j];
        float obj0 = f[0] + bc[0], obj1 = f[1] + bc[1];
        float offv[10];
        #pragma unroll
        for (int j = 0; j < 10; j++) offv[j] = f[2+j] + bo[j];
        float ang0 = f[12] + ba[0], ang1 = f[13] + ba[1];
        float mx = fmaxf(obj0, obj1);
        float e0 = expf(obj0 - mx), e1 = expf(obj1 - mx);
        float den = e0 + e1;
        obj_soft[row*2+0] = e0 / den;
        obj_soft[row*2+1] = e1 / den;
        scores[row] = obj1;
        orient[row] = atan2f(ang1, ang0);
        float pa[6];
        #pragma unroll
        for (int j = 0; j < 6; j++) {
            pa[j] = anchors[row*6+j] + offv[j];
            pred[row*6+j] = pa[j];
        }
        #pragma unroll
        for (int j = 0; j < 10; j++) off_out[row*10+j] = offv[j];
        float x = pa[0], z = pa[2], ddx = pa[3], ddz = pa[5];
        pbev[row*4+0] = ((x - ddx*0.5f) - (-40.0f)) / 0.1f;
        pbev[row*4+1] = (70.0f - (z + ddz*0.5f)) / 0.1f;
        pbev[row*4+2] = ((x + ddx*0.5f) - (-40.0f)) / 0.1f;
        pbev[row*4+3] = (70.0f - (z - ddz*0.5f)) / 0.1f;
    }
}

// ---------------- K6a: NMS suppression bitmap (parallel) ----------------
// M[i] = 16 u64 words; bit j set iff iou(box_i, box_j) > thr.
// Self-iou = 1 > thr sets the diagonal (replicates s.at[i].set(-inf)).
__global__ __launch_bounds__(256) void nms_mask_kernel(
        const float* __restrict__ boxes, unsigned long long* __restrict__ M) {
    int i = blockIdx.x;
    const float4* bp = (const float4*)boxes;
    float4 bi4 = bp[i];
    float ai = (bi4.z - bi4.x) * (bi4.w - bi4.y);
    int lane = threadIdx.x & 63, wave = threadIdx.x >> 6;
    #pragma unroll
    for (int it = 0; it < 4; it++) {
        int q = it*256 + wave*64 + lane;
        float4 bq = bp[q];
        float aq = (bq.z - bq.x) * (bq.w - bq.y);
        float xx1 = fmaxf(bi4.x, bq.x), yy1 = fmaxf(bi4.y, bq.y);
        float xx2 = fminf(bi4.z, bq.z), yy2 = fminf(bi4.w, bq.w);
        float inter = fmaxf(xx2 - xx1, 0.0f) * fmaxf(yy2 - yy1, 0.0f);
        float iou = inter / (ai + aq - inter + 1e-6f);
        unsigned long long bal = __ballot(iou > NMS_THR);
        if (lane == 0) M[(size_t)i*16 + it*4 + wave] = bal;
    }
}

// ---------------- K6b: sequential scan over bitmap (1 wave) ----------------
// Per step: masked argmax (exact reference tie semantics), then
// rem &= ~M[bi].  No divides / no IoU in the serial loop.
__global__ void nms_scan_kernel(const float* __restrict__ scores_g,
                                const unsigned long long* __restrict__ M,
                                int* __restrict__ idx_out) {
    int lane = threadIdx.x;   // 64 threads
    float sc[16];
    unsigned long long rem[16];
    #pragma unroll
    for (int j = 0; j < 16; j++) {
        sc[j] = scores_g[lane + 64*j];
        rem[j] = ~0ull;
    }
    for (int t = 0; t < NMS_K; t++) {
        // per-lane masked argmax over its 16 boxes (tie -> smaller j = smaller idx)
        float bv = -INFINITY; int bj = 0;
        #pragma unroll
        for (int j = 0; j < 16; j++) {
            float v = ((rem[j] >> lane) & 1ull) ? sc[j] : -INFINITY;
            if (v > bv) { bv = v; bj = j; }
        }
        int bi = lane + 64*bj;
        // butterfly: max value, tie -> min index (matches jnp.argmax; all -inf -> 0)
        #pragma unroll
        for (int d = 1; d < 64; d <<= 1) {
            float ov = __shfl_xor(bv, d);
            int   oi = __shfl_xor(bi, d);
            if (ov > bv || (ov == bv && oi < bi)) { bv = ov; bi = oi; }
        }
        if (lane == 0) idx_out[t] = bi;
        const unsigned long long* row = M + (size_t)bi * 16;
        #pragma unroll
        for (int j = 0; j < 16; j++) rem[j] &= ~row[j];
    }
}

// ---------------- K7: gather outputs ----------------
__global__ void gather_kernel(const int* __restrict__ idx,
                              const float* __restrict__ obj_soft,
                              const float* __restrict__ pred,
                              const float* __restrict__ off,
                              const float* __restrict__ orient,
                              float* __restrict__ out) {
    int i = threadIdx.x;
    if (i < NMS_K) {
        int j = idx[i];
        out[2*i+0] = obj_soft[j*2+0];
        out[2*i+1] = obj_soft[j*2+1];
        #pragma unroll
        for (int t = 0; t < 6; t++) out[200 + 6*i + t] = pred[j*6+t];
        #pragma unroll
        for (int t = 0; t < 10; t++) out[800 + 10*i + t] = off[j*10+t];
        #pragma unroll
        for (int t = 0; t < 6; t++) out[1800 + 7*i + t] = pred[j*6+t];
        out[1800 + 7*i + 6] = 0.0f;
        out[2500 + i] = orient[j];
    }
}

extern "C" void kernel_launch(void* const* d_in, const int* in_sizes, int n_in,
                              void* d_out, int out_size, void* d_ws, size_t ws_size,
                              hipStream_t stream) {
    const float* imgF     = (const float*)d_in[0];
    const float* bevF     = (const float*)d_in[1];
    const float* anchors  = (const float*)d_in[2];
    const float* calib    = (const float*)d_in[3];
    const float* img_mask = (const float*)d_in[5];
    const float* bev_mask = (const float*)d_in[6];
    const float* W1 = (const float*)d_in[7];
    const float* b1 = (const float*)d_in[8];
    const float* W2 = (const float*)d_in[9];
    const float* b2 = (const float*)d_in[10];
    const float* Wc = (const float*)d_in[11];
    const float* bc = (const float*)d_in[12];
    const float* Wo = (const float*)d_in[13];
    const float* bo = (const float*)d_in[14];
    const float* Wa = (const float*)d_in[15];
    const float* ba = (const float*)d_in[16];
    const int* image_shape = (const int*)d_in[17];

    float* ws = (float*)d_ws;
    float* img_boxes = ws + WS_IMG_BOXES;
    float* bev_boxes = ws + WS_BEV_BOXES;
    float* obj_soft  = ws + WS_OBJS;
    float* off       = ws + WS_OFF;
    float* orient    = ws + WS_ORIENT;
    float* pred      = ws + WS_PRED;
    float* pbev      = ws + WS_PBEV;
    float* scores    = ws + WS_SCORES;
    int*   idx       = (int*)(ws + WS_IDX);
    float* img_s     = ws + WS_R0;
    float* bev_s     = ws + WS_R1;
    float* img_t     = ws + WS_IMGT;    // alias of R1+ region; dead before bev roi
    unsigned short* fusedHi = (unsigned short*)(ws + WS_FUSED_HI);
    unsigned short* fusedLo = (unsigned short*)(ws + WS_FUSED_LO);
    unsigned short* h1Hi    = (unsigned short*)(ws + WS_H1HI);
    unsigned short* h1Lo    = (unsigned short*)(ws + WS_H1LO);
    float* h2        = ws + WS_H2;
    unsigned long long* nmsM = (unsigned long long*)(ws + WS_NMSM); // dead h1

    boxes_kernel<<<N_PROP/64, 64, 0, stream>>>(anchors, calib, image_shape,
                                               img_boxes, bev_boxes);
    for (int ch = 0; ch < 4; ch++) {
        transpose_img_kernel<<<dim3((IMG_W+63)/64, IMG_H), 256, 0, stream>>>(
            imgF, img_t, ch*8);
        roi_img_cl_kernel<<<N_PROP, 256, 0, stream>>>(
            img_t, img_boxes, img_s, ch*8);
    }
    roi_bev_kernel<<<dim3(C_FEAT, N_PROP), 64, 0, stream>>>(
        bevF, bev_boxes, bev_s);
    combine_split_kernel<<<(N_PROP*D_FEAT/4 + 255)/256, 256, 0, stream>>>(
        (const float4*)img_s, (const float4*)bev_s, img_mask, bev_mask,
        (ushort4*)fusedHi, (ushort4*)fusedLo, N_PROP*D_FEAT/4);
    gemm_bf16x2_kernel<1><<<dim3(16, 16), 256, 0, stream>>>(
        fusedHi, fusedLo, W1, b1, D_FEAT, h1Hi, h1Lo, nullptr);
    gemm_bf16x2_kernel<0><<<dim3(16, 16), 256, 0, stream>>>(
        h1Hi, h1Lo, W2, b2, HID, nullptr, nullptr, h2);
    heads_kernel<<<N_PROP, 256, 0, stream>>>(h2, Wc, bc, Wo, bo, Wa, ba, anchors,
                                             obj_soft, off, orient, pred, pbev, scores);
    nms_mask_kernel<<<N_PROP, 256, 0, stream>>>(pbev, nmsM);
    nms_scan_kernel<<<1, 64, 0, stream>>>(scores, nmsM, idx);
    gather_kernel<<<1, 128, 0, stream>>>(idx, obj_soft, pred, off, orient,
                                         (float*)d_out);
}

// Round 4
// 594.379 us; speedup vs baseline: 1.2034x; 1.1206x over previous
//
#include <hip/hip_runtime.h>
#include <math.h>

#define N_PROP 1024
#define C_FEAT 32
#define ROI 7
#define SR 6
#define S_GRID 42
#define IMG_H 360
#define IMG_W 1200
#define BEV_H 700
#define BEV_W 800
#define D_FEAT (C_FEAT*ROI*ROI)   // 1568
#define HID 2048
#define NMS_K 100
#define NMS_THR 0.01f

typedef __attribute__((ext_vector_type(8))) short bf16x8;
typedef __attribute__((ext_vector_type(4))) float f32x4;
typedef __attribute__((ext_vector_type(2), aligned(4))) float f32x2u;

// ---------------- workspace layout (float offsets) ----------------
// Peak 5,102,592 floats = 20.4 MB (< 25.3 MB proven).
#define WS_IMG_BOXES 0
#define WS_BEV_BOXES (WS_IMG_BOXES + 4*N_PROP)
#define WS_OBJS      (WS_BEV_BOXES + 4*N_PROP)
#define WS_OFF       (WS_OBJS + 2*N_PROP)
#define WS_ORIENT    (WS_OFF + 10*N_PROP)
#define WS_PRED      (WS_ORIENT + N_PROP)
#define WS_PBEV      (WS_PRED + 6*N_PROP)
#define WS_SCORES    (WS_PBEV + 4*N_PROP)
#define WS_IDX       (WS_SCORES + N_PROP)                // 100 ints
#define WS_SORT      (WS_IDX + 128)                      // 1024 ints, ends 34176 < 40960
#define WS_R0        40960
#define WS_R1        (WS_R0 + N_PROP*D_FEAT)            // 1646592
#define WS_IMGT      WS_R1                               // img_t chunk alias
#define WS_FUSED_HI  (WS_R0 + 2*N_PROP*D_FEAT)          // 3252224
#define WS_FUSED_LO  (WS_FUSED_HI + N_PROP*D_FEAT/2)    // 4055040
#define WS_H1HI      WS_R0
#define WS_H1LO      (WS_R0 + N_PROP*HID/2)
#define WS_H2        (WS_R0 + N_PROP*HID)               // 2138112
#define WS_NMSM      WS_R0                               // u64[1024][16] over dead h1

__device__ __forceinline__ unsigned int bf16_rtn(float x) {
    unsigned int u = __float_as_uint(x);
    return (u + 0x7FFFu + ((u >> 16) & 1u)) >> 16;
}

// ---------------- K1: project boxes ----------------
__global__ void boxes_kernel(const float* __restrict__ anchors,
                             const float* __restrict__ calib,
                             const int* __restrict__ imshape,
                             float* __restrict__ img_boxes,
                             float* __restrict__ bev_boxes) {
    int n = blockIdx.x * blockDim.x + threadIdx.x;
    if (n >= N_PROP) return;
    float x = anchors[n*6+0], y = anchors[n*6+1], z = anchors[n*6+2];
    float dx = anchors[n*6+3], dy = anchors[n*6+4], dz = anchors[n*6+5];

    bev_boxes[n*4+0] = ((x - dx*0.5f) - (-40.0f)) / 0.1f;
    bev_boxes[n*4+1] = (70.0f - (z + dz*0.5f)) / 0.1f;
    bev_boxes[n*4+2] = ((x + dx*0.5f) - (-40.0f)) / 0.1f;
    bev_boxes[n*4+3] = (70.0f - (z - dz*0.5f)) / 0.1f;

    float P[12];
    #pragma unroll
    for (int i = 0; i < 12; i++) P[i] = calib[i];

    float umin = 1e30f, vmin = 1e30f, umax = -1e30f, vmax = -1e30f;
    #pragma unroll
    for (int k = 0; k < 8; k++) {
        float fsx = (k & 4) ? 1.0f : -1.0f;
        float fsy = (k & 2) ? 1.0f : -1.0f;
        float fsz = (k & 1) ? 1.0f : -1.0f;
        float cx = x + fsx * dx * 0.5f;
        float cy = y + fsy * dy * 0.5f;
        float cz = z + fsz * dz * 0.5f;
        float p0 = P[0]*cx + P[1]*cy + P[2]*cz + P[3];
        float p1 = P[4]*cx + P[5]*cy + P[6]*cz + P[7];
        float p2 = P[8]*cx + P[9]*cy + P[10]*cz + P[11];
        float zz = fmaxf(p2, 0.1f);
        float u = p0 / zz, v = p1 / zz;
        umin = fminf(umin, u); umax = fmaxf(umax, u);
        vmin = fminf(vmin, v); vmax = fmaxf(vmax, v);
    }
    float Hf = (float)imshape[0];
    float Wf = (float)imshape[1];
    img_boxes[n*4+0] = fminf(fmaxf(umin, 0.0f), Wf);
    img_boxes[n*4+1] = fminf(fmaxf(vmin, 0.0f), Hf);
    img_boxes[n*4+2] = fminf(fmaxf(umax, 0.0f), Wf);
    img_boxes[n*4+3] = fminf(fmaxf(vmax, 0.0f), Hf);
}

// ---------------- K2a: transpose img chunk [8c][H][W] -> [H][W][8c] ----------
__global__ __launch_bounds__(256) void transpose_img_kernel(
        const float* __restrict__ in, float* __restrict__ out, int c0) {
    __shared__ float lds[64*9];
    int y = blockIdx.y;
    int x0 = blockIdx.x * 64;
    int xl = threadIdx.x & 63;
    int ch = threadIdx.x >> 6;       // 0..3
    int x = x0 + xl;
    #pragma unroll
    for (int i = 0; i < 2; i++) {
        int c = ch + i*4;            // 0..7
        float v = 0.0f;
        if (x < IMG_W)
            v = in[(size_t)(c0+c)*IMG_H*IMG_W + (size_t)y*IMG_W + x];
        lds[xl*9 + c] = v;
    }
    __syncthreads();
    int c8 = threadIdx.x & 7;
    int xp = threadIdx.x >> 3;       // 0..31
    #pragma unroll
    for (int j = 0; j < 2; j++) {
        int xx = x0 + xp + j*32;
        if (xx < IMG_W)
            out[((size_t)y*IMG_W + xx)*8 + c8] = lds[(xp + j*32)*9 + c8];
    }
}

// ---------------- K2b: channel-last img roi (tap-optimized) ----------------
__global__ __launch_bounds__(256) void roi_img_cl_kernel(
        const float* __restrict__ T, const float* __restrict__ img_boxes,
        float* __restrict__ img_out, int c0) {
    int b = blockIdx.x;
    __shared__ float s_xw[S_GRID], s_yw[S_GRID];
    __shared__ int   s_xi[S_GRID], s_yr[S_GRID];
    __shared__ float s_out[8*49];
    int tid = threadIdx.x;
    if (tid < S_GRID) {
        float g = ((float)tid + 0.5f) / (float)S_GRID;
        float bx1 = img_boxes[b*4+0] - 0.5f, by1 = img_boxes[b*4+1] - 0.5f;
        float bx2 = img_boxes[b*4+2] - 0.5f, by2 = img_boxes[b*4+3] - 0.5f;
        float xs = bx1 + g * (bx2 - bx1);
        float x0f = fminf(fmaxf(floorf(xs), 0.0f), (float)(IMG_W-2));
        s_xw[tid] = fminf(fmaxf(xs - x0f, 0.0f), 1.0f);
        s_xi[tid] = (int)x0f * 8;                 // float offset: x*8
        float ys = by1 + g * (by2 - by1);
        float y0f = fminf(fmaxf(floorf(ys), 0.0f), (float)(IMG_H-2));
        s_yw[tid] = fminf(fmaxf(ys - y0f, 0.0f), 1.0f);
        s_yr[tid] = (int)y0f * (IMG_W*8);         // float offset: y*W*8
    }
    __syncthreads();

    int wv   = tid >> 6;
    int lane = tid & 63;
    int sy2 = lane >> 5;
    int sxb = (lane >> 4) & 1;
    int px  = (lane >> 1) & 7;    // 7 is idle
    int c4  = lane & 1;
    bool act = (px < 7);

    for (int pyi = 0; pyi < 2; pyi++) {
        int py = wv + pyi*4;
        if (py > 6) break;
        f32x4 acc = {0.f, 0.f, 0.f, 0.f};
        if (act) {
            #pragma unroll
            for (int t = 0; t < 3; t++) {
                int sy = py*6 + t*2 + sy2;
                int row0 = s_yr[sy];
                float wy = s_yw[sy];
                #pragma unroll
                for (int s = 0; s < 3; s++) {
                    int sx = px*6 + s*2 + sxb;
                    int col = s_xi[sx] + c4*4;
                    const float* p00 = T + row0 + col;
                    f32x4 v00 = *(const f32x4*)(p00);
                    f32x4 v01 = *(const f32x4*)(p00 + 8);
                    f32x4 v10 = *(const f32x4*)(p00 + IMG_W*8);
                    f32x4 v11 = *(const f32x4*)(p00 + IMG_W*8 + 8);
                    float wx = s_xw[sx];
                    #pragma unroll
                    for (int e = 0; e < 4; e++) {
                        float top = fmaf(wx, v01[e] - v00[e], v00[e]);
                        float bot = fmaf(wx, v11[e] - v10[e], v10[e]);
                        acc[e] += fmaf(wy, bot - top, top);
                    }
                }
            }
        }
        #pragma unroll
        for (int e = 0; e < 4; e++) acc[e] += __shfl_xor(acc[e], 32);
        #pragma unroll
        for (int e = 0; e < 4; e++) acc[e] += __shfl_xor(acc[e], 16);
        if (act && sy2 == 0 && sxb == 0) {
            #pragma unroll
            for (int e = 0; e < 4; e++)
                s_out[(c4*4+e)*49 + py*7 + px] = acc[e];
        }
    }
    __syncthreads();
    float* op = img_out + (size_t)b * D_FEAT + c0*49;
    for (int t = tid; t < 8*49; t += 256) op[t] = s_out[t];
}

// ---------------- K2c: bev roi (planar — bev boxes are narrow) -------
__global__ __launch_bounds__(64, 8) void roi_bev_kernel(
        const float* __restrict__ bevF, const float* __restrict__ bev_boxes,
        float* __restrict__ bev_out) {
    int c = blockIdx.x;
    int b = blockIdx.y;
    const int W = BEV_W, H = BEV_H;
    const float* f = bevF + (size_t)c * W * H;

    int lane = threadIdx.x;
    float bx1 = bev_boxes[b*4+0], by1 = bev_boxes[b*4+1];
    float bx2 = bev_boxes[b*4+2], by2 = bev_boxes[b*4+3];

    __shared__ int   s_row0[S_GRID];
    __shared__ float s_wy[S_GRID];

    int x0i = 0;
    float wx = 0.0f;
    if (lane < S_GRID) {
        float g = ((float)lane + 0.5f) / (float)S_GRID;
        float c1 = bx1 - 0.5f, c2 = bx2 - 0.5f;
        float xs = c1 + g * (c2 - c1);
        float x0f = fminf(fmaxf(floorf(xs), 0.0f), (float)(W-2));
        wx = fminf(fmaxf(xs - x0f, 0.0f), 1.0f);
        x0i = (int)x0f;

        float d1 = by1 - 0.5f, d2 = by2 - 0.5f;
        float ys = d1 + g * (d2 - d1);
        float y0f = fminf(fmaxf(floorf(ys), 0.0f), (float)(H-2));
        float wyv = fminf(fmaxf(ys - y0f, 0.0f), 1.0f);
        int y0 = (int)y0f;
        s_row0[lane] = y0 * W;
        s_wy[lane] = wyv;
    }
    __syncthreads();

    float* op = bev_out + (size_t)b * D_FEAT + c * 49;
    #pragma unroll 1
    for (int py = 0; py < ROI; py++) {
        float pl = 0.0f;
        #pragma unroll
        for (int sy = 0; sy < SR; sy++) {
            int yi = py * SR + sy;
            int r0 = s_row0[yi];
            float wy = s_wy[yi];
            if (lane < S_GRID) {
                f32x2u p0 = *(const f32x2u*)(f + r0 + x0i);
                f32x2u p1 = *(const f32x2u*)(f + r0 + W + x0i);
                float top = fmaf(wx, p0.y - p0.x, p0.x);
                float bot = fmaf(wx, p1.y - p1.x, p1.x);
                pl += fmaf(wy, bot - top, top);
            }
        }
        float s = pl;
        #pragma unroll
        for (int k = 1; k < 6; k++) s += __shfl_down(pl, k);
        if (lane < S_GRID && (lane % 6) == 0)
            op[py * ROI + lane / 6] = s;
    }
}

// ---------------- K3: combine masks + split fp32 -> bf16 hi/lo ----------------
__global__ __launch_bounds__(256) void combine_split_kernel(
        const float4* __restrict__ img, const float4* __restrict__ bev,
        const float* __restrict__ img_mask, const float* __restrict__ bev_mask,
        ushort4* __restrict__ outHi, ushort4* __restrict__ outLo, int total4) {
    int i = blockIdx.x * 256 + threadIdx.x;
    if (i >= total4) return;
    float m0 = img_mask[0], m1 = bev_mask[0];
    float inv = 1.0f / ((m0 + m1) * 36.0f);
    float w0 = m0 * inv, w1 = m1 * inv;
    float4 a = img[i], b = bev[i];
    float v[4] = { w0*a.x + w1*b.x, w0*a.y + w1*b.y, w0*a.z + w1*b.z, w0*a.w + w1*b.w };
    ushort4 hv, lv;
    unsigned short* hp = &hv.x;
    unsigned short* lp = &lv.x;
    #pragma unroll
    for (int e = 0; e < 4; e++) {
        unsigned int rh = bf16_rtn(v[e]);
        float lo = v[e] - __uint_as_float(rh << 16);
        hp[e] = (unsigned short)rh;
        lp[e] = (unsigned short)bf16_rtn(lo);
    }
    outHi[i] = hv;
    outLo[i] = lv;
}

// ---------------- K4: bf16x2 MFMA GEMM, C = relu(A@W + bias) ----------------
#define LDK 40   // LDS row stride (shorts); 80B rows keep b128 16B-aligned
template<int EPI>
__global__ __launch_bounds__(256) void gemm_bf16x2_kernel(
        const unsigned short* __restrict__ Ahi, const unsigned short* __restrict__ Alo,
        const float* __restrict__ W, const float* __restrict__ bias, int K,
        unsigned short* __restrict__ outHi, unsigned short* __restrict__ outLo,
        float* __restrict__ outF) {
    __shared__ short AsH[64*LDK], AsL[64*LDK];
    __shared__ short BsH[128*LDK], BsL[128*LDK];

    const int tid = threadIdx.x;
    const int m0 = blockIdx.y * 64, n0 = blockIdx.x * 128;

    const int am = tid >> 2, ac = tid & 3;
    const uint4* ApH = (const uint4*)(Ahi + (size_t)(m0 + am) * K + ac*8);
    const uint4* ApL = (const uint4*)(Alo + (size_t)(m0 + am) * K + ac*8);
    const int nn = tid & 127, rbase = (tid >> 7) * 16;
    const float* Bp = W + (size_t)rbase * 2048 + n0 + nn;

    const int lane = tid & 63, wave = tid >> 6;
    const int wm = wave & 1, wn = wave >> 1;
    const int l15 = lane & 15, quad = lane >> 4;

    f32x4 acc[2][4];
    #pragma unroll
    for (int i = 0; i < 2; i++)
        #pragma unroll
        for (int j = 0; j < 4; j++)
            acc[i][j] = (f32x4){0.f, 0.f, 0.f, 0.f};

    const int nK = K >> 5;
    uint4 aHr = ApH[0];
    uint4 aLr = ApL[0];
    float bReg[16];
    #pragma unroll
    for (int j = 0; j < 16; j++) bReg[j] = Bp[(size_t)j * 2048];

    for (int ks = 0; ks < nK; ks++) {
        __syncthreads();
        *(uint4*)&AsH[am*LDK + ac*8] = aHr;
        *(uint4*)&AsL[am*LDK + ac*8] = aLr;
        {
            unsigned short hv[16], lv[16];
            #pragma unroll
            for (int j = 0; j < 16; j++) {
                unsigned int rh = bf16_rtn(bReg[j]);
                float lo = bReg[j] - __uint_as_float(rh << 16);
                hv[j] = (unsigned short)rh;
                lv[j] = (unsigned short)bf16_rtn(lo);
            }
            *(uint4*)&BsH[nn*LDK + rbase + 0] = *(uint4*)&hv[0];
            *(uint4*)&BsH[nn*LDK + rbase + 8] = *(uint4*)&hv[8];
            *(uint4*)&BsL[nn*LDK + rbase + 0] = *(uint4*)&lv[0];
            *(uint4*)&BsL[nn*LDK + rbase + 8] = *(uint4*)&lv[8];
        }
        __syncthreads();
        if (ks + 1 < nK) {
            int k0n = (ks + 1) * 32;
            aHr = ApH[k0n >> 3];
            aLr = ApL[k0n >> 3];
            #pragma unroll
            for (int j = 0; j < 16; j++) bReg[j] = Bp[(size_t)(k0n + j) * 2048];
        }
        const short* aBH = AsH + (wm*32 + l15)*LDK + quad*8;
        const short* aBL = AsL + (wm*32 + l15)*LDK + quad*8;
        const short* bBH = BsH + (wn*64 + l15)*LDK + quad*8;
        const short* bBL = BsL + (wn*64 + l15)*LDK + quad*8;
        bf16x8 aH0 = *(const bf16x8*)(aBH);
        bf16x8 aH1 = *(const bf16x8*)(aBH + 16*LDK);
        bf16x8 aL0 = *(const bf16x8*)(aBL);
        bf16x8 aL1 = *(const bf16x8*)(aBL + 16*LDK);
        #pragma unroll
        for (int nt = 0; nt < 4; nt++) {
            bf16x8 bH = *(const bf16x8*)(bBH + nt*16*LDK);
            bf16x8 bL = *(const bf16x8*)(bBL + nt*16*LDK);
            acc[0][nt] = __builtin_amdgcn_mfma_f32_16x16x32_bf16(aH0, bH, acc[0][nt], 0, 0, 0);
            acc[0][nt] = __builtin_amdgcn_mfma_f32_16x16x32_bf16(aH0, bL, acc[0][nt], 0, 0, 0);
            acc[0][nt] = __builtin_amdgcn_mfma_f32_16x16x32_bf16(aL0, bH, acc[0][nt], 0, 0, 0);
            acc[1][nt] = __builtin_amdgcn_mfma_f32_16x16x32_bf16(aH1, bH, acc[1][nt], 0, 0, 0);
            acc[1][nt] = __builtin_amdgcn_mfma_f32_16x16x32_bf16(aH1, bL, acc[1][nt], 0, 0, 0);
            acc[1][nt] = __builtin_amdgcn_mfma_f32_16x16x32_bf16(aL1, bH, acc[1][nt], 0, 0, 0);
        }
    }

    #pragma unroll
    for (int mt = 0; mt < 2; mt++) {
        #pragma unroll
        for (int nt = 0; nt < 4; nt++) {
            int n = n0 + wn*64 + nt*16 + l15;
            float bv = bias[n];
            #pragma unroll
            for (int reg = 0; reg < 4; reg++) {
                int m = m0 + wm*32 + mt*16 + quad*4 + reg;
                float v = fmaxf(acc[mt][nt][reg] + bv, 0.0f);
                if (EPI == 1) {
                    unsigned int rh = bf16_rtn(v);
                    float lo = v - __uint_as_float(rh << 16);
                    outHi[(size_t)m * 2048 + n] = (unsigned short)rh;
                    outLo[(size_t)m * 2048 + n] = (unsigned short)bf16_rtn(lo);
                } else {
                    outF[(size_t)m * 2048 + n] = v;
                }
            }
        }
    }
}

// ---------------- K5: heads (obj/off/ang) + postprocess per row ----------------
__global__ __launch_bounds__(256) void heads_kernel(
        const float* __restrict__ h,
        const float* __restrict__ Wc, const float* __restrict__ bc,
        const float* __restrict__ Wo, const float* __restrict__ bo,
        const float* __restrict__ Wa, const float* __restrict__ ba,
        const float* __restrict__ anchors,
        float* __restrict__ obj_soft, float* __restrict__ off_out,
        float* __restrict__ orient, float* __restrict__ pred,
        float* __restrict__ pbev, float* __restrict__ scores) {
    int row = blockIdx.x;
    const float* hr = h + (size_t)row * HID;
    float acc[14];
    #pragma unroll
    for (int j = 0; j < 14; j++) acc[j] = 0.0f;
    for (int k = threadIdx.x; k < HID; k += 256) {
        float hv = hr[k];
        acc[0]  += hv * Wc[k*2+0];
        acc[1]  += hv * Wc[k*2+1];
        #pragma unroll
        for (int j = 0; j < 10; j++) acc[2+j] += hv * Wo[k*10+j];
        acc[12] += hv * Wa[k*2+0];
        acc[13] += hv * Wa[k*2+1];
    }
    #pragma unroll
    for (int d = 32; d > 0; d >>= 1) {
        #pragma unroll
        for (int j = 0; j < 14; j++) acc[j] += __shfl_down(acc[j], d);
    }
    __shared__ float red[4][14];
    int wid = threadIdx.x >> 6, lane = threadIdx.x & 63;
    if (lane == 0) {
        #pragma unroll
        for (int j = 0; j < 14; j++) red[wid][j] = acc[j];
    }
    __syncthreads();
    if (threadIdx.x == 0) {
        float f[14];
        #pragma unroll
        for (int j = 0; j < 14; j++)
            f[j] = red[0][j] + red[1][j] + red[2][j] + red[3][j];
        float obj0 = f[0] + bc[0], obj1 = f[1] + bc[1];
        float offv[10];
        #pragma unroll
        for (int j = 0; j < 10; j++) offv[j] = f[2+j] + bo[j];
        float ang0 = f[12] + ba[0], ang1 = f[13] + ba[1];
        float mx = fmaxf(obj0, obj1);
        float e0 = expf(obj0 - mx), e1 = expf(obj1 - mx);
        float den = e0 + e1;
        obj_soft[row*2+0] = e0 / den;
        obj_soft[row*2+1] = e1 / den;
        scores[row] = obj1;
        orient[row] = atan2f(ang1, ang0);
        float pa[6];
        #pragma unroll
        for (int j = 0; j < 6; j++) {
            pa[j] = anchors[row*6+j] + offv[j];
            pred[row*6+j] = pa[j];
        }
        #pragma unroll
        for (int j = 0; j < 10; j++) off_out[row*10+j] = offv[j];
        float x = pa[0], z = pa[2], ddx = pa[3], ddz = pa[5];
        pbev[row*4+0] = ((x - ddx*0.5f) - (-40.0f)) / 0.1f;
        pbev[row*4+1] = (70.0f - (z + ddz*0.5f)) / 0.1f;
        pbev[row*4+2] = ((x + ddx*0.5f) - (-40.0f)) / 0.1f;
        pbev[row*4+3] = (70.0f - (z - ddz*0.5f)) / 0.1f;
    }
}

// ---------------- K6a: NMS suppression bitmap (parallel) ----------------
// M[i] = 16 u64 words; bit j set iff iou(box_i, box_j) > thr.
__global__ __launch_bounds__(256) void nms_mask_kernel(
        const float* __restrict__ boxes, unsigned long long* __restrict__ M) {
    int i = blockIdx.x;
    const float4* bp = (const float4*)boxes;
    float4 bi4 = bp[i];
    float ai = (bi4.z - bi4.x) * (bi4.w - bi4.y);
    int lane = threadIdx.x & 63, wave = threadIdx.x >> 6;
    #pragma unroll
    for (int it = 0; it < 4; it++) {
        int q = it*256 + wave*64 + lane;
        float4 bq = bp[q];
        float aq = (bq.z - bq.x) * (bq.w - bq.y);
        float xx1 = fmaxf(bi4.x, bq.x), yy1 = fmaxf(bi4.y, bq.y);
        float xx2 = fminf(bi4.z, bq.z), yy2 = fminf(bi4.w, bq.w);
        float inter = fmaxf(xx2 - xx1, 0.0f) * fmaxf(yy2 - yy1, 0.0f);
        float iou = inter / (ai + aq - inter + 1e-6f);
        unsigned long long bal = __ballot(iou > NMS_THR);
        if (lane == 0) M[(size_t)i*16 + it*4 + wave] = bal;
    }
}

// ---------------- K6b: counting-rank sort by (score desc, idx asc) -----------
// key = (sortable(score) << 10) | (1023 - i): strict total order, so
// rank = #{j : key_j > key_i} is a bijection; sorted[rank] = i reproduces
// jnp.argmax's max-value/min-index selection order exactly.
__global__ __launch_bounds__(256) void nms_rank_kernel(
        const float* __restrict__ scores, int* __restrict__ sorted) {
    int i = blockIdx.x;
    unsigned int u = __float_as_uint(scores[i]);
    unsigned int ki = (u & 0x80000000u) ? ~u : (u | 0x80000000u);
    unsigned long long keyi = ((unsigned long long)ki << 10) | (unsigned)(1023 - i);
    int cnt = 0;
    #pragma unroll
    for (int t = 0; t < 4; t++) {
        int j = threadIdx.x + t*256;
        unsigned int uj = __float_as_uint(scores[j]);
        unsigned int kj = (uj & 0x80000000u) ? ~uj : (uj | 0x80000000u);
        unsigned long long keyj = ((unsigned long long)kj << 10) | (unsigned)(1023 - j);
        cnt += (keyj > keyi) ? 1 : 0;
    }
    #pragma unroll
    for (int d = 32; d > 0; d >>= 1) cnt += __shfl_down(cnt, d);
    __shared__ int red[4];
    if ((threadIdx.x & 63) == 0) red[threadIdx.x >> 6] = cnt;
    __syncthreads();
    if (threadIdx.x == 0) sorted[red[0] + red[1] + red[2] + red[3]] = i;
}

// ---------------- K6c: sorted-order greedy scan (1 wave) ----------------
// Visit boxes in descending (score, -idx) order; select iff not yet
// suppressed; suppress via precomputed bitmap rows.  Equivalent to the
// reference's iterative argmax (suppression only removes candidates).
// Fewer than K survivors -> pad with 0 (argmax of all -inf = 0).
__global__ void nms_scan2_kernel(const int* __restrict__ sorted,
                                 const unsigned long long* __restrict__ M,
                                 int* __restrict__ idx_out) {
    int lane = threadIdx.x;            // 64 lanes
    unsigned long long sup = 0ull;     // lanes 0..15 hold suppression words
    int n = 0;
    for (int chunk = 0; chunk < 16 && n < NMS_K; chunk++) {
        int cid = sorted[chunk*64 + lane];
        int cw = cid >> 6, cb = cid & 63;
        unsigned long long supw = __shfl(sup, cw);
        unsigned long long mask = __ballot(((supw >> cb) & 1ull) == 0ull);
        while (mask != 0ull && n < NMS_K) {
            int p = __ffsll(mask) - 1;          // earliest free candidate
            int c = __shfl(cid, p);             // its box id (wave-uniform)
            if (lane == 0) idx_out[n] = c;
            n++;
            unsigned long long roww = (lane < 16) ? M[(size_t)c*16 + lane] : 0ull;
            sup |= roww;
            unsigned long long tw = __shfl(roww, cw);   // row word covering cid
            unsigned long long kill = __ballot(((tw >> cb) & 1ull) != 0ull);
            mask &= ~kill;
            mask &= ~(1ull << p);               // safety: always retire p
        }
    }
    if (lane == 0) {
        for (; n < NMS_K; n++) idx_out[n] = 0;
    }
}

// ---------------- K7: gather outputs ----------------
__global__ void gather_kernel(const int* __restrict__ idx,
                              const float* __restrict__ obj_soft,
                              const float* __restrict__ pred,
                              const float* __restrict__ off,
                              const float* __restrict__ orient,
                              float* __restrict__ out) {
    int i = threadIdx.x;
    if (i < NMS_K) {
        int j = idx[i];
        out[2*i+0] = obj_soft[j*2+0];
        out[2*i+1] = obj_soft[j*2+1];
        #pragma unroll
        for (int t = 0; t < 6; t++) out[200 + 6*i + t] = pred[j*6+t];
        #pragma unroll
        for (int t = 0; t < 10; t++) out[800 + 10*i + t] = off[j*10+t];
        #pragma unroll
        for (int t = 0; t < 6; t++) out[1800 + 7*i + t] = pred[j*6+t];
        out[1800 + 7*i + 6] = 0.0f;
        out[2500 + i] = orient[j];
    }
}

extern "C" void kernel_launch(void* const* d_in, const int* in_sizes, int n_in,
                              void* d_out, int out_size, void* d_ws, size_t ws_size,
                              hipStream_t stream) {
    const float* imgF     = (const float*)d_in[0];
    const float* bevF     = (const float*)d_in[1];
    const float* anchors  = (const float*)d_in[2];
    const float* calib    = (const float*)d_in[3];
    const float* img_mask = (const float*)d_in[5];
    const float* bev_mask = (const float*)d_in[6];
    const float* W1 = (const float*)d_in[7];
    const float* b1 = (const float*)d_in[8];
    const float* W2 = (const float*)d_in[9];
    const float* b2 = (const float*)d_in[10];
    const float* Wc = (const float*)d_in[11];
    const float* bc = (const float*)d_in[12];
    const float* Wo = (const float*)d_in[13];
    const float* bo = (const float*)d_in[14];
    const float* Wa = (const float*)d_in[15];
    const float* ba = (const float*)d_in[16];
    const int* image_shape = (const int*)d_in[17];

    float* ws = (float*)d_ws;
    float* img_boxes = ws + WS_IMG_BOXES;
    float* bev_boxes = ws + WS_BEV_BOXES;
    float* obj_soft  = ws + WS_OBJS;
    float* off       = ws + WS_OFF;
    float* orient    = ws + WS_ORIENT;
    float* pred      = ws + WS_PRED;
    float* pbev      = ws + WS_PBEV;
    float* scores    = ws + WS_SCORES;
    int*   idx       = (int*)(ws + WS_IDX);
    int*   sorted    = (int*)(ws + WS_SORT);
    float* img_s     = ws + WS_R0;
    float* bev_s     = ws + WS_R1;
    float* img_t     = ws + WS_IMGT;    // alias of R1+ region; dead before bev roi
    unsigned short* fusedHi = (unsigned short*)(ws + WS_FUSED_HI);
    unsigned short* fusedLo = (unsigned short*)(ws + WS_FUSED_LO);
    unsigned short* h1Hi    = (unsigned short*)(ws + WS_H1HI);
    unsigned short* h1Lo    = (unsigned short*)(ws + WS_H1LO);
    float* h2        = ws + WS_H2;
    unsigned long long* nmsM = (unsigned long long*)(ws + WS_NMSM); // dead h1

    boxes_kernel<<<N_PROP/64, 64, 0, stream>>>(anchors, calib, image_shape,
                                               img_boxes, bev_boxes);
    for (int ch = 0; ch < 4; ch++) {
        transpose_img_kernel<<<dim3((IMG_W+63)/64, IMG_H), 256, 0, stream>>>(
            imgF, img_t, ch*8);
        roi_img_cl_kernel<<<N_PROP, 256, 0, stream>>>(
            img_t, img_boxes, img_s, ch*8);
    }
    roi_bev_kernel<<<dim3(C_FEAT, N_PROP), 64, 0, stream>>>(
        bevF, bev_boxes, bev_s);
    combine_split_kernel<<<(N_PROP*D_FEAT/4 + 255)/256, 256, 0, stream>>>(
        (const float4*)img_s, (const float4*)bev_s, img_mask, bev_mask,
        (ushort4*)fusedHi, (ushort4*)fusedLo, N_PROP*D_FEAT/4);
    gemm_bf16x2_kernel<1><<<dim3(16, 16), 256, 0, stream>>>(
        fusedHi, fusedLo, W1, b1, D_FEAT, h1Hi, h1Lo, nullptr);
    gemm_bf16x2_kernel<0><<<dim3(16, 16), 256, 0, stream>>>(
        h1Hi, h1Lo, W2, b2, HID, nullptr, nullptr, h2);
    heads_kernel<<<N_PROP, 256, 0, stream>>>(h2, Wc, bc, Wo, bo, Wa, ba, anchors,
                                             obj_soft, off, orient, pred, pbev, scores);
    nms_mask_kernel<<<N_PROP, 256, 0, stream>>>(pbev, nmsM);
    nms_rank_kernel<<<N_PROP, 256, 0, stream>>>(scores, sorted);
    nms_scan2_kernel<<<1, 64, 0, stream>>>(sorted, nmsM, idx);
    gather_kernel<<<1, 128, 0, stream>>>(idx, obj_soft, pred, off, orient,
                                         (float*)d_out);
}

// Round 5
// 591.197 us; speedup vs baseline: 1.2099x; 1.0054x over previous
//
#include <hip/hip_runtime.h>
#include <math.h>

#define N_PROP 1024
#define C_FEAT 32
#define ROI 7
#define SR 6
#define S_GRID 42
#define IMG_H 360
#define IMG_W 1200
#define BEV_H 700
#define BEV_W 800
#define D_FEAT (C_FEAT*ROI*ROI)   // 1568
#define HID 2048
#define NMS_K 100
#define NMS_THR 0.01f
#define CHPB 8   // bev channels per block

typedef __attribute__((ext_vector_type(8))) short bf16x8;
typedef __attribute__((ext_vector_type(4))) float f32x4;
typedef __attribute__((ext_vector_type(2), aligned(4))) float f32x2u;

// ---------------- workspace layout (float offsets) ----------------
// Peak 5,102,592 floats = 20.4 MB (< 25.3 MB proven).
#define WS_IMG_BOXES 0
#define WS_BEV_BOXES (WS_IMG_BOXES + 4*N_PROP)
#define WS_OBJS      (WS_BEV_BOXES + 4*N_PROP)
#define WS_OFF       (WS_OBJS + 2*N_PROP)
#define WS_ORIENT    (WS_OFF + 10*N_PROP)
#define WS_PRED      (WS_ORIENT + N_PROP)
#define WS_PBEV      (WS_PRED + 6*N_PROP)
#define WS_SCORES    (WS_PBEV + 4*N_PROP)
#define WS_IDX       (WS_SCORES + N_PROP)                // 100 ints
#define WS_SORT      (WS_IDX + 128)                      // 1024 ints
#define WS_R0        40960
#define WS_R1        (WS_R0 + N_PROP*D_FEAT)            // 1646592
#define WS_IMGT      WS_R1                               // img_t chunk alias
#define WS_FUSED_HI  (WS_R0 + 2*N_PROP*D_FEAT)          // 3252224
#define WS_FUSED_LO  (WS_FUSED_HI + N_PROP*D_FEAT/2)    // 4055040
#define WS_H1HI      WS_R0
#define WS_H1LO      (WS_R0 + N_PROP*HID/2)
#define WS_H2        (WS_R0 + N_PROP*HID)               // 2138112
#define WS_NMSM      WS_R0                               // u64[1024][16] over dead h1

__device__ __forceinline__ unsigned int bf16_rtn(float x) {
    unsigned int u = __float_as_uint(x);
    return (u + 0x7FFFu + ((u >> 16) & 1u)) >> 16;
}

// ---------------- K1: project boxes ----------------
__global__ void boxes_kernel(const float* __restrict__ anchors,
                             const float* __restrict__ calib,
                             const int* __restrict__ imshape,
                             float* __restrict__ img_boxes,
                             float* __restrict__ bev_boxes) {
    int n = blockIdx.x * blockDim.x + threadIdx.x;
    if (n >= N_PROP) return;
    float x = anchors[n*6+0], y = anchors[n*6+1], z = anchors[n*6+2];
    float dx = anchors[n*6+3], dy = anchors[n*6+4], dz = anchors[n*6+5];

    bev_boxes[n*4+0] = ((x - dx*0.5f) - (-40.0f)) / 0.1f;
    bev_boxes[n*4+1] = (70.0f - (z + dz*0.5f)) / 0.1f;
    bev_boxes[n*4+2] = ((x + dx*0.5f) - (-40.0f)) / 0.1f;
    bev_boxes[n*4+3] = (70.0f - (z - dz*0.5f)) / 0.1f;

    float P[12];
    #pragma unroll
    for (int i = 0; i < 12; i++) P[i] = calib[i];

    float umin = 1e30f, vmin = 1e30f, umax = -1e30f, vmax = -1e30f;
    #pragma unroll
    for (int k = 0; k < 8; k++) {
        float fsx = (k & 4) ? 1.0f : -1.0f;
        float fsy = (k & 2) ? 1.0f : -1.0f;
        float fsz = (k & 1) ? 1.0f : -1.0f;
        float cx = x + fsx * dx * 0.5f;
        float cy = y + fsy * dy * 0.5f;
        float cz = z + fsz * dz * 0.5f;
        float p0 = P[0]*cx + P[1]*cy + P[2]*cz + P[3];
        float p1 = P[4]*cx + P[5]*cy + P[6]*cz + P[7];
        float p2 = P[8]*cx + P[9]*cy + P[10]*cz + P[11];
        float zz = fmaxf(p2, 0.1f);
        float u = p0 / zz, v = p1 / zz;
        umin = fminf(umin, u); umax = fmaxf(umax, u);
        vmin = fminf(vmin, v); vmax = fmaxf(vmax, v);
    }
    float Hf = (float)imshape[0];
    float Wf = (float)imshape[1];
    img_boxes[n*4+0] = fminf(fmaxf(umin, 0.0f), Wf);
    img_boxes[n*4+1] = fminf(fmaxf(vmin, 0.0f), Hf);
    img_boxes[n*4+2] = fminf(fmaxf(umax, 0.0f), Wf);
    img_boxes[n*4+3] = fminf(fmaxf(vmax, 0.0f), Hf);
}

// ---------------- K2a: transpose img chunk [8c][H][W] -> [H][W][8c] ----------
__global__ __launch_bounds__(256) void transpose_img_kernel(
        const float* __restrict__ in, float* __restrict__ out, int c0) {
    __shared__ float lds[64*9];
    int y = blockIdx.y;
    int x0 = blockIdx.x * 64;
    int xl = threadIdx.x & 63;
    int ch = threadIdx.x >> 6;       // 0..3
    int x = x0 + xl;
    #pragma unroll
    for (int i = 0; i < 2; i++) {
        int c = ch + i*4;            // 0..7
        float v = 0.0f;
        if (x < IMG_W)
            v = in[(size_t)(c0+c)*IMG_H*IMG_W + (size_t)y*IMG_W + x];
        lds[xl*9 + c] = v;
    }
    __syncthreads();
    int c8 = threadIdx.x & 7;
    int xp = threadIdx.x >> 3;       // 0..31
    #pragma unroll
    for (int j = 0; j < 2; j++) {
        int xx = x0 + xp + j*32;
        if (xx < IMG_W)
            out[((size_t)y*IMG_W + xx)*8 + c8] = lds[(xp + j*32)*9 + c8];
    }
}

// ---------------- K2b: channel-last img roi (tap-optimized) ----------------
__global__ __launch_bounds__(256) void roi_img_cl_kernel(
        const float* __restrict__ T, const float* __restrict__ img_boxes,
        float* __restrict__ img_out, int c0) {
    int b = blockIdx.x;
    __shared__ float s_xw[S_GRID], s_yw[S_GRID];
    __shared__ int   s_xi[S_GRID], s_yr[S_GRID];
    __shared__ float s_out[8*49];
    int tid = threadIdx.x;
    if (tid < S_GRID) {
        float g = ((float)tid + 0.5f) / (float)S_GRID;
        float bx1 = img_boxes[b*4+0] - 0.5f, by1 = img_boxes[b*4+1] - 0.5f;
        float bx2 = img_boxes[b*4+2] - 0.5f, by2 = img_boxes[b*4+3] - 0.5f;
        float xs = bx1 + g * (bx2 - bx1);
        float x0f = fminf(fmaxf(floorf(xs), 0.0f), (float)(IMG_W-2));
        s_xw[tid] = fminf(fmaxf(xs - x0f, 0.0f), 1.0f);
        s_xi[tid] = (int)x0f * 8;                 // float offset: x*8
        float ys = by1 + g * (by2 - by1);
        float y0f = fminf(fmaxf(floorf(ys), 0.0f), (float)(IMG_H-2));
        s_yw[tid] = fminf(fmaxf(ys - y0f, 0.0f), 1.0f);
        s_yr[tid] = (int)y0f * (IMG_W*8);         // float offset: y*W*8
    }
    __syncthreads();

    int wv   = tid >> 6;
    int lane = tid & 63;
    int sy2 = lane >> 5;
    int sxb = (lane >> 4) & 1;
    int px  = (lane >> 1) & 7;    // 7 is idle
    int c4  = lane & 1;
    bool act = (px < 7);

    for (int pyi = 0; pyi < 2; pyi++) {
        int py = wv + pyi*4;
        if (py > 6) break;
        f32x4 acc = {0.f, 0.f, 0.f, 0.f};
        if (act) {
            #pragma unroll
            for (int t = 0; t < 3; t++) {
                int sy = py*6 + t*2 + sy2;
                int row0 = s_yr[sy];
                float wy = s_yw[sy];
                #pragma unroll
                for (int s = 0; s < 3; s++) {
                    int sx = px*6 + s*2 + sxb;
                    int col = s_xi[sx] + c4*4;
                    const float* p00 = T + row0 + col;
                    f32x4 v00 = *(const f32x4*)(p00);
                    f32x4 v01 = *(const f32x4*)(p00 + 8);
                    f32x4 v10 = *(const f32x4*)(p00 + IMG_W*8);
                    f32x4 v11 = *(const f32x4*)(p00 + IMG_W*8 + 8);
                    float wx = s_xw[sx];
                    #pragma unroll
                    for (int e = 0; e < 4; e++) {
                        float top = fmaf(wx, v01[e] - v00[e], v00[e]);
                        float bot = fmaf(wx, v11[e] - v10[e], v10[e]);
                        acc[e] += fmaf(wy, bot - top, top);
                    }
                }
            }
        }
        #pragma unroll
        for (int e = 0; e < 4; e++) acc[e] += __shfl_xor(acc[e], 32);
        #pragma unroll
        for (int e = 0; e < 4; e++) acc[e] += __shfl_xor(acc[e], 16);
        if (act && sy2 == 0 && sxb == 0) {
            #pragma unroll
            for (int e = 0; e < 4; e++)
                s_out[(c4*4+e)*49 + py*7 + px] = acc[e];
        }
    }
    __syncthreads();
    float* op = img_out + (size_t)b * D_FEAT + c0*49;
    for (int t = tid; t < 8*49; t += 256) op[t] = s_out[t];
}

// ---------------- K2c: bev roi, 8 channels/block, 2-channel ILP ----------
// R8: previous 1-channel blocks were L2-miss-latency bound (~12 loads in
// flight/wave, VALUBusy 29%).  One box's sample geometry now serves 8
// channels; inner loop runs 2 channels at once -> 4 independent loads per
// (py,sy) step and a long per-wave load stream.  Same fmaf/reduce order.
__global__ __launch_bounds__(64, 8) void roi_bev_kernel(
        const float* __restrict__ bevF, const float* __restrict__ bev_boxes,
        float* __restrict__ bev_out) {
    int chunk = blockIdx.x;          // 0..3
    int b = blockIdx.y;
    int c0 = chunk * CHPB;
    const int W = BEV_W, H = BEV_H;

    int lane = threadIdx.x;
    float bx1 = bev_boxes[b*4+0], by1 = bev_boxes[b*4+1];
    float bx2 = bev_boxes[b*4+2], by2 = bev_boxes[b*4+3];

    __shared__ int   s_row0[S_GRID];
    __shared__ float s_wy[S_GRID];

    int x0i = 0;
    float wx = 0.0f;
    if (lane < S_GRID) {
        float g = ((float)lane + 0.5f) / (float)S_GRID;
        float c1 = bx1 - 0.5f, c2 = bx2 - 0.5f;
        float xs = c1 + g * (c2 - c1);
        float x0f = fminf(fmaxf(floorf(xs), 0.0f), (float)(W-2));
        wx = fminf(fmaxf(xs - x0f, 0.0f), 1.0f);
        x0i = (int)x0f;

        float d1 = by1 - 0.5f, d2 = by2 - 0.5f;
        float ys = d1 + g * (d2 - d1);
        float y0f = fminf(fmaxf(floorf(ys), 0.0f), (float)(H-2));
        float wyv = fminf(fmaxf(ys - y0f, 0.0f), 1.0f);
        int y0 = (int)y0f;
        s_row0[lane] = y0 * W;
        s_wy[lane] = wyv;
    }
    __syncthreads();

    float* opb = bev_out + (size_t)b * D_FEAT + c0*49;
    #pragma unroll 1
    for (int cc = 0; cc < CHPB; cc += 2) {
        const float* f0 = bevF + (size_t)(c0 + cc) * W * H;
        const float* f1 = f0 + (size_t)W * H;
        #pragma unroll 1
        for (int py = 0; py < ROI; py++) {
            float pl0 = 0.0f, pl1 = 0.0f;
            #pragma unroll
            for (int sy = 0; sy < SR; sy++) {
                int yi = py * SR + sy;
                int r0 = s_row0[yi];
                float wy = s_wy[yi];
                if (lane < S_GRID) {
                    f32x2u a0 = *(const f32x2u*)(f0 + r0 + x0i);
                    f32x2u a1 = *(const f32x2u*)(f0 + r0 + W + x0i);
                    f32x2u b0 = *(const f32x2u*)(f1 + r0 + x0i);
                    f32x2u b1 = *(const f32x2u*)(f1 + r0 + W + x0i);
                    float t0 = fmaf(wx, a0.y - a0.x, a0.x);
                    float u0 = fmaf(wx, a1.y - a1.x, a1.x);
                    pl0 += fmaf(wy, u0 - t0, t0);
                    float t1 = fmaf(wx, b0.y - b0.x, b0.x);
                    float u1 = fmaf(wx, b1.y - b1.x, b1.x);
                    pl1 += fmaf(wy, u1 - t1, t1);
                }
            }
            float s0 = pl0, s1 = pl1;
            #pragma unroll
            for (int k = 1; k < 6; k++) {
                s0 += __shfl_down(pl0, k);
                s1 += __shfl_down(pl1, k);
            }
            if (lane < S_GRID && (lane % 6) == 0) {
                opb[cc*49 + py*ROI + lane/6] = s0;
                opb[(cc+1)*49 + py*ROI + lane/6] = s1;
            }
        }
    }
}

// ---------------- K3: combine masks + split fp32 -> bf16 hi/lo ----------------
__global__ __launch_bounds__(256) void combine_split_kernel(
        const float4* __restrict__ img, const float4* __restrict__ bev,
        const float* __restrict__ img_mask, const float* __restrict__ bev_mask,
        ushort4* __restrict__ outHi, ushort4* __restrict__ outLo, int total4) {
    int i = blockIdx.x * 256 + threadIdx.x;
    if (i >= total4) return;
    float m0 = img_mask[0], m1 = bev_mask[0];
    float inv = 1.0f / ((m0 + m1) * 36.0f);
    float w0 = m0 * inv, w1 = m1 * inv;
    float4 a = img[i], b = bev[i];
    float v[4] = { w0*a.x + w1*b.x, w0*a.y + w1*b.y, w0*a.z + w1*b.z, w0*a.w + w1*b.w };
    ushort4 hv, lv;
    unsigned short* hp = &hv.x;
    unsigned short* lp = &lv.x;
    #pragma unroll
    for (int e = 0; e < 4; e++) {
        unsigned int rh = bf16_rtn(v[e]);
        float lo = v[e] - __uint_as_float(rh << 16);
        hp[e] = (unsigned short)rh;
        lp[e] = (unsigned short)bf16_rtn(lo);
    }
    outHi[i] = hv;
    outLo[i] = lv;
}

// ---------------- K4: bf16x2 MFMA GEMM, C = relu(A@W + bias) ----------------
#define LDK 40   // LDS row stride (shorts); 80B rows keep b128 16B-aligned
template<int EPI>
__global__ __launch_bounds__(256) void gemm_bf16x2_kernel(
        const unsigned short* __restrict__ Ahi, const unsigned short* __restrict__ Alo,
        const float* __restrict__ W, const float* __restrict__ bias, int K,
        unsigned short* __restrict__ outHi, unsigned short* __restrict__ outLo,
        float* __restrict__ outF) {
    __shared__ short AsH[64*LDK], AsL[64*LDK];
    __shared__ short BsH[128*LDK], BsL[128*LDK];

    const int tid = threadIdx.x;
    const int m0 = blockIdx.y * 64, n0 = blockIdx.x * 128;

    const int am = tid >> 2, ac = tid & 3;
    const uint4* ApH = (const uint4*)(Ahi + (size_t)(m0 + am) * K + ac*8);
    const uint4* ApL = (const uint4*)(Alo + (size_t)(m0 + am) * K + ac*8);
    const int nn = tid & 127, rbase = (tid >> 7) * 16;
    const float* Bp = W + (size_t)rbase * 2048 + n0 + nn;

    const int lane = tid & 63, wave = tid >> 6;
    const int wm = wave & 1, wn = wave >> 1;
    const int l15 = lane & 15, quad = lane >> 4;

    f32x4 acc[2][4];
    #pragma unroll
    for (int i = 0; i < 2; i++)
        #pragma unroll
        for (int j = 0; j < 4; j++)
            acc[i][j] = (f32x4){0.f, 0.f, 0.f, 0.f};

    const int nK = K >> 5;
    uint4 aHr = ApH[0];
    uint4 aLr = ApL[0];
    float bReg[16];
    #pragma unroll
    for (int j = 0; j < 16; j++) bReg[j] = Bp[(size_t)j * 2048];

    for (int ks = 0; ks < nK; ks++) {
        __syncthreads();
        *(uint4*)&AsH[am*LDK + ac*8] = aHr;
        *(uint4*)&AsL[am*LDK + ac*8] = aLr;
        {
            unsigned short hv[16], lv[16];
            #pragma unroll
            for (int j = 0; j < 16; j++) {
                unsigned int rh = bf16_rtn(bReg[j]);
                float lo = bReg[j] - __uint_as_float(rh << 16);
                hv[j] = (unsigned short)rh;
                lv[j] = (unsigned short)bf16_rtn(lo);
            }
            *(uint4*)&BsH[nn*LDK + rbase + 0] = *(uint4*)&hv[0];
            *(uint4*)&BsH[nn*LDK + rbase + 8] = *(uint4*)&hv[8];
            *(uint4*)&BsL[nn*LDK + rbase + 0] = *(uint4*)&lv[0];
            *(uint4*)&BsL[nn*LDK + rbase + 8] = *(uint4*)&lv[8];
        }
        __syncthreads();
        if (ks + 1 < nK) {
            int k0n = (ks + 1) * 32;
            aHr = ApH[k0n >> 3];
            aLr = ApL[k0n >> 3];
            #pragma unroll
            for (int j = 0; j < 16; j++) bReg[j] = Bp[(size_t)(k0n + j) * 2048];
        }
        const short* aBH = AsH + (wm*32 + l15)*LDK + quad*8;
        const short* aBL = AsL + (wm*32 + l15)*LDK + quad*8;
        const short* bBH = BsH + (wn*64 + l15)*LDK + quad*8;
        const short* bBL = BsL + (wn*64 + l15)*LDK + quad*8;
        bf16x8 aH0 = *(const bf16x8*)(aBH);
        bf16x8 aH1 = *(const bf16x8*)(aBH + 16*LDK);
        bf16x8 aL0 = *(const bf16x8*)(aBL);
        bf16x8 aL1 = *(const bf16x8*)(aBL + 16*LDK);
        #pragma unroll
        for (int nt = 0; nt < 4; nt++) {
            bf16x8 bH = *(const bf16x8*)(bBH + nt*16*LDK);
            bf16x8 bL = *(const bf16x8*)(bBL + nt*16*LDK);
            acc[0][nt] = __builtin_amdgcn_mfma_f32_16x16x32_bf16(aH0, bH, acc[0][nt], 0, 0, 0);
            acc[0][nt] = __builtin_amdgcn_mfma_f32_16x16x32_bf16(aH0, bL, acc[0][nt], 0, 0, 0);
            acc[0][nt] = __builtin_amdgcn_mfma_f32_16x16x32_bf16(aL0, bH, acc[0][nt], 0, 0, 0);
            acc[1][nt] = __builtin_amdgcn_mfma_f32_16x16x32_bf16(aH1, bH, acc[1][nt], 0, 0, 0);
            acc[1][nt] = __builtin_amdgcn_mfma_f32_16x16x32_bf16(aH1, bL, acc[1][nt], 0, 0, 0);
            acc[1][nt] = __builtin_amdgcn_mfma_f32_16x16x32_bf16(aL1, bH, acc[1][nt], 0, 0, 0);
        }
    }

    #pragma unroll
    for (int mt = 0; mt < 2; mt++) {
        #pragma unroll
        for (int nt = 0; nt < 4; nt++) {
            int n = n0 + wn*64 + nt*16 + l15;
            float bv = bias[n];
            #pragma unroll
            for (int reg = 0; reg < 4; reg++) {
                int m = m0 + wm*32 + mt*16 + quad*4 + reg;
                float v = fmaxf(acc[mt][nt][reg] + bv, 0.0f);
                if (EPI == 1) {
                    unsigned int rh = bf16_rtn(v);
                    float lo = v - __uint_as_float(rh << 16);
                    outHi[(size_t)m * 2048 + n] = (unsigned short)rh;
                    outLo[(size_t)m * 2048 + n] = (unsigned short)bf16_rtn(lo);
                } else {
                    outF[(size_t)m * 2048 + n] = v;
                }
            }
        }
    }
}

// ---------------- K5: heads (obj/off/ang) + postprocess per row ----------------
__global__ __launch_bounds__(256) void heads_kernel(
        const float* __restrict__ h,
        const float* __restrict__ Wc, const float* __restrict__ bc,
        const float* __restrict__ Wo, const float* __restrict__ bo,
        const float* __restrict__ Wa, const float* __restrict__ ba,
        const float* __restrict__ anchors,
        float* __restrict__ obj_soft, float* __restrict__ off_out,
        float* __restrict__ orient, float* __restrict__ pred,
        float* __restrict__ pbev, float* __restrict__ scores) {
    int row = blockIdx.x;
    const float* hr = h + (size_t)row * HID;
    float acc[14];
    #pragma unroll
    for (int j = 0; j < 14; j++) acc[j] = 0.0f;
    for (int k = threadIdx.x; k < HID; k += 256) {
        float hv = hr[k];
        acc[0]  += hv * Wc[k*2+0];
        acc[1]  += hv * Wc[k*2+1];
        #pragma unroll
        for (int j = 0; j < 10; j++) acc[2+j] += hv * Wo[k*10+j];
        acc[12] += hv * Wa[k*2+0];
        acc[13] += hv * Wa[k*2+1];
    }
    #pragma unroll
    for (int d = 32; d > 0; d >>= 1) {
        #pragma unroll
        for (int j = 0; j < 14; j++) acc[j] += __shfl_down(acc[j], d);
    }
    __shared__ float red[4][14];
    int wid = threadIdx.x >> 6, lane = threadIdx.x & 63;
    if (lane == 0) {
        #pragma unroll
        for (int j = 0; j < 14; j++) red[wid][j] = acc[j];
    }
    __syncthreads();
    if (threadIdx.x == 0) {
        float f[14];
        #pragma unroll
        for (int j = 0; j < 14; j++)
            f[j] = red[0][j] + red[1][j] + red[2][j] + red[3][j];
        float obj0 = f[0] + bc[0], obj1 = f[1] + bc[1];
        float offv[10];
        #pragma unroll
        for (int j = 0; j < 10; j++) offv[j] = f[2+j] + bo[j];
        float ang0 = f[12] + ba[0], ang1 = f[13] + ba[1];
        float mx = fmaxf(obj0, obj1);
        float e0 = expf(obj0 - mx), e1 = expf(obj1 - mx);
        float den = e0 + e1;
        obj_soft[row*2+0] = e0 / den;
        obj_soft[row*2+1] = e1 / den;
        scores[row] = obj1;
        orient[row] = atan2f(ang1, ang0);
        float pa[6];
        #pragma unroll
        for (int j = 0; j < 6; j++) {
            pa[j] = anchors[row*6+j] + offv[j];
            pred[row*6+j] = pa[j];
        }
        #pragma unroll
        for (int j = 0; j < 10; j++) off_out[row*10+j] = offv[j];
        float x = pa[0], z = pa[2], ddx = pa[3], ddz = pa[5];
        pbev[row*4+0] = ((x - ddx*0.5f) - (-40.0f)) / 0.1f;
        pbev[row*4+1] = (70.0f - (z + ddz*0.5f)) / 0.1f;
        pbev[row*4+2] = ((x + ddx*0.5f) - (-40.0f)) / 0.1f;
        pbev[row*4+3] = (70.0f - (z - ddz*0.5f)) / 0.1f;
    }
}

// ---------------- K6a: NMS suppression bitmap (parallel) ----------------
__global__ __launch_bounds__(256) void nms_mask_kernel(
        const float* __restrict__ boxes, unsigned long long* __restrict__ M) {
    int i = blockIdx.x;
    const float4* bp = (const float4*)boxes;
    float4 bi4 = bp[i];
    float ai = (bi4.z - bi4.x) * (bi4.w - bi4.y);
    int lane = threadIdx.x & 63, wave = threadIdx.x >> 6;
    #pragma unroll
    for (int it = 0; it < 4; it++) {
        int q = it*256 + wave*64 + lane;
        float4 bq = bp[q];
        float aq = (bq.z - bq.x) * (bq.w - bq.y);
        float xx1 = fmaxf(bi4.x, bq.x), yy1 = fmaxf(bi4.y, bq.y);
        float xx2 = fminf(bi4.z, bq.z), yy2 = fminf(bi4.w, bq.w);
        float inter = fmaxf(xx2 - xx1, 0.0f) * fmaxf(yy2 - yy1, 0.0f);
        float iou = inter / (ai + aq - inter + 1e-6f);
        unsigned long long bal = __ballot(iou > NMS_THR);
        if (lane == 0) M[(size_t)i*16 + it*4 + wave] = bal;
    }
}

// ---------------- K6b: counting-rank sort by (score desc, idx asc) -----------
__global__ __launch_bounds__(256) void nms_rank_kernel(
        const float* __restrict__ scores, int* __restrict__ sorted) {
    int i = blockIdx.x;
    unsigned int u = __float_as_uint(scores[i]);
    unsigned int ki = (u & 0x80000000u) ? ~u : (u | 0x80000000u);
    unsigned long long keyi = ((unsigned long long)ki << 10) | (unsigned)(1023 - i);
    int cnt = 0;
    #pragma unroll
    for (int t = 0; t < 4; t++) {
        int j = threadIdx.x + t*256;
        unsigned int uj = __float_as_uint(scores[j]);
        unsigned int kj = (uj & 0x80000000u) ? ~uj : (uj | 0x80000000u);
        unsigned long long keyj = ((unsigned long long)kj << 10) | (unsigned)(1023 - j);
        cnt += (keyj > keyi) ? 1 : 0;
    }
    #pragma unroll
    for (int d = 32; d > 0; d >>= 1) cnt += __shfl_down(cnt, d);
    __shared__ int red[4];
    if ((threadIdx.x & 63) == 0) red[threadIdx.x >> 6] = cnt;
    __syncthreads();
    if (threadIdx.x == 0) sorted[red[0] + red[1] + red[2] + red[3]] = i;
}

// ---------------- K6c: sorted-order greedy scan (1 wave) ----------------
__global__ void nms_scan2_kernel(const int* __restrict__ sorted,
                                 const unsigned long long* __restrict__ M,
                                 int* __restrict__ idx_out) {
    int lane = threadIdx.x;            // 64 lanes
    unsigned long long sup = 0ull;     // lanes 0..15 hold suppression words
    int n = 0;
    for (int chunk = 0; chunk < 16 && n < NMS_K; chunk++) {
        int cid = sorted[chunk*64 + lane];
        int cw = cid >> 6, cb = cid & 63;
        unsigned long long supw = __shfl(sup, cw);
        unsigned long long mask = __ballot(((supw >> cb) & 1ull) == 0ull);
        while (mask != 0ull && n < NMS_K) {
            int p = __ffsll(mask) - 1;          // earliest free candidate
            int c = __shfl(cid, p);             // its box id (wave-uniform)
            if (lane == 0) idx_out[n] = c;
            n++;
            unsigned long long roww = (lane < 16) ? M[(size_t)c*16 + lane] : 0ull;
            sup |= roww;
            unsigned long long tw = __shfl(roww, cw);   // row word covering cid
            unsigned long long kill = __ballot(((tw >> cb) & 1ull) != 0ull);
            mask &= ~kill;
            mask &= ~(1ull << p);               // safety: always retire p
        }
    }
    if (lane == 0) {
        for (; n < NMS_K; n++) idx_out[n] = 0;
    }
}

// ---------------- K7: gather outputs ----------------
__global__ void gather_kernel(const int* __restrict__ idx,
                              const float* __restrict__ obj_soft,
                              const float* __restrict__ pred,
                              const float* __restrict__ off,
                              const float* __restrict__ orient,
                              float* __restrict__ out) {
    int i = threadIdx.x;
    if (i < NMS_K) {
        int j = idx[i];
        out[2*i+0] = obj_soft[j*2+0];
        out[2*i+1] = obj_soft[j*2+1];
        #pragma unroll
        for (int t = 0; t < 6; t++) out[200 + 6*i + t] = pred[j*6+t];
        #pragma unroll
        for (int t = 0; t < 10; t++) out[800 + 10*i + t] = off[j*10+t];
        #pragma unroll
        for (int t = 0; t < 6; t++) out[1800 + 7*i + t] = pred[j*6+t];
        out[1800 + 7*i + 6] = 0.0f;
        out[2500 + i] = orient[j];
    }
}

extern "C" void kernel_launch(void* const* d_in, const int* in_sizes, int n_in,
                              void* d_out, int out_size, void* d_ws, size_t ws_size,
                              hipStream_t stream) {
    const float* imgF     = (const float*)d_in[0];
    const float* bevF     = (const float*)d_in[1];
    const float* anchors  = (const float*)d_in[2];
    const float* calib    = (const float*)d_in[3];
    const float* img_mask = (const float*)d_in[5];
    const float* bev_mask = (const float*)d_in[6];
    const float* W1 = (const float*)d_in[7];
    const float* b1 = (const float*)d_in[8];
    const float* W2 = (const float*)d_in[9];
    const float* b2 = (const float*)d_in[10];
    const float* Wc = (const float*)d_in[11];
    const float* bc = (const float*)d_in[12];
    const float* Wo = (const float*)d_in[13];
    const float* bo = (const float*)d_in[14];
    const float* Wa = (const float*)d_in[15];
    const float* ba = (const float*)d_in[16];
    const int* image_shape = (const int*)d_in[17];

    float* ws = (float*)d_ws;
    float* img_boxes = ws + WS_IMG_BOXES;
    float* bev_boxes = ws + WS_BEV_BOXES;
    float* obj_soft  = ws + WS_OBJS;
    float* off       = ws + WS_OFF;
    float* orient    = ws + WS_ORIENT;
    float* pred      = ws + WS_PRED;
    float* pbev      = ws + WS_PBEV;
    float* scores    = ws + WS_SCORES;
    int*   idx       = (int*)(ws + WS_IDX);
    int*   sorted    = (int*)(ws + WS_SORT);
    float* img_s     = ws + WS_R0;
    float* bev_s     = ws + WS_R1;
    float* img_t     = ws + WS_IMGT;    // alias of R1+ region; dead before bev roi
    unsigned short* fusedHi = (unsigned short*)(ws + WS_FUSED_HI);
    unsigned short* fusedLo = (unsigned short*)(ws + WS_FUSED_LO);
    unsigned short* h1Hi    = (unsigned short*)(ws + WS_H1HI);
    unsigned short* h1Lo    = (unsigned short*)(ws + WS_H1LO);
    float* h2        = ws + WS_H2;
    unsigned long long* nmsM = (unsigned long long*)(ws + WS_NMSM); // dead h1

    boxes_kernel<<<N_PROP/64, 64, 0, stream>>>(anchors, calib, image_shape,
                                               img_boxes, bev_boxes);
    for (int ch = 0; ch < 4; ch++) {
        transpose_img_kernel<<<dim3((IMG_W+63)/64, IMG_H), 256, 0, stream>>>(
            imgF, img_t, ch*8);
        roi_img_cl_kernel<<<N_PROP, 256, 0, stream>>>(
            img_t, img_boxes, img_s, ch*8);
    }
    roi_bev_kernel<<<dim3(C_FEAT/CHPB, N_PROP), 64, 0, stream>>>(
        bevF, bev_boxes, bev_s);
    combine_split_kernel<<<(N_PROP*D_FEAT/4 + 255)/256, 256, 0, stream>>>(
        (const float4*)img_s, (const float4*)bev_s, img_mask, bev_mask,
        (ushort4*)fusedHi, (ushort4*)fusedLo, N_PROP*D_FEAT/4);
    gemm_bf16x2_kernel<1><<<dim3(16, 16), 256, 0, stream>>>(
        fusedHi, fusedLo, W1, b1, D_FEAT, h1Hi, h1Lo, nullptr);
    gemm_bf16x2_kernel<0><<<dim3(16, 16), 256, 0, stream>>>(
        h1Hi, h1Lo, W2, b2, HID, nullptr, nullptr, h2);
    heads_kernel<<<N_PROP, 256, 0, stream>>>(h2, Wc, bc, Wo, bo, Wa, ba, anchors,
                                             obj_soft, off, orient, pred, pbev, scores);
    nms_mask_kernel<<<N_PROP, 256, 0, stream>>>(pbev, nmsM);
    nms_rank_kernel<<<N_PROP, 256, 0, stream>>>(scores, sorted);
    nms_scan2_kernel<<<1, 64, 0, stream>>>(sorted, nmsM, idx);
    gather_kernel<<<1, 128, 0, stream>>>(idx, obj_soft, pred, off, orient,
                                         (float*)d_out);
}

// Round 6
// 560.072 us; speedup vs baseline: 1.2771x; 1.0556x over previous
//
#include <hip/hip_runtime.h>
#include <math.h>

#define N_PROP 1024
#define C_FEAT 32
#define ROI 7
#define SR 6
#define S_GRID 42
#define IMG_H 360
#define IMG_W 1200
#define BEV_H 700
#define BEV_W 800
#define D_FEAT (C_FEAT*ROI*ROI)   // 1568
#define HID 2048
#define NMS_K 100
#define NMS_THR 0.01f

typedef __attribute__((ext_vector_type(8))) short bf16x8;
typedef __attribute__((ext_vector_type(4))) float f32x4;
typedef __attribute__((ext_vector_type(2), aligned(4))) float f32x2u;
typedef __attribute__((ext_vector_type(4), aligned(4))) float f32x4u;

// ---------------- workspace layout (float offsets) ----------------
// Peak 5,102,592 floats = 20.4 MB (< 25.3 MB proven).
#define WS_IMG_BOXES 0
#define WS_BEV_BOXES (WS_IMG_BOXES + 4*N_PROP)
#define WS_OBJS      (WS_BEV_BOXES + 4*N_PROP)
#define WS_OFF       (WS_OBJS + 2*N_PROP)
#define WS_ORIENT    (WS_OFF + 10*N_PROP)
#define WS_PRED      (WS_ORIENT + N_PROP)
#define WS_PBEV      (WS_PRED + 6*N_PROP)
#define WS_SCORES    (WS_PBEV + 4*N_PROP)
#define WS_IDX       (WS_SCORES + N_PROP)                // 100 ints
#define WS_SORT      (WS_IDX + 128)                      // 1024 ints
#define WS_R0        40960
#define WS_R1        (WS_R0 + N_PROP*D_FEAT)            // 1646592
#define WS_IMGT      WS_R1                               // img_t chunk alias
#define WS_FUSED_HI  (WS_R0 + 2*N_PROP*D_FEAT)          // 3252224
#define WS_FUSED_LO  (WS_FUSED_HI + N_PROP*D_FEAT/2)    // 4055040
#define WS_H1HI      WS_R0
#define WS_H1LO      (WS_R0 + N_PROP*HID/2)
#define WS_H2        (WS_R0 + N_PROP*HID)               // 2138112
#define WS_NMSM      WS_R0                               // u64[1024][16] over dead h1

__device__ __forceinline__ unsigned int bf16_rtn(float x) {
    unsigned int u = __float_as_uint(x);
    return (u + 0x7FFFu + ((u >> 16) & 1u)) >> 16;
}

// ---------------- K1: project boxes ----------------
__global__ void boxes_kernel(const float* __restrict__ anchors,
                             const float* __restrict__ calib,
                             const int* __restrict__ imshape,
                             float* __restrict__ img_boxes,
                             float* __restrict__ bev_boxes) {
    int n = blockIdx.x * blockDim.x + threadIdx.x;
    if (n >= N_PROP) return;
    float x = anchors[n*6+0], y = anchors[n*6+1], z = anchors[n*6+2];
    float dx = anchors[n*6+3], dy = anchors[n*6+4], dz = anchors[n*6+5];

    bev_boxes[n*4+0] = ((x - dx*0.5f) - (-40.0f)) / 0.1f;
    bev_boxes[n*4+1] = (70.0f - (z + dz*0.5f)) / 0.1f;
    bev_boxes[n*4+2] = ((x + dx*0.5f) - (-40.0f)) / 0.1f;
    bev_boxes[n*4+3] = (70.0f - (z - dz*0.5f)) / 0.1f;

    float P[12];
    #pragma unroll
    for (int i = 0; i < 12; i++) P[i] = calib[i];

    float umin = 1e30f, vmin = 1e30f, umax = -1e30f, vmax = -1e30f;
    #pragma unroll
    for (int k = 0; k < 8; k++) {
        float fsx = (k & 4) ? 1.0f : -1.0f;
        float fsy = (k & 2) ? 1.0f : -1.0f;
        float fsz = (k & 1) ? 1.0f : -1.0f;
        float cx = x + fsx * dx * 0.5f;
        float cy = y + fsy * dy * 0.5f;
        float cz = z + fsz * dz * 0.5f;
        float p0 = P[0]*cx + P[1]*cy + P[2]*cz + P[3];
        float p1 = P[4]*cx + P[5]*cy + P[6]*cz + P[7];
        float p2 = P[8]*cx + P[9]*cy + P[10]*cz + P[11];
        float zz = fmaxf(p2, 0.1f);
        float u = p0 / zz, v = p1 / zz;
        umin = fminf(umin, u); umax = fmaxf(umax, u);
        vmin = fminf(vmin, v); vmax = fmaxf(vmax, v);
    }
    float Hf = (float)imshape[0];
    float Wf = (float)imshape[1];
    img_boxes[n*4+0] = fminf(fmaxf(umin, 0.0f), Wf);
    img_boxes[n*4+1] = fminf(fmaxf(vmin, 0.0f), Hf);
    img_boxes[n*4+2] = fminf(fmaxf(umax, 0.0f), Wf);
    img_boxes[n*4+3] = fminf(fmaxf(vmax, 0.0f), Hf);
}

// ---------------- K2a: transpose img chunk [8c][H][W] -> [H][W][8c] ----------
__global__ __launch_bounds__(256) void transpose_img_kernel(
        const float* __restrict__ in, float* __restrict__ out, int c0) {
    __shared__ float lds[64*9];
    int y = blockIdx.y;
    int x0 = blockIdx.x * 64;
    int xl = threadIdx.x & 63;
    int ch = threadIdx.x >> 6;       // 0..3
    int x = x0 + xl;
    #pragma unroll
    for (int i = 0; i < 2; i++) {
        int c = ch + i*4;            // 0..7
        float v = 0.0f;
        if (x < IMG_W)
            v = in[(size_t)(c0+c)*IMG_H*IMG_W + (size_t)y*IMG_W + x];
        lds[xl*9 + c] = v;
    }
    __syncthreads();
    int c8 = threadIdx.x & 7;
    int xp = threadIdx.x >> 3;       // 0..31
    #pragma unroll
    for (int j = 0; j < 2; j++) {
        int xx = x0 + xp + j*32;
        if (xx < IMG_W)
            out[((size_t)y*IMG_W + xx)*8 + c8] = lds[(xp + j*32)*9 + c8];
    }
}

// ---------------- K2b: channel-last img roi (tap-optimized) ----------------
__global__ __launch_bounds__(256) void roi_img_cl_kernel(
        const float* __restrict__ T, const float* __restrict__ img_boxes,
        float* __restrict__ img_out, int c0) {
    int b = blockIdx.x;
    __shared__ float s_xw[S_GRID], s_yw[S_GRID];
    __shared__ int   s_xi[S_GRID], s_yr[S_GRID];
    __shared__ float s_out[8*49];
    int tid = threadIdx.x;
    if (tid < S_GRID) {
        float g = ((float)tid + 0.5f) / (float)S_GRID;
        float bx1 = img_boxes[b*4+0] - 0.5f, by1 = img_boxes[b*4+1] - 0.5f;
        float bx2 = img_boxes[b*4+2] - 0.5f, by2 = img_boxes[b*4+3] - 0.5f;
        float xs = bx1 + g * (bx2 - bx1);
        float x0f = fminf(fmaxf(floorf(xs), 0.0f), (float)(IMG_W-2));
        s_xw[tid] = fminf(fmaxf(xs - x0f, 0.0f), 1.0f);
        s_xi[tid] = (int)x0f * 8;                 // float offset: x*8
        float ys = by1 + g * (by2 - by1);
        float y0f = fminf(fmaxf(floorf(ys), 0.0f), (float)(IMG_H-2));
        s_yw[tid] = fminf(fmaxf(ys - y0f, 0.0f), 1.0f);
        s_yr[tid] = (int)y0f * (IMG_W*8);         // float offset: y*W*8
    }
    __syncthreads();

    int wv   = tid >> 6;
    int lane = tid & 63;
    int sy2 = lane >> 5;
    int sxb = (lane >> 4) & 1;
    int px  = (lane >> 1) & 7;    // 7 is idle
    int c4  = lane & 1;
    bool act = (px < 7);

    for (int pyi = 0; pyi < 2; pyi++) {
        int py = wv + pyi*4;
        if (py > 6) break;
        f32x4 acc = {0.f, 0.f, 0.f, 0.f};
        if (act) {
            #pragma unroll
            for (int t = 0; t < 3; t++) {
                int sy = py*6 + t*2 + sy2;
                int row0 = s_yr[sy];
                float wy = s_yw[sy];
                #pragma unroll
                for (int s = 0; s < 3; s++) {
                    int sx = px*6 + s*2 + sxb;
                    int col = s_xi[sx] + c4*4;
                    const float* p00 = T + row0 + col;
                    f32x4 v00 = *(const f32x4*)(p00);
                    f32x4 v01 = *(const f32x4*)(p00 + 8);
                    f32x4 v10 = *(const f32x4*)(p00 + IMG_W*8);
                    f32x4 v11 = *(const f32x4*)(p00 + IMG_W*8 + 8);
                    float wx = s_xw[sx];
                    #pragma unroll
                    for (int e = 0; e < 4; e++) {
                        float top = fmaf(wx, v01[e] - v00[e], v00[e]);
                        float bot = fmaf(wx, v11[e] - v10[e], v10[e]);
                        acc[e] += fmaf(wy, bot - top, top);
                    }
                }
            }
        }
        #pragma unroll
        for (int e = 0; e < 4; e++) acc[e] += __shfl_xor(acc[e], 32);
        #pragma unroll
        for (int e = 0; e < 4; e++) acc[e] += __shfl_xor(acc[e], 16);
        if (act && sy2 == 0 && sxb == 0) {
            #pragma unroll
            for (int e = 0; e < 4; e++)
                s_out[(c4*4+e)*49 + py*7 + px] = acc[e];
        }
    }
    __syncthreads();
    float* op = img_out + (size_t)b * D_FEAT + c0*49;
    for (int t = tid; t < 8*49; t += 256) op[t] = s_out[t];
}

// ---------------- K2c: bev roi, x-pair f32x4 gathers, 3 ch/wave ----------
// R9: validated model — gather wave-loads cost ~25 cy/CU each regardless of
// structure (R1/R4/R5 all within 5% of count*24.6cy).  bev x-step < 1 px,
// so samples (2j,2j+1) need cols [x0,x0+3]: one f32x4 per row serves TWO
// bilinear samples.  Lanes = 3 ch-groups x 21 x-pairs: 2 wave-loads per
// (py,sy) serve 3 channels x 42 samples -> 3.7K loads/CU (was 10.7K).
// Extraction via per-lane 4-wide weight windows (no dyn-index, no cndmask).
__global__ __launch_bounds__(64, 8) void roi_bev_kernel(
        const float* __restrict__ bevF, const float* __restrict__ bev_boxes,
        float* __restrict__ bev_out) {
    int gx = blockIdx.x;             // 0..10: channel triple
    int b  = blockIdx.y;
    int c0 = gx * 3;
    int nch = (C_FEAT - c0 < 3) ? (C_FEAT - c0) : 3;    // 3, last group 2
    const int W = BEV_W, H = BEV_H;

    int lane = threadIdx.x;
    __shared__ int   s_xi[S_GRID];
    __shared__ float s_xw[S_GRID];
    __shared__ int   s_row0[S_GRID];
    __shared__ float s_wy[S_GRID];

    if (lane < S_GRID) {
        float g = ((float)lane + 0.5f) / (float)S_GRID;
        float bx1 = bev_boxes[b*4+0], by1 = bev_boxes[b*4+1];
        float bx2 = bev_boxes[b*4+2], by2 = bev_boxes[b*4+3];
        float e1 = bx1 - 0.5f, e2 = bx2 - 0.5f;
        float xs = e1 + g * (e2 - e1);
        float x0f = fminf(fmaxf(floorf(xs), 0.0f), (float)(W-2));
        s_xw[lane] = fminf(fmaxf(xs - x0f, 0.0f), 1.0f);
        s_xi[lane] = (int)x0f;
        float d1 = by1 - 0.5f, d2 = by2 - 0.5f;
        float ys = d1 + g * (d2 - d1);
        float y0f = fminf(fmaxf(floorf(ys), 0.0f), (float)(H-2));
        s_wy[lane] = fminf(fmaxf(ys - y0f, 0.0f), 1.0f);
        s_row0[lane] = (int)y0f * W;
    }
    __syncthreads();

    int gl = lane / 21;          // channel in triple (3 -> idle lane 63)
    int j  = lane - gl*21;       // x-pair index 0..20 (samples 2j, 2j+1)
    bool act = (gl < nch);

    // per-lane fixed 4-col window + bilinear weight windows (built once)
    int basecol = 0;
    float wa0=0.f,wa1=0.f,wa2=0.f,wa3=0.f;
    float wb0=0.f,wb1=0.f,wb2=0.f,wb3=0.f;
    if (act) {
        int x0a = s_xi[2*j];
        int x0b = s_xi[2*j+1];           // in {x0a, x0a+1} (step < 1 px)
        float wxa = s_xw[2*j], wxb = s_xw[2*j+1];
        basecol = min(x0a, W-4);         // window [base..base+3] in-row always
        int ca = x0a - basecol;          // 0..2
        int cb = min(x0b - basecol, 2);  // 0..2 (clamp for safety)
        wa0 = (ca==0)? 1.f-wxa : 0.f;
        wa1 = (ca==0)? wxa : ((ca==1)? 1.f-wxa : 0.f);
        wa2 = (ca==1)? wxa : ((ca==2)? 1.f-wxa : 0.f);
        wa3 = (ca==2)? wxa : 0.f;
        wb0 = (cb==0)? 1.f-wxb : 0.f;
        wb1 = (cb==0)? wxb : ((cb==1)? 1.f-wxb : 0.f);
        wb2 = (cb==1)? wxb : ((cb==2)? 1.f-wxb : 0.f);
        wb3 = (cb==2)? wxb : 0.f;
    }
    const float* fp = bevF + (size_t)(c0 + (act ? gl : 0)) * W * H + basecol;
    int pxw = j / 3;
    bool wr = act && (j - pxw*3 == 0);
    float* op = bev_out + (size_t)b * D_FEAT + (c0+gl)*49;

    #pragma unroll 1
    for (int py = 0; py < ROI; py++) {
        float pl = 0.0f;
        #pragma unroll
        for (int sy = 0; sy < SR; sy++) {
            int yi = py*SR + sy;
            int r0 = s_row0[yi];
            float wy = s_wy[yi];
            if (act) {
                f32x4u q0 = *(const f32x4u*)(fp + r0);       // row y0
                f32x4u q1 = *(const f32x4u*)(fp + r0 + W);   // row y0+1
                float tA = fmaf(q0.x,wa0, fmaf(q0.y,wa1, fmaf(q0.z,wa2, q0.w*wa3)));
                float bA = fmaf(q1.x,wa0, fmaf(q1.y,wa1, fmaf(q1.z,wa2, q1.w*wa3)));
                float tB = fmaf(q0.x,wb0, fmaf(q0.y,wb1, fmaf(q0.z,wb2, q0.w*wb3)));
                float bB = fmaf(q1.x,wb0, fmaf(q1.y,wb1, fmaf(q1.z,wb2, q1.w*wb3)));
                pl += fmaf(wy, bA - tA, tA);
                pl += fmaf(wy, bB - tB, tB);
            }
        }
        float s = pl + __shfl_down(pl, 1) + __shfl_down(pl, 2);
        if (wr) op[py*ROI + pxw] = s;
    }
}

// ---------------- K3: combine masks + split fp32 -> bf16 hi/lo ----------------
__global__ __launch_bounds__(256) void combine_split_kernel(
        const float4* __restrict__ img, const float4* __restrict__ bev,
        const float* __restrict__ img_mask, const float* __restrict__ bev_mask,
        ushort4* __restrict__ outHi, ushort4* __restrict__ outLo, int total4) {
    int i = blockIdx.x * 256 + threadIdx.x;
    if (i >= total4) return;
    float m0 = img_mask[0], m1 = bev_mask[0];
    float inv = 1.0f / ((m0 + m1) * 36.0f);
    float w0 = m0 * inv, w1 = m1 * inv;
    float4 a = img[i], b = bev[i];
    float v[4] = { w0*a.x + w1*b.x, w0*a.y + w1*b.y, w0*a.z + w1*b.z, w0*a.w + w1*b.w };
    ushort4 hv, lv;
    unsigned short* hp = &hv.x;
    unsigned short* lp = &lv.x;
    #pragma unroll
    for (int e = 0; e < 4; e++) {
        unsigned int rh = bf16_rtn(v[e]);
        float lo = v[e] - __uint_as_float(rh << 16);
        hp[e] = (unsigned short)rh;
        lp[e] = (unsigned short)bf16_rtn(lo);
    }
    outHi[i] = hv;
    outLo[i] = lv;
}

// ---------------- K4: bf16x2 MFMA GEMM, C = relu(A@W + bias) ----------------
#define LDK 40   // LDS row stride (shorts); 80B rows keep b128 16B-aligned
template<int EPI>
__global__ __launch_bounds__(256) void gemm_bf16x2_kernel(
        const unsigned short* __restrict__ Ahi, const unsigned short* __restrict__ Alo,
        const float* __restrict__ W, const float* __restrict__ bias, int K,
        unsigned short* __restrict__ outHi, unsigned short* __restrict__ outLo,
        float* __restrict__ outF) {
    __shared__ short AsH[64*LDK], AsL[64*LDK];
    __shared__ short BsH[128*LDK], BsL[128*LDK];

    const int tid = threadIdx.x;
    const int m0 = blockIdx.y * 64, n0 = blockIdx.x * 128;

    const int am = tid >> 2, ac = tid & 3;
    const uint4* ApH = (const uint4*)(Ahi + (size_t)(m0 + am) * K + ac*8);
    const uint4* ApL = (const uint4*)(Alo + (size_t)(m0 + am) * K + ac*8);
    const int nn = tid & 127, rbase = (tid >> 7) * 16;
    const float* Bp = W + (size_t)rbase * 2048 + n0 + nn;

    const int lane = tid & 63, wave = tid >> 6;
    const int wm = wave & 1, wn = wave >> 1;
    const int l15 = lane & 15, quad = lane >> 4;

    f32x4 acc[2][4];
    #pragma unroll
    for (int i = 0; i < 2; i++)
        #pragma unroll
        for (int j = 0; j < 4; j++)
            acc[i][j] = (f32x4){0.f, 0.f, 0.f, 0.f};

    const int nK = K >> 5;
    uint4 aHr = ApH[0];
    uint4 aLr = ApL[0];
    float bReg[16];
    #pragma unroll
    for (int j = 0; j < 16; j++) bReg[j] = Bp[(size_t)j * 2048];

    for (int ks = 0; ks < nK; ks++) {
        __syncthreads();
        *(uint4*)&AsH[am*LDK + ac*8] = aHr;
        *(uint4*)&AsL[am*LDK + ac*8] = aLr;
        {
            unsigned short hv[16], lv[16];
            #pragma unroll
            for (int j = 0; j < 16; j++) {
                unsigned int rh = bf16_rtn(bReg[j]);
                float lo = bReg[j] - __uint_as_float(rh << 16);
                hv[j] = (unsigned short)rh;
                lv[j] = (unsigned short)bf16_rtn(lo);
            }
            *(uint4*)&BsH[nn*LDK + rbase + 0] = *(uint4*)&hv[0];
            *(uint4*)&BsH[nn*LDK + rbase + 8] = *(uint4*)&hv[8];
            *(uint4*)&BsL[nn*LDK + rbase + 0] = *(uint4*)&lv[0];
            *(uint4*)&BsL[nn*LDK + rbase + 8] = *(uint4*)&lv[8];
        }
        __syncthreads();
        if (ks + 1 < nK) {
            int k0n = (ks + 1) * 32;
            aHr = ApH[k0n >> 3];
            aLr = ApL[k0n >> 3];
            #pragma unroll
            for (int j = 0; j < 16; j++) bReg[j] = Bp[(size_t)(k0n + j) * 2048];
        }
        const short* aBH = AsH + (wm*32 + l15)*LDK + quad*8;
        const short* aBL = AsL + (wm*32 + l15)*LDK + quad*8;
        const short* bBH = BsH + (wn*64 + l15)*LDK + quad*8;
        const short* bBL = BsL + (wn*64 + l15)*LDK + quad*8;
        bf16x8 aH0 = *(const bf16x8*)(aBH);
        bf16x8 aH1 = *(const bf16x8*)(aBH + 16*LDK);
        bf16x8 aL0 = *(const bf16x8*)(aBL);
        bf16x8 aL1 = *(const bf16x8*)(aBL + 16*LDK);
        #pragma unroll
        for (int nt = 0; nt < 4; nt++) {
            bf16x8 bH = *(const bf16x8*)(bBH + nt*16*LDK);
            bf16x8 bL = *(const bf16x8*)(bBL + nt*16*LDK);
            acc[0][nt] = __builtin_amdgcn_mfma_f32_16x16x32_bf16(aH0, bH, acc[0][nt], 0, 0, 0);
            acc[0][nt] = __builtin_amdgcn_mfma_f32_16x16x32_bf16(aH0, bL, acc[0][nt], 0, 0, 0);
            acc[0][nt] = __builtin_amdgcn_mfma_f32_16x16x32_bf16(aL0, bH, acc[0][nt], 0, 0, 0);
            acc[1][nt] = __builtin_amdgcn_mfma_f32_16x16x32_bf16(aH1, bH, acc[1][nt], 0, 0, 0);
            acc[1][nt] = __builtin_amdgcn_mfma_f32_16x16x32_bf16(aH1, bL, acc[1][nt], 0, 0, 0);
            acc[1][nt] = __builtin_amdgcn_mfma_f32_16x16x32_bf16(aL1, bH, acc[1][nt], 0, 0, 0);
        }
    }

    #pragma unroll
    for (int mt = 0; mt < 2; mt++) {
        #pragma unroll
        for (int nt = 0; nt < 4; nt++) {
            int n = n0 + wn*64 + nt*16 + l15;
            float bv = bias[n];
            #pragma unroll
            for (int reg = 0; reg < 4; reg++) {
                int m = m0 + wm*32 + mt*16 + quad*4 + reg;
                float v = fmaxf(acc[mt][nt][reg] + bv, 0.0f);
                if (EPI == 1) {
                    unsigned int rh = bf16_rtn(v);
                    float lo = v - __uint_as_float(rh << 16);
                    outHi[(size_t)m * 2048 + n] = (unsigned short)rh;
                    outLo[(size_t)m * 2048 + n] = (unsigned short)bf16_rtn(lo);
                } else {
                    outF[(size_t)m * 2048 + n] = v;
                }
            }
        }
    }
}

// ---------------- K5: heads (obj/off/ang) + postprocess per row ----------------
__global__ __launch_bounds__(256) void heads_kernel(
        const float* __restrict__ h,
        const float* __restrict__ Wc, const float* __restrict__ bc,
        const float* __restrict__ Wo, const float* __restrict__ bo,
        const float* __restrict__ Wa, const float* __restrict__ ba,
        const float* __restrict__ anchors,
        float* __restrict__ obj_soft, float* __restrict__ off_out,
        float* __restrict__ orient, float* __restrict__ pred,
        float* __restrict__ pbev, float* __restrict__ scores) {
    int row = blockIdx.x;
    const float* hr = h + (size_t)row * HID;
    float acc[14];
    #pragma unroll
    for (int j = 0; j < 14; j++) acc[j] = 0.0f;
    for (int k = threadIdx.x; k < HID; k += 256) {
        float hv = hr[k];
        acc[0]  += hv * Wc[k*2+0];
        acc[1]  += hv * Wc[k*2+1];
        #pragma unroll
        for (int j = 0; j < 10; j++) acc[2+j] += hv * Wo[k*10+j];
        acc[12] += hv * Wa[k*2+0];
        acc[13] += hv * Wa[k*2+1];
    }
    #pragma unroll
    for (int d = 32; d > 0; d >>= 1) {
        #pragma unroll
        for (int j = 0; j < 14; j++) acc[j] += __shfl_down(acc[j], d);
    }
    __shared__ float red[4][14];
    int wid = threadIdx.x >> 6, lane = threadIdx.x & 63;
    if (lane == 0) {
        #pragma unroll
        for (int j = 0; j < 14; j++) red[wid][j] = acc[j];
    }
    __syncthreads();
    if (threadIdx.x == 0) {
        float f[14];
        #pragma unroll
        for (int j = 0; j < 14; j++)
            f[j] = red[0][j] + red[1][j] + red[2][j] + red[3][j];
        float obj0 = f[0] + bc[0], obj1 = f[1] + bc[1];
        float offv[10];
        #pragma unroll
        for (int j = 0; j < 10; j++) offv[j] = f[2+j] + bo[j];
        float ang0 = f[12] + ba[0], ang1 = f[13] + ba[1];
        float mx = fmaxf(obj0, obj1);
        float e0 = expf(obj0 - mx), e1 = expf(obj1 - mx);
        float den = e0 + e1;
        obj_soft[row*2+0] = e0 / den;
        obj_soft[row*2+1] = e1 / den;
        scores[row] = obj1;
        orient[row] = atan2f(ang1, ang0);
        float pa[6];
        #pragma unroll
        for (int j = 0; j < 6; j++) {
            pa[j] = anchors[row*6+j] + offv[j];
            pred[row*6+j] = pa[j];
        }
        #pragma unroll
        for (int j = 0; j < 10; j++) off_out[row*10+j] = offv[j];
        float x = pa[0], z = pa[2], ddx = pa[3], ddz = pa[5];
        pbev[row*4+0] = ((x - ddx*0.5f) - (-40.0f)) / 0.1f;
        pbev[row*4+1] = (70.0f - (z + ddz*0.5f)) / 0.1f;
        pbev[row*4+2] = ((x + ddx*0.5f) - (-40.0f)) / 0.1f;
        pbev[row*4+3] = (70.0f - (z - ddz*0.5f)) / 0.1f;
    }
}

// ---------------- K6a: NMS suppression bitmap (parallel) ----------------
__global__ __launch_bounds__(256) void nms_mask_kernel(
        const float* __restrict__ boxes, unsigned long long* __restrict__ M) {
    int i = blockIdx.x;
    const float4* bp = (const float4*)boxes;
    float4 bi4 = bp[i];
    float ai = (bi4.z - bi4.x) * (bi4.w - bi4.y);
    int lane = threadIdx.x & 63, wave = threadIdx.x >> 6;
    #pragma unroll
    for (int it = 0; it < 4; it++) {
        int q = it*256 + wave*64 + lane;
        float4 bq = bp[q];
        float aq = (bq.z - bq.x) * (bq.w - bq.y);
        float xx1 = fmaxf(bi4.x, bq.x), yy1 = fmaxf(bi4.y, bq.y);
        float xx2 = fminf(bi4.z, bq.z), yy2 = fminf(bi4.w, bq.w);
        float inter = fmaxf(xx2 - xx1, 0.0f) * fmaxf(yy2 - yy1, 0.0f);
        float iou = inter / (ai + aq - inter + 1e-6f);
        unsigned long long bal = __ballot(iou > NMS_THR);
        if (lane == 0) M[(size_t)i*16 + it*4 + wave] = bal;
    }
}

// ---------------- K6b: counting-rank sort by (score desc, idx asc) -----------
__global__ __launch_bounds__(256) void nms_rank_kernel(
        const float* __restrict__ scores, int* __restrict__ sorted) {
    int i = blockIdx.x;
    unsigned int u = __float_as_uint(scores[i]);
    unsigned int ki = (u & 0x80000000u) ? ~u : (u | 0x80000000u);
    unsigned long long keyi = ((unsigned long long)ki << 10) | (unsigned)(1023 - i);
    int cnt = 0;
    #pragma unroll
    for (int t = 0; t < 4; t++) {
        int j = threadIdx.x + t*256;
        unsigned int uj = __float_as_uint(scores[j]);
        unsigned int kj = (uj & 0x80000000u) ? ~uj : (uj | 0x80000000u);
        unsigned long long keyj = ((unsigned long long)kj << 10) | (unsigned)(1023 - j);
        cnt += (keyj > keyi) ? 1 : 0;
    }
    #pragma unroll
    for (int d = 32; d > 0; d >>= 1) cnt += __shfl_down(cnt, d);
    __shared__ int red[4];
    if ((threadIdx.x & 63) == 0) red[threadIdx.x >> 6] = cnt;
    __syncthreads();
    if (threadIdx.x == 0) sorted[red[0] + red[1] + red[2] + red[3]] = i;
}

// ---------------- K6c: sorted-order greedy scan (1 wave) ----------------
__global__ void nms_scan2_kernel(const int* __restrict__ sorted,
                                 const unsigned long long* __restrict__ M,
                                 int* __restrict__ idx_out) {
    int lane = threadIdx.x;            // 64 lanes
    unsigned long long sup = 0ull;     // lanes 0..15 hold suppression words
    int n = 0;
    for (int chunk = 0; chunk < 16 && n < NMS_K; chunk++) {
        int cid = sorted[chunk*64 + lane];
        int cw = cid >> 6, cb = cid & 63;
        unsigned long long supw = __shfl(sup, cw);
        unsigned long long mask = __ballot(((supw >> cb) & 1ull) == 0ull);
        while (mask != 0ull && n < NMS_K) {
            int p = __ffsll(mask) - 1;          // earliest free candidate
            int c = __shfl(cid, p);             // its box id (wave-uniform)
            if (lane == 0) idx_out[n] = c;
            n++;
            unsigned long long roww = (lane < 16) ? M[(size_t)c*16 + lane] : 0ull;
            sup |= roww;
            unsigned long long tw = __shfl(roww, cw);   // row word covering cid
            unsigned long long kill = __ballot(((tw >> cb) & 1ull) != 0ull);
            mask &= ~kill;
            mask &= ~(1ull << p);               // safety: always retire p
        }
    }
    if (lane == 0) {
        for (; n < NMS_K; n++) idx_out[n] = 0;
    }
}

// ---------------- K7: gather outputs ----------------
__global__ void gather_kernel(const int* __restrict__ idx,
                              const float* __restrict__ obj_soft,
                              const float* __restrict__ pred,
                              const float* __restrict__ off,
                              const float* __restrict__ orient,
                              float* __restrict__ out) {
    int i = threadIdx.x;
    if (i < NMS_K) {
        int j = idx[i];
        out[2*i+0] = obj_soft[j*2+0];
        out[2*i+1] = obj_soft[j*2+1];
        #pragma unroll
        for (int t = 0; t < 6; t++) out[200 + 6*i + t] = pred[j*6+t];
        #pragma unroll
        for (int t = 0; t < 10; t++) out[800 + 10*i + t] = off[j*10+t];
        #pragma unroll
        for (int t = 0; t < 6; t++) out[1800 + 7*i + t] = pred[j*6+t];
        out[1800 + 7*i + 6] = 0.0f;
        out[2500 + i] = orient[j];
    }
}

extern "C" void kernel_launch(void* const* d_in, const int* in_sizes, int n_in,
                              void* d_out, int out_size, void* d_ws, size_t ws_size,
                              hipStream_t stream) {
    const float* imgF     = (const float*)d_in[0];
    const float* bevF     = (const float*)d_in[1];
    const float* anchors  = (const float*)d_in[2];
    const float* calib    = (const float*)d_in[3];
    const float* img_mask = (const float*)d_in[5];
    const float* bev_mask = (const float*)d_in[6];
    const float* W1 = (const float*)d_in[7];
    const float* b1 = (const float*)d_in[8];
    const float* W2 = (const float*)d_in[9];
    const float* b2 = (const float*)d_in[10];
    const float* Wc = (const float*)d_in[11];
    const float* bc = (const float*)d_in[12];
    const float* Wo = (const float*)d_in[13];
    const float* bo = (const float*)d_in[14];
    const float* Wa = (const float*)d_in[15];
    const float* ba = (const float*)d_in[16];
    const int* image_shape = (const int*)d_in[17];

    float* ws = (float*)d_ws;
    float* img_boxes = ws + WS_IMG_BOXES;
    float* bev_boxes = ws + WS_BEV_BOXES;
    float* obj_soft  = ws + WS_OBJS;
    float* off       = ws + WS_OFF;
    float* orient    = ws + WS_ORIENT;
    float* pred      = ws + WS_PRED;
    float* pbev      = ws + WS_PBEV;
    float* scores    = ws + WS_SCORES;
    int*   idx       = (int*)(ws + WS_IDX);
    int*   sorted    = (int*)(ws + WS_SORT);
    float* img_s     = ws + WS_R0;
    float* bev_s     = ws + WS_R1;
    float* img_t     = ws + WS_IMGT;    // alias of R1+ region; dead before bev roi
    unsigned short* fusedHi = (unsigned short*)(ws + WS_FUSED_HI);
    unsigned short* fusedLo = (unsigned short*)(ws + WS_FUSED_LO);
    unsigned short* h1Hi    = (unsigned short*)(ws + WS_H1HI);
    unsigned short* h1Lo    = (unsigned short*)(ws + WS_H1LO);
    float* h2        = ws + WS_H2;
    unsigned long long* nmsM = (unsigned long long*)(ws + WS_NMSM); // dead h1

    boxes_kernel<<<N_PROP/64, 64, 0, stream>>>(anchors, calib, image_shape,
                                               img_boxes, bev_boxes);
    for (int ch = 0; ch < 4; ch++) {
        transpose_img_kernel<<<dim3((IMG_W+63)/64, IMG_H), 256, 0, stream>>>(
            imgF, img_t, ch*8);
        roi_img_cl_kernel<<<N_PROP, 256, 0, stream>>>(
            img_t, img_boxes, img_s, ch*8);
    }
    roi_bev_kernel<<<dim3(11, N_PROP), 64, 0, stream>>>(
        bevF, bev_boxes, bev_s);
    combine_split_kernel<<<(N_PROP*D_FEAT/4 + 255)/256, 256, 0, stream>>>(
        (const float4*)img_s, (const float4*)bev_s, img_mask, bev_mask,
        (ushort4*)fusedHi, (ushort4*)fusedLo, N_PROP*D_FEAT/4);
    gemm_bf16x2_kernel<1><<<dim3(16, 16), 256, 0, stream>>>(
        fusedHi, fusedLo, W1, b1, D_FEAT, h1Hi, h1Lo, nullptr);
    gemm_bf16x2_kernel<0><<<dim3(16, 16), 256, 0, stream>>>(
        h1Hi, h1Lo, W2, b2, HID, nullptr, nullptr, h2);
    heads_kernel<<<N_PROP, 256, 0, stream>>>(h2, Wc, bc, Wo, bo, Wa, ba, anchors,
                                             obj_soft, off, orient, pred, pbev, scores);
    nms_mask_kernel<<<N_PROP, 256, 0, stream>>>(pbev, nmsM);
    nms_rank_kernel<<<N_PROP, 256, 0, stream>>>(scores, sorted);
    nms_scan2_kernel<<<1, 64, 0, stream>>>(sorted, nmsM, idx);
    gather_kernel<<<1, 128, 0, stream>>>(idx, obj_soft, pred, off, orient,
                                         (float*)d_out);
}

// Round 7
// 528.248 us; speedup vs baseline: 1.3540x; 1.0602x over previous
//
#include <hip/hip_runtime.h>
#include <math.h>

#define N_PROP 1024
#define C_FEAT 32
#define ROI 7
#define SR 6
#define S_GRID 42
#define IMG_H 360
#define IMG_W 1200
#define BEV_H 700
#define BEV_W 800
#define D_FEAT (C_FEAT*ROI*ROI)   // 1568
#define HID 2048
#define NMS_K 100
#define NMS_THR 0.01f

typedef __attribute__((ext_vector_type(8))) short bf16x8;
typedef __attribute__((ext_vector_type(4))) float f32x4;
typedef __attribute__((ext_vector_type(2), aligned(4))) float f32x2u;
typedef __attribute__((ext_vector_type(4), aligned(4))) float f32x4u;

// ---------------- workspace layout (float offsets) ----------------
// Peak 5,102,592 floats = 20.4 MB (< 25.3 MB proven).
#define WS_IMG_BOXES 0
#define WS_BEV_BOXES (WS_IMG_BOXES + 4*N_PROP)
#define WS_OBJS      (WS_BEV_BOXES + 4*N_PROP)
#define WS_OFF       (WS_OBJS + 2*N_PROP)
#define WS_ORIENT    (WS_OFF + 10*N_PROP)
#define WS_PRED      (WS_ORIENT + N_PROP)
#define WS_PBEV      (WS_PRED + 6*N_PROP)
#define WS_SCORES    (WS_PBEV + 4*N_PROP)
#define WS_IDX       (WS_SCORES + N_PROP)                // 100 ints
#define WS_SORT      (WS_IDX + 128)                      // 1024 ints
#define WS_R0        40960
#define WS_R1        (WS_R0 + N_PROP*D_FEAT)            // 1646592
#define WS_IMGT      WS_R1                               // img_t chunk alias
#define WS_FUSED_HI  (WS_R0 + 2*N_PROP*D_FEAT)          // 3252224
#define WS_FUSED_LO  (WS_FUSED_HI + N_PROP*D_FEAT/2)    // 4055040
#define WS_H1HI      WS_R0
#define WS_H1LO      (WS_R0 + N_PROP*HID/2)
#define WS_H2        (WS_R0 + N_PROP*HID)               // 2138112
#define WS_NMSM      WS_R0                               // u64[1024][16] over dead h1

__device__ __forceinline__ unsigned int bf16_rtn(float x) {
    unsigned int u = __float_as_uint(x);
    return (u + 0x7FFFu + ((u >> 16) & 1u)) >> 16;
}

// ---------------- K1: project boxes ----------------
__global__ void boxes_kernel(const float* __restrict__ anchors,
                             const float* __restrict__ calib,
                             const int* __restrict__ imshape,
                             float* __restrict__ img_boxes,
                             float* __restrict__ bev_boxes) {
    int n = blockIdx.x * blockDim.x + threadIdx.x;
    if (n >= N_PROP) return;
    float x = anchors[n*6+0], y = anchors[n*6+1], z = anchors[n*6+2];
    float dx = anchors[n*6+3], dy = anchors[n*6+4], dz = anchors[n*6+5];

    bev_boxes[n*4+0] = ((x - dx*0.5f) - (-40.0f)) / 0.1f;
    bev_boxes[n*4+1] = (70.0f - (z + dz*0.5f)) / 0.1f;
    bev_boxes[n*4+2] = ((x + dx*0.5f) - (-40.0f)) / 0.1f;
    bev_boxes[n*4+3] = (70.0f - (z - dz*0.5f)) / 0.1f;

    float P[12];
    #pragma unroll
    for (int i = 0; i < 12; i++) P[i] = calib[i];

    float umin = 1e30f, vmin = 1e30f, umax = -1e30f, vmax = -1e30f;
    #pragma unroll
    for (int k = 0; k < 8; k++) {
        float fsx = (k & 4) ? 1.0f : -1.0f;
        float fsy = (k & 2) ? 1.0f : -1.0f;
        float fsz = (k & 1) ? 1.0f : -1.0f;
        float cx = x + fsx * dx * 0.5f;
        float cy = y + fsy * dy * 0.5f;
        float cz = z + fsz * dz * 0.5f;
        float p0 = P[0]*cx + P[1]*cy + P[2]*cz + P[3];
        float p1 = P[4]*cx + P[5]*cy + P[6]*cz + P[7];
        float p2 = P[8]*cx + P[9]*cy + P[10]*cz + P[11];
        float zz = fmaxf(p2, 0.1f);
        float u = p0 / zz, v = p1 / zz;
        umin = fminf(umin, u); umax = fmaxf(umax, u);
        vmin = fminf(vmin, v); vmax = fmaxf(vmax, v);
    }
    float Hf = (float)imshape[0];
    float Wf = (float)imshape[1];
    img_boxes[n*4+0] = fminf(fmaxf(umin, 0.0f), Wf);
    img_boxes[n*4+1] = fminf(fmaxf(vmin, 0.0f), Hf);
    img_boxes[n*4+2] = fminf(fmaxf(umax, 0.0f), Wf);
    img_boxes[n*4+3] = fminf(fmaxf(vmax, 0.0f), Hf);
}

// ---------------- K2a: transpose img chunk [8c][H][W] -> [H][W][8c] ----------
__global__ __launch_bounds__(256) void transpose_img_kernel(
        const float* __restrict__ in, float* __restrict__ out, int c0) {
    __shared__ float lds[64*9];
    int y = blockIdx.y;
    int x0 = blockIdx.x * 64;
    int xl = threadIdx.x & 63;
    int ch = threadIdx.x >> 6;       // 0..3
    int x = x0 + xl;
    #pragma unroll
    for (int i = 0; i < 2; i++) {
        int c = ch + i*4;            // 0..7
        float v = 0.0f;
        if (x < IMG_W)
            v = in[(size_t)(c0+c)*IMG_H*IMG_W + (size_t)y*IMG_W + x];
        lds[xl*9 + c] = v;
    }
    __syncthreads();
    int c8 = threadIdx.x & 7;
    int xp = threadIdx.x >> 3;       // 0..31
    #pragma unroll
    for (int j = 0; j < 2; j++) {
        int xx = x0 + xp + j*32;
        if (xx < IMG_W)
            out[((size_t)y*IMG_W + xx)*8 + c8] = lds[(xp + j*32)*9 + c8];
    }
}

// ---------------- K2b: channel-last img roi (tap-optimized) ----------------
__global__ __launch_bounds__(256) void roi_img_cl_kernel(
        const float* __restrict__ T, const float* __restrict__ img_boxes,
        float* __restrict__ img_out, int c0) {
    int b = blockIdx.x;
    __shared__ float s_xw[S_GRID], s_yw[S_GRID];
    __shared__ int   s_xi[S_GRID], s_yr[S_GRID];
    __shared__ float s_out[8*49];
    int tid = threadIdx.x;
    if (tid < S_GRID) {
        float g = ((float)tid + 0.5f) / (float)S_GRID;
        float bx1 = img_boxes[b*4+0] - 0.5f, by1 = img_boxes[b*4+1] - 0.5f;
        float bx2 = img_boxes[b*4+2] - 0.5f, by2 = img_boxes[b*4+3] - 0.5f;
        float xs = bx1 + g * (bx2 - bx1);
        float x0f = fminf(fmaxf(floorf(xs), 0.0f), (float)(IMG_W-2));
        s_xw[tid] = fminf(fmaxf(xs - x0f, 0.0f), 1.0f);
        s_xi[tid] = (int)x0f * 8;                 // float offset: x*8
        float ys = by1 + g * (by2 - by1);
        float y0f = fminf(fmaxf(floorf(ys), 0.0f), (float)(IMG_H-2));
        s_yw[tid] = fminf(fmaxf(ys - y0f, 0.0f), 1.0f);
        s_yr[tid] = (int)y0f * (IMG_W*8);         // float offset: y*W*8
    }
    __syncthreads();

    int wv   = tid >> 6;
    int lane = tid & 63;
    int sy2 = lane >> 5;
    int sxb = (lane >> 4) & 1;
    int px  = (lane >> 1) & 7;    // 7 is idle
    int c4  = lane & 1;
    bool act = (px < 7);

    for (int pyi = 0; pyi < 2; pyi++) {
        int py = wv + pyi*4;
        if (py > 6) break;
        f32x4 acc = {0.f, 0.f, 0.f, 0.f};
        if (act) {
            #pragma unroll
            for (int t = 0; t < 3; t++) {
                int sy = py*6 + t*2 + sy2;
                int row0 = s_yr[sy];
                float wy = s_yw[sy];
                #pragma unroll
                for (int s = 0; s < 3; s++) {
                    int sx = px*6 + s*2 + sxb;
                    int col = s_xi[sx] + c4*4;
                    const float* p00 = T + row0 + col;
                    f32x4 v00 = *(const f32x4*)(p00);
                    f32x4 v01 = *(const f32x4*)(p00 + 8);
                    f32x4 v10 = *(const f32x4*)(p00 + IMG_W*8);
                    f32x4 v11 = *(const f32x4*)(p00 + IMG_W*8 + 8);
                    float wx = s_xw[sx];
                    #pragma unroll
                    for (int e = 0; e < 4; e++) {
                        float top = fmaf(wx, v01[e] - v00[e], v00[e]);
                        float bot = fmaf(wx, v11[e] - v10[e], v10[e]);
                        acc[e] += fmaf(wy, bot - top, top);
                    }
                }
            }
        }
        #pragma unroll
        for (int e = 0; e < 4; e++) acc[e] += __shfl_xor(acc[e], 32);
        #pragma unroll
        for (int e = 0; e < 4; e++) acc[e] += __shfl_xor(acc[e], 16);
        if (act && sy2 == 0 && sxb == 0) {
            #pragma unroll
            for (int e = 0; e < 4; e++)
                s_out[(c4*4+e)*49 + py*7 + px] = acc[e];
        }
    }
    __syncthreads();
    float* op = img_out + (size_t)b * D_FEAT + c0*49;
    for (int t = tid; t < 8*49; t += 256) op[t] = s_out[t];
}

// ---------------- K2c: bev roi, x-pair f32x4 gathers, 3 ch/wave ----------
__global__ __launch_bounds__(64, 8) void roi_bev_kernel(
        const float* __restrict__ bevF, const float* __restrict__ bev_boxes,
        float* __restrict__ bev_out) {
    int gx = blockIdx.x;             // 0..10: channel triple
    int b  = blockIdx.y;
    int c0 = gx * 3;
    int nch = (C_FEAT - c0 < 3) ? (C_FEAT - c0) : 3;    // 3, last group 2
    const int W = BEV_W, H = BEV_H;

    int lane = threadIdx.x;
    __shared__ int   s_xi[S_GRID];
    __shared__ float s_xw[S_GRID];
    __shared__ int   s_row0[S_GRID];
    __shared__ float s_wy[S_GRID];

    if (lane < S_GRID) {
        float g = ((float)lane + 0.5f) / (float)S_GRID;
        float bx1 = bev_boxes[b*4+0], by1 = bev_boxes[b*4+1];
        float bx2 = bev_boxes[b*4+2], by2 = bev_boxes[b*4+3];
        float e1 = bx1 - 0.5f, e2 = bx2 - 0.5f;
        float xs = e1 + g * (e2 - e1);
        float x0f = fminf(fmaxf(floorf(xs), 0.0f), (float)(W-2));
        s_xw[lane] = fminf(fmaxf(xs - x0f, 0.0f), 1.0f);
        s_xi[lane] = (int)x0f;
        float d1 = by1 - 0.5f, d2 = by2 - 0.5f;
        float ys = d1 + g * (d2 - d1);
        float y0f = fminf(fmaxf(floorf(ys), 0.0f), (float)(H-2));
        s_wy[lane] = fminf(fmaxf(ys - y0f, 0.0f), 1.0f);
        s_row0[lane] = (int)y0f * W;
    }
    __syncthreads();

    int gl = lane / 21;          // channel in triple (3 -> idle lane 63)
    int j  = lane - gl*21;       // x-pair index 0..20 (samples 2j, 2j+1)
    bool act = (gl < nch);

    int basecol = 0;
    float wa0=0.f,wa1=0.f,wa2=0.f,wa3=0.f;
    float wb0=0.f,wb1=0.f,wb2=0.f,wb3=0.f;
    if (act) {
        int x0a = s_xi[2*j];
        int x0b = s_xi[2*j+1];           // in {x0a, x0a+1} (step < 1 px)
        float wxa = s_xw[2*j], wxb = s_xw[2*j+1];
        basecol = min(x0a, W-4);         // window [base..base+3] in-row always
        int ca = x0a - basecol;          // 0..2
        int cb = min(x0b - basecol, 2);  // 0..2 (clamp for safety)
        wa0 = (ca==0)? 1.f-wxa : 0.f;
        wa1 = (ca==0)? wxa : ((ca==1)? 1.f-wxa : 0.f);
        wa2 = (ca==1)? wxa : ((ca==2)? 1.f-wxa : 0.f);
        wa3 = (ca==2)? wxa : 0.f;
        wb0 = (cb==0)? 1.f-wxb : 0.f;
        wb1 = (cb==0)? wxb : ((cb==1)? 1.f-wxb : 0.f);
        wb2 = (cb==1)? wxb : ((cb==2)? 1.f-wxb : 0.f);
        wb3 = (cb==2)? wxb : 0.f;
    }
    const float* fp = bevF + (size_t)(c0 + (act ? gl : 0)) * W * H + basecol;
    int pxw = j / 3;
    bool wr = act && (j - pxw*3 == 0);
    float* op = bev_out + (size_t)b * D_FEAT + (c0+gl)*49;

    #pragma unroll 1
    for (int py = 0; py < ROI; py++) {
        float pl = 0.0f;
        #pragma unroll
        for (int sy = 0; sy < SR; sy++) {
            int yi = py*SR + sy;
            int r0 = s_row0[yi];
            float wy = s_wy[yi];
            if (act) {
                f32x4u q0 = *(const f32x4u*)(fp + r0);       // row y0
                f32x4u q1 = *(const f32x4u*)(fp + r0 + W);   // row y0+1
                float tA = fmaf(q0.x,wa0, fmaf(q0.y,wa1, fmaf(q0.z,wa2, q0.w*wa3)));
                float bA = fmaf(q1.x,wa0, fmaf(q1.y,wa1, fmaf(q1.z,wa2, q1.w*wa3)));
                float tB = fmaf(q0.x,wb0, fmaf(q0.y,wb1, fmaf(q0.z,wb2, q0.w*wb3)));
                float bB = fmaf(q1.x,wb0, fmaf(q1.y,wb1, fmaf(q1.z,wb2, q1.w*wb3)));
                pl += fmaf(wy, bA - tA, tA);
                pl += fmaf(wy, bB - tB, tB);
            }
        }
        float s = pl + __shfl_down(pl, 1) + __shfl_down(pl, 2);
        if (wr) op[py*ROI + pxw] = s;
    }
}

// ---------------- K3: combine masks + split fp32 -> bf16 hi/lo ----------------
__global__ __launch_bounds__(256) void combine_split_kernel(
        const float4* __restrict__ img, const float4* __restrict__ bev,
        const float* __restrict__ img_mask, const float* __restrict__ bev_mask,
        ushort4* __restrict__ outHi, ushort4* __restrict__ outLo, int total4) {
    int i = blockIdx.x * 256 + threadIdx.x;
    if (i >= total4) return;
    float m0 = img_mask[0], m1 = bev_mask[0];
    float inv = 1.0f / ((m0 + m1) * 36.0f);
    float w0 = m0 * inv, w1 = m1 * inv;
    float4 a = img[i], b = bev[i];
    float v[4] = { w0*a.x + w1*b.x, w0*a.y + w1*b.y, w0*a.z + w1*b.z, w0*a.w + w1*b.w };
    ushort4 hv, lv;
    unsigned short* hp = &hv.x;
    unsigned short* lp = &lv.x;
    #pragma unroll
    for (int e = 0; e < 4; e++) {
        unsigned int rh = bf16_rtn(v[e]);
        float lo = v[e] - __uint_as_float(rh << 16);
        hp[e] = (unsigned short)rh;
        lp[e] = (unsigned short)bf16_rtn(lo);
    }
    outHi[i] = hv;
    outLo[i] = lv;
}

// ---------------- K4: bf16x2 MFMA GEMM, C = relu(A@W + bias) ----------------
// R10: double-buffered LDS + 2 register prefetch sets (all statically
// indexed; loop unrolled x2).  Previous single-buffer chain drained
// vmcnt(0)+2 barriers every K-step with 1 wave/SIMD (occ 10.7%): 3520
// cy/iter measured vs ~600 useful.  Now 1 barrier/iter; global loads get a
// 2-iteration window so the loop never waits on memory; convert/ds_read/
// MFMA pipeline back-to-back.  LDS 2x30720 = 61.4 KB (1 block/CU as before).
#define LDK 40   // LDS row stride (shorts); 80B rows keep b128 16B-aligned
#define GLOAD(ks, S) { \
    int k0_ = (ks) * 32; \
    aH##S = ApH[k0_ >> 3]; \
    aL##S = ApL[k0_ >> 3]; \
    _Pragma("unroll") \
    for (int j_ = 0; j_ < 16; j_++) bR##S[j_] = Bp[(size_t)(k0_ + j_) * 2048]; }

#define LSTORE(S, B) { \
    *(uint4*)&AsH[B][am*LDK + ac*8] = aH##S; \
    *(uint4*)&AsL[B][am*LDK + ac*8] = aL##S; \
    unsigned short hv_[16], lv_[16]; \
    _Pragma("unroll") \
    for (int j_ = 0; j_ < 16; j_++) { \
        unsigned int rh_ = bf16_rtn(bR##S[j_]); \
        float lo_ = bR##S[j_] - __uint_as_float(rh_ << 16); \
        hv_[j_] = (unsigned short)rh_; \
        lv_[j_] = (unsigned short)bf16_rtn(lo_); } \
    *(uint4*)&BsH[B][nn*LDK + rbase + 0] = *(uint4*)&hv_[0]; \
    *(uint4*)&BsH[B][nn*LDK + rbase + 8] = *(uint4*)&hv_[8]; \
    *(uint4*)&BsL[B][nn*LDK + rbase + 0] = *(uint4*)&lv_[0]; \
    *(uint4*)&BsL[B][nn*LDK + rbase + 8] = *(uint4*)&lv_[8]; }

#define KCOMPUTE(B) { \
    const short* aBH = &AsH[B][(wm*32 + l15)*LDK + quad*8]; \
    const short* aBL = &AsL[B][(wm*32 + l15)*LDK + quad*8]; \
    const short* bBH = &BsH[B][(wn*64 + l15)*LDK + quad*8]; \
    const short* bBL = &BsL[B][(wn*64 + l15)*LDK + quad*8]; \
    bf16x8 aH0 = *(const bf16x8*)(aBH); \
    bf16x8 aH1 = *(const bf16x8*)(aBH + 16*LDK); \
    bf16x8 aL0 = *(const bf16x8*)(aBL); \
    bf16x8 aL1 = *(const bf16x8*)(aBL + 16*LDK); \
    _Pragma("unroll") \
    for (int nt = 0; nt < 4; nt++) { \
        bf16x8 bH = *(const bf16x8*)(bBH + nt*16*LDK); \
        bf16x8 bL = *(const bf16x8*)(bBL + nt*16*LDK); \
        acc[0][nt] = __builtin_amdgcn_mfma_f32_16x16x32_bf16(aH0, bH, acc[0][nt], 0, 0, 0); \
        acc[0][nt] = __builtin_amdgcn_mfma_f32_16x16x32_bf16(aH0, bL, acc[0][nt], 0, 0, 0); \
        acc[0][nt] = __builtin_amdgcn_mfma_f32_16x16x32_bf16(aL0, bH, acc[0][nt], 0, 0, 0); \
        acc[1][nt] = __builtin_amdgcn_mfma_f32_16x16x32_bf16(aH1, bH, acc[1][nt], 0, 0, 0); \
        acc[1][nt] = __builtin_amdgcn_mfma_f32_16x16x32_bf16(aH1, bL, acc[1][nt], 0, 0, 0); \
        acc[1][nt] = __builtin_amdgcn_mfma_f32_16x16x32_bf16(aL1, bH, acc[1][nt], 0, 0, 0); \
    } }

template<int EPI>
__global__ __launch_bounds__(256) void gemm_bf16x2_kernel(
        const unsigned short* __restrict__ Ahi, const unsigned short* __restrict__ Alo,
        const float* __restrict__ W, const float* __restrict__ bias, int K,
        unsigned short* __restrict__ outHi, unsigned short* __restrict__ outLo,
        float* __restrict__ outF) {
    __shared__ short AsH[2][64*LDK], AsL[2][64*LDK];
    __shared__ short BsH[2][128*LDK], BsL[2][128*LDK];

    const int tid = threadIdx.x;
    const int m0 = blockIdx.y * 64, n0 = blockIdx.x * 128;

    const int am = tid >> 2, ac = tid & 3;
    const uint4* ApH = (const uint4*)(Ahi + (size_t)(m0 + am) * K + ac*8);
    const uint4* ApL = (const uint4*)(Alo + (size_t)(m0 + am) * K + ac*8);
    const int nn = tid & 127, rbase = (tid >> 7) * 16;
    const float* Bp = W + (size_t)rbase * 2048 + n0 + nn;

    const int lane = tid & 63, wave = tid >> 6;
    const int wm = wave & 1, wn = wave >> 1;
    const int l15 = lane & 15, quad = lane >> 4;

    f32x4 acc[2][4];
    #pragma unroll
    for (int i = 0; i < 2; i++)
        #pragma unroll
        for (int j = 0; j < 4; j++)
            acc[i][j] = (f32x4){0.f, 0.f, 0.f, 0.f};

    const int nK = K >> 5;   // >= 2 always (49 or 64)
    uint4 aHA, aLA, aHB, aLB;
    float bRA[16], bRB[16];

    // prologue: tile0 -> setA -> buf0; tile1 -> setB (in flight)
    GLOAD(0, A);
    LSTORE(A, 0);
    GLOAD(1, B);

    int ks = 0;
    while (true) {
        // even phase: compute buf0 (tile ks); stage tile ks+1 -> buf1; load ks+2 -> setA
        __syncthreads();
        if (ks + 1 < nK) LSTORE(B, 1);
        if (ks + 2 < nK) GLOAD(ks + 2, A);
        KCOMPUTE(0);
        ks++;
        if (ks >= nK) break;
        // odd phase: compute buf1 (tile ks); stage tile ks+1 -> buf0; load ks+2 -> setB
        __syncthreads();
        if (ks + 1 < nK) LSTORE(A, 0);
        if (ks + 2 < nK) GLOAD(ks + 2, B);
        KCOMPUTE(1);
        ks++;
        if (ks >= nK) break;
    }

    #pragma unroll
    for (int mt = 0; mt < 2; mt++) {
        #pragma unroll
        for (int nt = 0; nt < 4; nt++) {
            int n = n0 + wn*64 + nt*16 + l15;
            float bv = bias[n];
            #pragma unroll
            for (int reg = 0; reg < 4; reg++) {
                int m = m0 + wm*32 + mt*16 + quad*4 + reg;
                float v = fmaxf(acc[mt][nt][reg] + bv, 0.0f);
                if (EPI == 1) {
                    unsigned int rh = bf16_rtn(v);
                    float lo = v - __uint_as_float(rh << 16);
                    outHi[(size_t)m * 2048 + n] = (unsigned short)rh;
                    outLo[(size_t)m * 2048 + n] = (unsigned short)bf16_rtn(lo);
                } else {
                    outF[(size_t)m * 2048 + n] = v;
                }
            }
        }
    }
}

// ---------------- K5: heads (obj/off/ang) + postprocess per row ----------------
__global__ __launch_bounds__(256) void heads_kernel(
        const float* __restrict__ h,
        const float* __restrict__ Wc, const float* __restrict__ bc,
        const float* __restrict__ Wo, const float* __restrict__ bo,
        const float* __restrict__ Wa, const float* __restrict__ ba,
        const float* __restrict__ anchors,
        float* __restrict__ obj_soft, float* __restrict__ off_out,
        float* __restrict__ orient, float* __restrict__ pred,
        float* __restrict__ pbev, float* __restrict__ scores) {
    int row = blockIdx.x;
    const float* hr = h + (size_t)row * HID;
    float acc[14];
    #pragma unroll
    for (int j = 0; j < 14; j++) acc[j] = 0.0f;
    for (int k = threadIdx.x; k < HID; k += 256) {
        float hv = hr[k];
        acc[0]  += hv * Wc[k*2+0];
        acc[1]  += hv * Wc[k*2+1];
        #pragma unroll
        for (int j = 0; j < 10; j++) acc[2+j] += hv * Wo[k*10+j];
        acc[12] += hv * Wa[k*2+0];
        acc[13] += hv * Wa[k*2+1];
    }
    #pragma unroll
    for (int d = 32; d > 0; d >>= 1) {
        #pragma unroll
        for (int j = 0; j < 14; j++) acc[j] += __shfl_down(acc[j], d);
    }
    __shared__ float red[4][14];
    int wid = threadIdx.x >> 6, lane = threadIdx.x & 63;
    if (lane == 0) {
        #pragma unroll
        for (int j = 0; j < 14; j++) red[wid][j] = acc[j];
    }
    __syncthreads();
    if (threadIdx.x == 0) {
        float f[14];
        #pragma unroll
        for (int j = 0; j < 14; j++)
            f[j] = red[0][j] + red[1][j] + red[2][j] + red[3][j];
        float obj0 = f[0] + bc[0], obj1 = f[1] + bc[1];
        float offv[10];
        #pragma unroll
        for (int j = 0; j < 10; j++) offv[j] = f[2+j] + bo[j];
        float ang0 = f[12] + ba[0], ang1 = f[13] + ba[1];
        float mx = fmaxf(obj0, obj1);
        float e0 = expf(obj0 - mx), e1 = expf(obj1 - mx);
        float den = e0 + e1;
        obj_soft[row*2+0] = e0 / den;
        obj_soft[row*2+1] = e1 / den;
        scores[row] = obj1;
        orient[row] = atan2f(ang1, ang0);
        float pa[6];
        #pragma unroll
        for (int j = 0; j < 6; j++) {
            pa[j] = anchors[row*6+j] + offv[j];
            pred[row*6+j] = pa[j];
        }
        #pragma unroll
        for (int j = 0; j < 10; j++) off_out[row*10+j] = offv[j];
        float x = pa[0], z = pa[2], ddx = pa[3], ddz = pa[5];
        pbev[row*4+0] = ((x - ddx*0.5f) - (-40.0f)) / 0.1f;
        pbev[row*4+1] = (70.0f - (z + ddz*0.5f)) / 0.1f;
        pbev[row*4+2] = ((x + ddx*0.5f) - (-40.0f)) / 0.1f;
        pbev[row*4+3] = (70.0f - (z - ddz*0.5f)) / 0.1f;
    }
}

// ---------------- K6a: NMS suppression bitmap (parallel) ----------------
__global__ __launch_bounds__(256) void nms_mask_kernel(
        const float* __restrict__ boxes, unsigned long long* __restrict__ M) {
    int i = blockIdx.x;
    const float4* bp = (const float4*)boxes;
    float4 bi4 = bp[i];
    float ai = (bi4.z - bi4.x) * (bi4.w - bi4.y);
    int lane = threadIdx.x & 63, wave = threadIdx.x >> 6;
    #pragma unroll
    for (int it = 0; it < 4; it++) {
        int q = it*256 + wave*64 + lane;
        float4 bq = bp[q];
        float aq = (bq.z - bq.x) * (bq.w - bq.y);
        float xx1 = fmaxf(bi4.x, bq.x), yy1 = fmaxf(bi4.y, bq.y);
        float xx2 = fminf(bi4.z, bq.z), yy2 = fminf(bi4.w, bq.w);
        float inter = fmaxf(xx2 - xx1, 0.0f) * fmaxf(yy2 - yy1, 0.0f);
        float iou = inter / (ai + aq - inter + 1e-6f);
        unsigned long long bal = __ballot(iou > NMS_THR);
        if (lane == 0) M[(size_t)i*16 + it*4 + wave] = bal;
    }
}

// ---------------- K6b: counting-rank sort by (score desc, idx asc) -----------
__global__ __launch_bounds__(256) void nms_rank_kernel(
        const float* __restrict__ scores, int* __restrict__ sorted) {
    int i = blockIdx.x;
    unsigned int u = __float_as_uint(scores[i]);
    unsigned int ki = (u & 0x80000000u) ? ~u : (u | 0x80000000u);
    unsigned long long keyi = ((unsigned long long)ki << 10) | (unsigned)(1023 - i);
    int cnt = 0;
    #pragma unroll
    for (int t = 0; t < 4; t++) {
        int j = threadIdx.x + t*256;
        unsigned int uj = __float_as_uint(scores[j]);
        unsigned int kj = (uj & 0x80000000u) ? ~uj : (uj | 0x80000000u);
        unsigned long long keyj = ((unsigned long long)kj << 10) | (unsigned)(1023 - j);
        cnt += (keyj > keyi) ? 1 : 0;
    }
    #pragma unroll
    for (int d = 32; d > 0; d >>= 1) cnt += __shfl_down(cnt, d);
    __shared__ int red[4];
    if ((threadIdx.x & 63) == 0) red[threadIdx.x >> 6] = cnt;
    __syncthreads();
    if (threadIdx.x == 0) sorted[red[0] + red[1] + red[2] + red[3]] = i;
}

// ---------------- K6c: sorted-order greedy scan (1 wave) ----------------
__global__ void nms_scan2_kernel(const int* __restrict__ sorted,
                                 const unsigned long long* __restrict__ M,
                                 int* __restrict__ idx_out) {
    int lane = threadIdx.x;            // 64 lanes
    unsigned long long sup = 0ull;     // lanes 0..15 hold suppression words
    int n = 0;
    for (int chunk = 0; chunk < 16 && n < NMS_K; chunk++) {
        int cid = sorted[chunk*64 + lane];
        int cw = cid >> 6, cb = cid & 63;
        unsigned long long supw = __shfl(sup, cw);
        unsigned long long mask = __ballot(((supw >> cb) & 1ull) == 0ull);
        while (mask != 0ull && n < NMS_K) {
            int p = __ffsll(mask) - 1;          // earliest free candidate
            int c = __shfl(cid, p);             // its box id (wave-uniform)
            if (lane == 0) idx_out[n] = c;
            n++;
            unsigned long long roww = (lane < 16) ? M[(size_t)c*16 + lane] : 0ull;
            sup |= roww;
            unsigned long long tw = __shfl(roww, cw);   // row word covering cid
            unsigned long long kill = __ballot(((tw >> cb) & 1ull) != 0ull);
            mask &= ~kill;
            mask &= ~(1ull << p);               // safety: always retire p
        }
    }
    if (lane == 0) {
        for (; n < NMS_K; n++) idx_out[n] = 0;
    }
}

// ---------------- K7: gather outputs ----------------
__global__ void gather_kernel(const int* __restrict__ idx,
                              const float* __restrict__ obj_soft,
                              const float* __restrict__ pred,
                              const float* __restrict__ off,
                              const float* __restrict__ orient,
                              float* __restrict__ out) {
    int i = threadIdx.x;
    if (i < NMS_K) {
        int j = idx[i];
        out[2*i+0] = obj_soft[j*2+0];
        out[2*i+1] = obj_soft[j*2+1];
        #pragma unroll
        for (int t = 0; t < 6; t++) out[200 + 6*i + t] = pred[j*6+t];
        #pragma unroll
        for (int t = 0; t < 10; t++) out[800 + 10*i + t] = off[j*10+t];
        #pragma unroll
        for (int t = 0; t < 6; t++) out[1800 + 7*i + t] = pred[j*6+t];
        out[1800 + 7*i + 6] = 0.0f;
        out[2500 + i] = orient[j];
    }
}

extern "C" void kernel_launch(void* const* d_in, const int* in_sizes, int n_in,
                              void* d_out, int out_size, void* d_ws, size_t ws_size,
                              hipStream_t stream) {
    const float* imgF     = (const float*)d_in[0];
    const float* bevF     = (const float*)d_in[1];
    const float* anchors  = (const float*)d_in[2];
    const float* calib    = (const float*)d_in[3];
    const float* img_mask = (const float*)d_in[5];
    const float* bev_mask = (const float*)d_in[6];
    const float* W1 = (const float*)d_in[7];
    const float* b1 = (const float*)d_in[8];
    const float* W2 = (const float*)d_in[9];
    const float* b2 = (const float*)d_in[10];
    const float* Wc = (const float*)d_in[11];
    const float* bc = (const float*)d_in[12];
    const float* Wo = (const float*)d_in[13];
    const float* bo = (const float*)d_in[14];
    const float* Wa = (const float*)d_in[15];
    const float* ba = (const float*)d_in[16];
    const int* image_shape = (const int*)d_in[17];

    float* ws = (float*)d_ws;
    float* img_boxes = ws + WS_IMG_BOXES;
    float* bev_boxes = ws + WS_BEV_BOXES;
    float* obj_soft  = ws + WS_OBJS;
    float* off       = ws + WS_OFF;
    float* orient    = ws + WS_ORIENT;
    float* pred      = ws + WS_PRED;
    float* pbev      = ws + WS_PBEV;
    float* scores    = ws + WS_SCORES;
    int*   idx       = (int*)(ws + WS_IDX);
    int*   sorted    = (int*)(ws + WS_SORT);
    float* img_s     = ws + WS_R0;
    float* bev_s     = ws + WS_R1;
    float* img_t     = ws + WS_IMGT;    // alias of R1+ region; dead before bev roi
    unsigned short* fusedHi = (unsigned short*)(ws + WS_FUSED_HI);
    unsigned short* fusedLo = (unsigned short*)(ws + WS_FUSED_LO);
    unsigned short* h1Hi    = (unsigned short*)(ws + WS_H1HI);
    unsigned short* h1Lo    = (unsigned short*)(ws + WS_H1LO);
    float* h2        = ws + WS_H2;
    unsigned long long* nmsM = (unsigned long long*)(ws + WS_NMSM); // dead h1

    boxes_kernel<<<N_PROP/64, 64, 0, stream>>>(anchors, calib, image_shape,
                                               img_boxes, bev_boxes);
    for (int ch = 0; ch < 4; ch++) {
        transpose_img_kernel<<<dim3((IMG_W+63)/64, IMG_H), 256, 0, stream>>>(
            imgF, img_t, ch*8);
        roi_img_cl_kernel<<<N_PROP, 256, 0, stream>>>(
            img_t, img_boxes, img_s, ch*8);
    }
    roi_bev_kernel<<<dim3(11, N_PROP), 64, 0, stream>>>(
        bevF, bev_boxes, bev_s);
    combine_split_kernel<<<(N_PROP*D_FEAT/4 + 255)/256, 256, 0, stream>>>(
        (const float4*)img_s, (const float4*)bev_s, img_mask, bev_mask,
        (ushort4*)fusedHi, (ushort4*)fusedLo, N_PROP*D_FEAT/4);
    gemm_bf16x2_kernel<1><<<dim3(16, 16), 256, 0, stream>>>(
        fusedHi, fusedLo, W1, b1, D_FEAT, h1Hi, h1Lo, nullptr);
    gemm_bf16x2_kernel<0><<<dim3(16, 16), 256, 0, stream>>>(
        h1Hi, h1Lo, W2, b2, HID, nullptr, nullptr, h2);
    heads_kernel<<<N_PROP, 256, 0, stream>>>(h2, Wc, bc, Wo, bo, Wa, ba, anchors,
                                             obj_soft, off, orient, pred, pbev, scores);
    nms_mask_kernel<<<N_PROP, 256, 0, stream>>>(pbev, nmsM);
    nms_rank_kernel<<<N_PROP, 256, 0, stream>>>(scores, sorted);
    nms_scan2_kernel<<<1, 64, 0, stream>>>(sorted, nmsM, idx);
    gather_kernel<<<1, 128, 0, stream>>>(idx, obj_soft, pred, off, orient,
                                         (float*)d_out);
}

// Round 9
// 513.146 us; speedup vs baseline: 1.3939x; 1.0294x over previous
//
#include <hip/hip_runtime.h>
#include <math.h>

#define N_PROP 1024
#define C_FEAT 32
#define ROI 7
#define SR 6
#define S_GRID 42
#define IMG_H 360
#define IMG_W 1200
#define BEV_H 700
#define BEV_W 800
#define D_FEAT (C_FEAT*ROI*ROI)   // 1568
#define HID 2048
#define NMS_K 100
#define NMS_THR 0.01f

typedef __attribute__((ext_vector_type(8))) short bf16x8;
typedef __attribute__((ext_vector_type(4))) float f32x4;
typedef __attribute__((ext_vector_type(2), aligned(4))) float f32x2u;
typedef __attribute__((ext_vector_type(4), aligned(4))) float f32x4u;

// ---------------- workspace layout (float offsets) ----------------
// Peak 5,102,592 floats = 20.4 MB (< 25.3 MB proven).
#define WS_IMG_BOXES 0
#define WS_BEV_BOXES (WS_IMG_BOXES + 4*N_PROP)
#define WS_OBJS      (WS_BEV_BOXES + 4*N_PROP)
#define WS_OFF       (WS_OBJS + 2*N_PROP)
#define WS_ORIENT    (WS_OFF + 10*N_PROP)
#define WS_PRED      (WS_ORIENT + N_PROP)
#define WS_PBEV      (WS_PRED + 6*N_PROP)
#define WS_SCORES    (WS_PBEV + 4*N_PROP)
#define WS_IDX       (WS_SCORES + N_PROP)                // 100 ints
#define WS_SORT      (WS_IDX + 128)                      // 1024 ints
#define WS_R0        40960
#define WS_R1        (WS_R0 + N_PROP*D_FEAT)            // 1646592
#define WS_IMGT      WS_R1                               // img_t chunk alias
#define WS_FUSED_HI  (WS_R0 + 2*N_PROP*D_FEAT)          // 3252224
#define WS_FUSED_LO  (WS_FUSED_HI + N_PROP*D_FEAT/2)    // 4055040
#define WS_H1HI      WS_R0
#define WS_H1LO      (WS_R0 + N_PROP*HID/2)
#define WS_H2        (WS_R0 + N_PROP*HID)               // 2138112
#define WS_NMSM      WS_R0                               // u64[1024][16] over dead h1

__device__ __forceinline__ unsigned int bf16_rtn(float x) {
    unsigned int u = __float_as_uint(x);
    return (u + 0x7FFFu + ((u >> 16) & 1u)) >> 16;
}

// ---------------- K1: project boxes ----------------
__global__ void boxes_kernel(const float* __restrict__ anchors,
                             const float* __restrict__ calib,
                             const int* __restrict__ imshape,
                             float* __restrict__ img_boxes,
                             float* __restrict__ bev_boxes) {
    int n = blockIdx.x * blockDim.x + threadIdx.x;
    if (n >= N_PROP) return;
    float x = anchors[n*6+0], y = anchors[n*6+1], z = anchors[n*6+2];
    float dx = anchors[n*6+3], dy = anchors[n*6+4], dz = anchors[n*6+5];

    bev_boxes[n*4+0] = ((x - dx*0.5f) - (-40.0f)) / 0.1f;
    bev_boxes[n*4+1] = (70.0f - (z + dz*0.5f)) / 0.1f;
    bev_boxes[n*4+2] = ((x + dx*0.5f) - (-40.0f)) / 0.1f;
    bev_boxes[n*4+3] = (70.0f - (z - dz*0.5f)) / 0.1f;

    float P[12];
    #pragma unroll
    for (int i = 0; i < 12; i++) P[i] = calib[i];

    float umin = 1e30f, vmin = 1e30f, umax = -1e30f, vmax = -1e30f;
    #pragma unroll
    for (int k = 0; k < 8; k++) {
        float fsx = (k & 4) ? 1.0f : -1.0f;
        float fsy = (k & 2) ? 1.0f : -1.0f;
        float fsz = (k & 1) ? 1.0f : -1.0f;
        float cx = x + fsx * dx * 0.5f;
        float cy = y + fsy * dy * 0.5f;
        float cz = z + fsz * dz * 0.5f;
        float p0 = P[0]*cx + P[1]*cy + P[2]*cz + P[3];
        float p1 = P[4]*cx + P[5]*cy + P[6]*cz + P[7];
        float p2 = P[8]*cx + P[9]*cy + P[10]*cz + P[11];
        float zz = fmaxf(p2, 0.1f);
        float u = p0 / zz, v = p1 / zz;
        umin = fminf(umin, u); umax = fmaxf(umax, u);
        vmin = fminf(vmin, v); vmax = fmaxf(vmax, v);
    }
    float Hf = (float)imshape[0];
    float Wf = (float)imshape[1];
    img_boxes[n*4+0] = fminf(fmaxf(umin, 0.0f), Wf);
    img_boxes[n*4+1] = fminf(fmaxf(vmin, 0.0f), Hf);
    img_boxes[n*4+2] = fminf(fmaxf(umax, 0.0f), Wf);
    img_boxes[n*4+3] = fminf(fmaxf(vmax, 0.0f), Hf);
}

// ---------------- K2a: transpose img chunk [8c][H][W] -> [H][W][8c] ----------
__global__ __launch_bounds__(256) void transpose_img_kernel(
        const float* __restrict__ in, float* __restrict__ out, int c0) {
    __shared__ float lds[64*9];
    int y = blockIdx.y;
    int x0 = blockIdx.x * 64;
    int xl = threadIdx.x & 63;
    int ch = threadIdx.x >> 6;       // 0..3
    int x = x0 + xl;
    #pragma unroll
    for (int i = 0; i < 2; i++) {
        int c = ch + i*4;            // 0..7
        float v = 0.0f;
        if (x < IMG_W)
            v = in[(size_t)(c0+c)*IMG_H*IMG_W + (size_t)y*IMG_W + x];
        lds[xl*9 + c] = v;
    }
    __syncthreads();
    int c8 = threadIdx.x & 7;
    int xp = threadIdx.x >> 3;       // 0..31
    #pragma unroll
    for (int j = 0; j < 2; j++) {
        int xx = x0 + xp + j*32;
        if (xx < IMG_W)
            out[((size_t)y*IMG_W + xx)*8 + c8] = lds[(xp + j*32)*9 + c8];
    }
}

// ---------------- K2b: channel-last img roi (tap-optimized) ----------------
__global__ __launch_bounds__(256) void roi_img_cl_kernel(
        const float* __restrict__ T, const float* __restrict__ img_boxes,
        float* __restrict__ img_out, int c0) {
    int b = blockIdx.x;
    __shared__ float s_xw[S_GRID], s_yw[S_GRID];
    __shared__ int   s_xi[S_GRID], s_yr[S_GRID];
    __shared__ float s_out[8*49];
    int tid = threadIdx.x;
    if (tid < S_GRID) {
        float g = ((float)tid + 0.5f) / (float)S_GRID;
        float bx1 = img_boxes[b*4+0] - 0.5f, by1 = img_boxes[b*4+1] - 0.5f;
        float bx2 = img_boxes[b*4+2] - 0.5f, by2 = img_boxes[b*4+3] - 0.5f;
        float xs = bx1 + g * (bx2 - bx1);
        float x0f = fminf(fmaxf(floorf(xs), 0.0f), (float)(IMG_W-2));
        s_xw[tid] = fminf(fmaxf(xs - x0f, 0.0f), 1.0f);
        s_xi[tid] = (int)x0f * 8;                 // float offset: x*8
        float ys = by1 + g * (by2 - by1);
        float y0f = fminf(fmaxf(floorf(ys), 0.0f), (float)(IMG_H-2));
        s_yw[tid] = fminf(fmaxf(ys - y0f, 0.0f), 1.0f);
        s_yr[tid] = (int)y0f * (IMG_W*8);         // float offset: y*W*8
    }
    __syncthreads();

    int wv   = tid >> 6;
    int lane = tid & 63;
    int sy2 = lane >> 5;
    int sxb = (lane >> 4) & 1;
    int px  = (lane >> 1) & 7;    // 7 is idle
    int c4  = lane & 1;
    bool act = (px < 7);

    for (int pyi = 0; pyi < 2; pyi++) {
        int py = wv + pyi*4;
        if (py > 6) break;
        f32x4 acc = {0.f, 0.f, 0.f, 0.f};
        if (act) {
            #pragma unroll
            for (int t = 0; t < 3; t++) {
                int sy = py*6 + t*2 + sy2;
                int row0 = s_yr[sy];
                float wy = s_yw[sy];
                #pragma unroll
                for (int s = 0; s < 3; s++) {
                    int sx = px*6 + s*2 + sxb;
                    int col = s_xi[sx] + c4*4;
                    const float* p00 = T + row0 + col;
                    f32x4 v00 = *(const f32x4*)(p00);
                    f32x4 v01 = *(const f32x4*)(p00 + 8);
                    f32x4 v10 = *(const f32x4*)(p00 + IMG_W*8);
                    f32x4 v11 = *(const f32x4*)(p00 + IMG_W*8 + 8);
                    float wx = s_xw[sx];
                    #pragma unroll
                    for (int e = 0; e < 4; e++) {
                        float top = fmaf(wx, v01[e] - v00[e], v00[e]);
                        float bot = fmaf(wx, v11[e] - v10[e], v10[e]);
                        acc[e] += fmaf(wy, bot - top, top);
                    }
                }
            }
        }
        #pragma unroll
        for (int e = 0; e < 4; e++) acc[e] += __shfl_xor(acc[e], 32);
        #pragma unroll
        for (int e = 0; e < 4; e++) acc[e] += __shfl_xor(acc[e], 16);
        if (act && sy2 == 0 && sxb == 0) {
            #pragma unroll
            for (int e = 0; e < 4; e++)
                s_out[(c4*4+e)*49 + py*7 + px] = acc[e];
        }
    }
    __syncthreads();
    float* op = img_out + (size_t)b * D_FEAT + c0*49;
    for (int t = tid; t < 8*49; t += 256) op[t] = s_out[t];
}

// ---------------- K2c: bev roi, rolling row cache ----------
// R11 (resubmit; R8 bench was an infra failure): y-step < 1 px, so
// consecutive sy rows overlap: keep a 2-row register cache (v0,v1)
// advanced by a wave-uniform while (s_y0 shared, monotone non-decreasing
// since dz>0; bounded by H-2 -> terminates).  Each unique row loaded ONCE:
// ~28 wave-loads/block vs 84.  Same lane layout as R9; math per sample
// bit-identical to R9.
__global__ __launch_bounds__(64, 8) void roi_bev_kernel(
        const float* __restrict__ bevF, const float* __restrict__ bev_boxes,
        float* __restrict__ bev_out) {
    int gx = blockIdx.x;             // 0..10: channel triple
    int b  = blockIdx.y;
    int c0 = gx * 3;
    int nch = (C_FEAT - c0 < 3) ? (C_FEAT - c0) : 3;    // 3, last group 2
    const int W = BEV_W, H = BEV_H;

    int lane = threadIdx.x;
    __shared__ int   s_xi[S_GRID];
    __shared__ float s_xw[S_GRID];
    __shared__ int   s_y0[S_GRID];
    __shared__ float s_wy[S_GRID];

    if (lane < S_GRID) {
        float g = ((float)lane + 0.5f) / (float)S_GRID;
        float bx1 = bev_boxes[b*4+0], by1 = bev_boxes[b*4+1];
        float bx2 = bev_boxes[b*4+2], by2 = bev_boxes[b*4+3];
        float e1 = bx1 - 0.5f, e2 = bx2 - 0.5f;
        float xs = e1 + g * (e2 - e1);
        float x0f = fminf(fmaxf(floorf(xs), 0.0f), (float)(W-2));
        s_xw[lane] = fminf(fmaxf(xs - x0f, 0.0f), 1.0f);
        s_xi[lane] = (int)x0f;
        float d1 = by1 - 0.5f, d2 = by2 - 0.5f;
        float ys = d1 + g * (d2 - d1);
        float y0f = fminf(fmaxf(floorf(ys), 0.0f), (float)(H-2));
        s_wy[lane] = fminf(fmaxf(ys - y0f, 0.0f), 1.0f);
        s_y0[lane] = (int)y0f;
    }
    __syncthreads();

    int gl = lane / 21;          // channel in triple (3 -> idle lane 63)
    int j  = lane - gl*21;       // x-pair index 0..20 (samples 2j, 2j+1)
    bool act = (gl < nch);

    int basecol = 0;
    float wa0=0.f,wa1=0.f,wa2=0.f,wa3=0.f;
    float wb0=0.f,wb1=0.f,wb2=0.f,wb3=0.f;
    if (act) {
        int x0a = s_xi[2*j];
        int x0b = s_xi[2*j+1];           // in {x0a, x0a+1} (step < 1 px)
        float wxa = s_xw[2*j], wxb = s_xw[2*j+1];
        basecol = min(x0a, W-4);         // window [base..base+3] in-row always
        int ca = x0a - basecol;          // 0..2
        int cb = min(x0b - basecol, 2);  // 0..2 (clamp for safety)
        wa0 = (ca==0)? 1.f-wxa : 0.f;
        wa1 = (ca==0)? wxa : ((ca==1)? 1.f-wxa : 0.f);
        wa2 = (ca==1)? wxa : ((ca==2)? 1.f-wxa : 0.f);
        wa3 = (ca==2)? wxa : 0.f;
        wb0 = (cb==0)? 1.f-wxb : 0.f;
        wb1 = (cb==0)? wxb : ((cb==1)? 1.f-wxb : 0.f);
        wb2 = (cb==1)? wxb : ((cb==2)? 1.f-wxb : 0.f);
        wb3 = (cb==2)? wxb : 0.f;
    }
    const float* fp = bevF + (size_t)(c0 + (act ? gl : 0)) * W * H + basecol;
    int pxw = j / 3;
    bool wr = act && (j - pxw*3 == 0);
    float* op = bev_out + (size_t)b * D_FEAT + (c0+gl)*49;

    // rolling 2-row cache; rows monotone, each unique row loaded once.
    int cur = s_y0[0];
    f32x4u v0 = *(const f32x4u*)(fp + (size_t)cur * W);
    f32x4u v1 = *(const f32x4u*)(fp + (size_t)(cur+1) * W);

    #pragma unroll 1
    for (int py = 0; py < ROI; py++) {
        float pl = 0.0f;
        #pragma unroll 1
        for (int sy = 0; sy < SR; sy++) {
            int yi = py*SR + sy;
            int y0s = s_y0[yi];                  // wave-uniform
            while (cur < y0s) {                  // uniform branch, amortized <1
                cur++;
                v0 = v1;
                v1 = *(const f32x4u*)(fp + (size_t)(cur+1) * W);
            }
            float wy = s_wy[yi];
            float tA = fmaf(v0.x,wa0, fmaf(v0.y,wa1, fmaf(v0.z,wa2, v0.w*wa3)));
            float bA = fmaf(v1.x,wa0, fmaf(v1.y,wa1, fmaf(v1.z,wa2, v1.w*wa3)));
            float tB = fmaf(v0.x,wb0, fmaf(v0.y,wb1, fmaf(v0.z,wb2, v0.w*wb3)));
            float bB = fmaf(v1.x,wb0, fmaf(v1.y,wb1, fmaf(v1.z,wb2, v1.w*wb3)));
            pl += fmaf(wy, bA - tA, tA);
            pl += fmaf(wy, bB - tB, tB);
        }
        float s = pl + __shfl_down(pl, 1) + __shfl_down(pl, 2);
        if (wr) op[py*ROI + pxw] = s;
    }
}

// ---------------- K3: combine masks + split fp32 -> bf16 hi/lo ----------------
__global__ __launch_bounds__(256) void combine_split_kernel(
        const float4* __restrict__ img, const float4* __restrict__ bev,
        const float* __restrict__ img_mask, const float* __restrict__ bev_mask,
        ushort4* __restrict__ outHi, ushort4* __restrict__ outLo, int total4) {
    int i = blockIdx.x * 256 + threadIdx.x;
    if (i >= total4) return;
    float m0 = img_mask[0], m1 = bev_mask[0];
    float inv = 1.0f / ((m0 + m1) * 36.0f);
    float w0 = m0 * inv, w1 = m1 * inv;
    float4 a = img[i], b = bev[i];
    float v[4] = { w0*a.x + w1*b.x, w0*a.y + w1*b.y, w0*a.z + w1*b.z, w0*a.w + w1*b.w };
    ushort4 hv, lv;
    unsigned short* hp = &hv.x;
    unsigned short* lp = &lv.x;
    #pragma unroll
    for (int e = 0; e < 4; e++) {
        unsigned int rh = bf16_rtn(v[e]);
        float lo = v[e] - __uint_as_float(rh << 16);
        hp[e] = (unsigned short)rh;
        lp[e] = (unsigned short)bf16_rtn(lo);
    }
    outHi[i] = hv;
    outLo[i] = lv;
}

// ---------------- K4: bf16x2 MFMA GEMM, C = relu(A@W + bias) ----------------
// R10: double-buffered LDS + 2 register prefetch sets (statically indexed).
#define LDK 40   // LDS row stride (shorts); 80B rows keep b128 16B-aligned
#define GLOAD(ks, S) { \
    int k0_ = (ks) * 32; \
    aH##S = ApH[k0_ >> 3]; \
    aL##S = ApL[k0_ >> 3]; \
    _Pragma("unroll") \
    for (int j_ = 0; j_ < 16; j_++) bR##S[j_] = Bp[(size_t)(k0_ + j_) * 2048]; }

#define LSTORE(S, B) { \
    *(uint4*)&AsH[B][am*LDK + ac*8] = aH##S; \
    *(uint4*)&AsL[B][am*LDK + ac*8] = aL##S; \
    unsigned short hv_[16], lv_[16]; \
    _Pragma("unroll") \
    for (int j_ = 0; j_ < 16; j_++) { \
        unsigned int rh_ = bf16_rtn(bR##S[j_]); \
        float lo_ = bR##S[j_] - __uint_as_float(rh_ << 16); \
        hv_[j_] = (unsigned short)rh_; \
        lv_[j_] = (unsigned short)bf16_rtn(lo_); } \
    *(uint4*)&BsH[B][nn*LDK + rbase + 0] = *(uint4*)&hv_[0]; \
    *(uint4*)&BsH[B][nn*LDK + rbase + 8] = *(uint4*)&hv_[8]; \
    *(uint4*)&BsL[B][nn*LDK + rbase + 0] = *(uint4*)&lv_[0]; \
    *(uint4*)&BsL[B][nn*LDK + rbase + 8] = *(uint4*)&lv_[8]; }

#define KCOMPUTE(B) { \
    const short* aBH = &AsH[B][(wm*32 + l15)*LDK + quad*8]; \
    const short* aBL = &AsL[B][(wm*32 + l15)*LDK + quad*8]; \
    const short* bBH = &BsH[B][(wn*64 + l15)*LDK + quad*8]; \
    const short* bBL = &BsL[B][(wn*64 + l15)*LDK + quad*8]; \
    bf16x8 aH0 = *(const bf16x8*)(aBH); \
    bf16x8 aH1 = *(const bf16x8*)(aBH + 16*LDK); \
    bf16x8 aL0 = *(const bf16x8*)(aBL); \
    bf16x8 aL1 = *(const bf16x8*)(aBL + 16*LDK); \
    _Pragma("unroll") \
    for (int nt = 0; nt < 4; nt++) { \
        bf16x8 bH = *(const bf16x8*)(bBH + nt*16*LDK); \
        bf16x8 bL = *(const bf16x8*)(bBL + nt*16*LDK); \
        acc[0][nt] = __builtin_amdgcn_mfma_f32_16x16x32_bf16(aH0, bH, acc[0][nt], 0, 0, 0); \
        acc[0][nt] = __builtin_amdgcn_mfma_f32_16x16x32_bf16(aH0, bL, acc[0][nt], 0, 0, 0); \
        acc[0][nt] = __builtin_amdgcn_mfma_f32_16x16x32_bf16(aL0, bH, acc[0][nt], 0, 0, 0); \
        acc[1][nt] = __builtin_amdgcn_mfma_f32_16x16x32_bf16(aH1, bH, acc[1][nt], 0, 0, 0); \
        acc[1][nt] = __builtin_amdgcn_mfma_f32_16x16x32_bf16(aH1, bL, acc[1][nt], 0, 0, 0); \
        acc[1][nt] = __builtin_amdgcn_mfma_f32_16x16x32_bf16(aL1, bH, acc[1][nt], 0, 0, 0); \
    } }

template<int EPI>
__global__ __launch_bounds__(256) void gemm_bf16x2_kernel(
        const unsigned short* __restrict__ Ahi, const unsigned short* __restrict__ Alo,
        const float* __restrict__ W, const float* __restrict__ bias, int K,
        unsigned short* __restrict__ outHi, unsigned short* __restrict__ outLo,
        float* __restrict__ outF) {
    __shared__ short AsH[2][64*LDK], AsL[2][64*LDK];
    __shared__ short BsH[2][128*LDK], BsL[2][128*LDK];

    const int tid = threadIdx.x;
    const int m0 = blockIdx.y * 64, n0 = blockIdx.x * 128;

    const int am = tid >> 2, ac = tid & 3;
    const uint4* ApH = (const uint4*)(Ahi + (size_t)(m0 + am) * K + ac*8);
    const uint4* ApL = (const uint4*)(Alo + (size_t)(m0 + am) * K + ac*8);
    const int nn = tid & 127, rbase = (tid >> 7) * 16;
    const float* Bp = W + (size_t)rbase * 2048 + n0 + nn;

    const int lane = tid & 63, wave = tid >> 6;
    const int wm = wave & 1, wn = wave >> 1;
    const int l15 = lane & 15, quad = lane >> 4;

    f32x4 acc[2][4];
    #pragma unroll
    for (int i = 0; i < 2; i++)
        #pragma unroll
        for (int j = 0; j < 4; j++)
            acc[i][j] = (f32x4){0.f, 0.f, 0.f, 0.f};

    const int nK = K >> 5;   // >= 2 always (49 or 64)
    uint4 aHA, aLA, aHB, aLB;
    float bRA[16], bRB[16];

    // prologue: tile0 -> setA -> buf0; tile1 -> setB (in flight)
    GLOAD(0, A);
    LSTORE(A, 0);
    GLOAD(1, B);

    int ks = 0;
    while (true) {
        __syncthreads();
        if (ks + 1 < nK) LSTORE(B, 1);
        if (ks + 2 < nK) GLOAD(ks + 2, A);
        KCOMPUTE(0);
        ks++;
        if (ks >= nK) break;
        __syncthreads();
        if (ks + 1 < nK) LSTORE(A, 0);
        if (ks + 2 < nK) GLOAD(ks + 2, B);
        KCOMPUTE(1);
        ks++;
        if (ks >= nK) break;
    }

    #pragma unroll
    for (int mt = 0; mt < 2; mt++) {
        #pragma unroll
        for (int nt = 0; nt < 4; nt++) {
            int n = n0 + wn*64 + nt*16 + l15;
            float bv = bias[n];
            #pragma unroll
            for (int reg = 0; reg < 4; reg++) {
                int m = m0 + wm*32 + mt*16 + quad*4 + reg;
                float v = fmaxf(acc[mt][nt][reg] + bv, 0.0f);
                if (EPI == 1) {
                    unsigned int rh = bf16_rtn(v);
                    float lo = v - __uint_as_float(rh << 16);
                    outHi[(size_t)m * 2048 + n] = (unsigned short)rh;
                    outLo[(size_t)m * 2048 + n] = (unsigned short)bf16_rtn(lo);
                } else {
                    outF[(size_t)m * 2048 + n] = v;
                }
            }
        }
    }
}

// ---------------- K5: heads (obj/off/ang) + postprocess per row ----------------
__global__ __launch_bounds__(256) void heads_kernel(
        const float* __restrict__ h,
        const float* __restrict__ Wc, const float* __restrict__ bc,
        const float* __restrict__ Wo, const float* __restrict__ bo,
        const float* __restrict__ Wa, const float* __restrict__ ba,
        const float* __restrict__ anchors,
        float* __restrict__ obj_soft, float* __restrict__ off_out,
        float* __restrict__ orient, float* __restrict__ pred,
        float* __restrict__ pbev, float* __restrict__ scores) {
    int row = blockIdx.x;
    const float* hr = h + (size_t)row * HID;
    float acc[14];
    #pragma unroll
    for (int j = 0; j < 14; j++) acc[j] = 0.0f;
    for (int k = threadIdx.x; k < HID; k += 256) {
        float hv = hr[k];
        acc[0]  += hv * Wc[k*2+0];
        acc[1]  += hv * Wc[k*2+1];
        #pragma unroll
        for (int j = 0; j < 10; j++) acc[2+j] += hv * Wo[k*10+j];
        acc[12] += hv * Wa[k*2+0];
        acc[13] += hv * Wa[k*2+1];
    }
    #pragma unroll
    for (int d = 32; d > 0; d >>= 1) {
        #pragma unroll
        for (int j = 0; j < 14; j++) acc[j] += __shfl_down(acc[j], d);
    }
    __shared__ float red[4][14];
    int wid = threadIdx.x >> 6, lane = threadIdx.x & 63;
    if (lane == 0) {
        #pragma unroll
        for (int j = 0; j < 14; j++) red[wid][j] = acc[j];
    }
    __syncthreads();
    if (threadIdx.x == 0) {
        float f[14];
        #pragma unroll
        for (int j = 0; j < 14; j++)
            f[j] = red[0][j] + red[1][j] + red[2][j] + red[3][j];
        float obj0 = f[0] + bc[0], obj1 = f[1] + bc[1];
        float offv[10];
        #pragma unroll
        for (int j = 0; j < 10; j++) offv[j] = f[2+j] + bo[j];
        float ang0 = f[12] + ba[0], ang1 = f[13] + ba[1];
        float mx = fmaxf(obj0, obj1);
        float e0 = expf(obj0 - mx), e1 = expf(obj1 - mx);
        float den = e0 + e1;
        obj_soft[row*2+0] = e0 / den;
        obj_soft[row*2+1] = e1 / den;
        scores[row] = obj1;
        orient[row] = atan2f(ang1, ang0);
        float pa[6];
        #pragma unroll
        for (int j = 0; j < 6; j++) {
            pa[j] = anchors[row*6+j] + offv[j];
            pred[row*6+j] = pa[j];
        }
        #pragma unroll
        for (int j = 0; j < 10; j++) off_out[row*10+j] = offv[j];
        float x = pa[0], z = pa[2], ddx = pa[3], ddz = pa[5];
        pbev[row*4+0] = ((x - ddx*0.5f) - (-40.0f)) / 0.1f;
        pbev[row*4+1] = (70.0f - (z + ddz*0.5f)) / 0.1f;
        pbev[row*4+2] = ((x + ddx*0.5f) - (-40.0f)) / 0.1f;
        pbev[row*4+3] = (70.0f - (z - ddz*0.5f)) / 0.1f;
    }
}

// ---------------- K6a: NMS suppression bitmap (parallel) ----------------
__global__ __launch_bounds__(256) void nms_mask_kernel(
        const float* __restrict__ boxes, unsigned long long* __restrict__ M) {
    int i = blockIdx.x;
    const float4* bp = (const float4*)boxes;
    float4 bi4 = bp[i];
    float ai = (bi4.z - bi4.x) * (bi4.w - bi4.y);
    int lane = threadIdx.x & 63, wave = threadIdx.x >> 6;
    #pragma unroll
    for (int it = 0; it < 4; it++) {
        int q = it*256 + wave*64 + lane;
        float4 bq = bp[q];
        float aq = (bq.z - bq.x) * (bq.w - bq.y);
        float xx1 = fmaxf(bi4.x, bq.x), yy1 = fmaxf(bi4.y, bq.y);
        float xx2 = fminf(bi4.z, bq.z), yy2 = fminf(bi4.w, bq.w);
        float inter = fmaxf(xx2 - xx1, 0.0f) * fmaxf(yy2 - yy1, 0.0f);
        float iou = inter / (ai + aq - inter + 1e-6f);
        unsigned long long bal = __ballot(iou > NMS_THR);
        if (lane == 0) M[(size_t)i*16 + it*4 + wave] = bal;
    }
}

// ---------------- K6b: counting-rank sort by (score desc, idx asc) -----------
__global__ __launch_bounds__(256) void nms_rank_kernel(
        const float* __restrict__ scores, int* __restrict__ sorted) {
    int i = blockIdx.x;
    unsigned int u = __float_as_uint(scores[i]);
    unsigned int ki = (u & 0x80000000u) ? ~u : (u | 0x80000000u);
    unsigned long long keyi = ((unsigned long long)ki << 10) | (unsigned)(1023 - i);
    int cnt = 0;
    #pragma unroll
    for (int t = 0; t < 4; t++) {
        int j = threadIdx.x + t*256;
        unsigned int uj = __float_as_uint(scores[j]);
        unsigned int kj = (uj & 0x80000000u) ? ~uj : (uj | 0x80000000u);
        unsigned long long keyj = ((unsigned long long)kj << 10) | (unsigned)(1023 - j);
        cnt += (keyj > keyi) ? 1 : 0;
    }
    #pragma unroll
    for (int d = 32; d > 0; d >>= 1) cnt += __shfl_down(cnt, d);
    __shared__ int red[4];
    if ((threadIdx.x & 63) == 0) red[threadIdx.x >> 6] = cnt;
    __syncthreads();
    if (threadIdx.x == 0) sorted[red[0] + red[1] + red[2] + red[3]] = i;
}

// ---------------- K6c: sorted-order greedy scan (1 wave) ----------------
__global__ void nms_scan2_kernel(const int* __restrict__ sorted,
                                 const unsigned long long* __restrict__ M,
                                 int* __restrict__ idx_out) {
    int lane = threadIdx.x;            // 64 lanes
    unsigned long long sup = 0ull;     // lanes 0..15 hold suppression words
    int n = 0;
    for (int chunk = 0; chunk < 16 && n < NMS_K; chunk++) {
        int cid = sorted[chunk*64 + lane];
        int cw = cid >> 6, cb = cid & 63;
        unsigned long long supw = __shfl(sup, cw);
        unsigned long long mask = __ballot(((supw >> cb) & 1ull) == 0ull);
        while (mask != 0ull && n < NMS_K) {
            int p = __ffsll(mask) - 1;          // earliest free candidate
            int c = __shfl(cid, p);             // its box id (wave-uniform)
            if (lane == 0) idx_out[n] = c;
            n++;
            unsigned long long roww = (lane < 16) ? M[(size_t)c*16 + lane] : 0ull;
            sup |= roww;
            unsigned long long tw = __shfl(roww, cw);   // row word covering cid
            unsigned long long kill = __ballot(((tw >> cb) & 1ull) != 0ull);
            mask &= ~kill;
            mask &= ~(1ull << p);               // safety: always retire p
        }
    }
    if (lane == 0) {
        for (; n < NMS_K; n++) idx_out[n] = 0;
    }
}

// ---------------- K7: gather outputs ----------------
__global__ void gather_kernel(const int* __restrict__ idx,
                              const float* __restrict__ obj_soft,
                              const float* __restrict__ pred,
                              const float* __restrict__ off,
                              const float* __restrict__ orient,
                              float* __restrict__ out) {
    int i = threadIdx.x;
    if (i < NMS_K) {
        int j = idx[i];
        out[2*i+0] = obj_soft[j*2+0];
        out[2*i+1] = obj_soft[j*2+1];
        #pragma unroll
        for (int t = 0; t < 6; t++) out[200 + 6*i + t] = pred[j*6+t];
        #pragma unroll
        for (int t = 0; t < 10; t++) out[800 + 10*i + t] = off[j*10+t];
        #pragma unroll
        for (int t = 0; t < 6; t++) out[1800 + 7*i + t] = pred[j*6+t];
        out[1800 + 7*i + 6] = 0.0f;
        out[2500 + i] = orient[j];
    }
}

extern "C" void kernel_launch(void* const* d_in, const int* in_sizes, int n_in,
                              void* d_out, int out_size, void* d_ws, size_t ws_size,
                              hipStream_t stream) {
    const float* imgF     = (const float*)d_in[0];
    const float* bevF     = (const float*)d_in[1];
    const float* anchors  = (const float*)d_in[2];
    const float* calib    = (const float*)d_in[3];
    const float* img_mask = (const float*)d_in[5];
    const float* bev_mask = (const float*)d_in[6];
    const float* W1 = (const float*)d_in[7];
    const float* b1 = (const float*)d_in[8];
    const float* W2 = (const float*)d_in[9];
    const float* b2 = (const float*)d_in[10];
    const float* Wc = (const float*)d_in[11];
    const float* bc = (const float*)d_in[12];
    const float* Wo = (const float*)d_in[13];
    const float* bo = (const float*)d_in[14];
    const float* Wa = (const float*)d_in[15];
    const float* ba = (const float*)d_in[16];
    const int* image_shape = (const int*)d_in[17];

    float* ws = (float*)d_ws;
    float* img_boxes = ws + WS_IMG_BOXES;
    float* bev_boxes = ws + WS_BEV_BOXES;
    float* obj_soft  = ws + WS_OBJS;
    float* off       = ws + WS_OFF;
    float* orient    = ws + WS_ORIENT;
    float* pred      = ws + WS_PRED;
    float* pbev      = ws + WS_PBEV;
    float* scores    = ws + WS_SCORES;
    int*   idx       = (int*)(ws + WS_IDX);
    int*   sorted    = (int*)(ws + WS_SORT);
    float* img_s     = ws + WS_R0;
    float* bev_s     = ws + WS_R1;
    float* img_t     = ws + WS_IMGT;    // alias of R1+ region; dead before bev roi
    unsigned short* fusedHi = (unsigned short*)(ws + WS_FUSED_HI);
    unsigned short* fusedLo = (unsigned short*)(ws + WS_FUSED_LO);
    unsigned short* h1Hi    = (unsigned short*)(ws + WS_H1HI);
    unsigned short* h1Lo    = (unsigned short*)(ws + WS_H1LO);
    float* h2        = ws + WS_H2;
    unsigned long long* nmsM = (unsigned long long*)(ws + WS_NMSM); // dead h1

    boxes_kernel<<<N_PROP/64, 64, 0, stream>>>(anchors, calib, image_shape,
                                               img_boxes, bev_boxes);
    for (int ch = 0; ch < 4; ch++) {
        transpose_img_kernel<<<dim3((IMG_W+63)/64, IMG_H), 256, 0, stream>>>(
            imgF, img_t, ch*8);
        roi_img_cl_kernel<<<N_PROP, 256, 0, stream>>>(
            img_t, img_boxes, img_s, ch*8);
    }
    roi_bev_kernel<<<dim3(11, N_PROP), 64, 0, stream>>>(
        bevF, bev_boxes, bev_s);
    combine_split_kernel<<<(N_PROP*D_FEAT/4 + 255)/256, 256, 0, stream>>>(
        (const float4*)img_s, (const float4*)bev_s, img_mask, bev_mask,
        (ushort4*)fusedHi, (ushort4*)fusedLo, N_PROP*D_FEAT/4);
    gemm_bf16x2_kernel<1><<<dim3(16, 16), 256, 0, stream>>>(
        fusedHi, fusedLo, W1, b1, D_FEAT, h1Hi, h1Lo, nullptr);
    gemm_bf16x2_kernel<0><<<dim3(16, 16), 256, 0, stream>>>(
        h1Hi, h1Lo, W2, b2, HID, nullptr, nullptr, h2);
    heads_kernel<<<N_PROP, 256, 0, stream>>>(h2, Wc, bc, Wo, bo, Wa, ba, anchors,
                                             obj_soft, off, orient, pred, pbev, scores);
    nms_mask_kernel<<<N_PROP, 256, 0, stream>>>(pbev, nmsM);
    nms_rank_kernel<<<N_PROP, 256, 0, stream>>>(scores, sorted);
    nms_scan2_kernel<<<1, 64, 0, stream>>>(sorted, nmsM, idx);
    gather_kernel<<<1, 128, 0, stream>>>(idx, obj_soft, pred, off, orient,
                                         (float*)d_out);
}